// Round 2
// baseline (647.512 us; speedup 1.0000x reference)
//
#include <hip/hip_runtime.h>
#include <hip/hip_bf16.h>
#include <math.h>

#define B_  4
#define N_  4096
#define D_  1024
#define H_  16
#define DK_ 64
#define M_  256
#define R_  (B_*N_)          // 16384 rows
#define EPS_ 1e-6f
#define VTROWS_ 80           // 64 V rows + row64=ones(ksum) + 65..79 pad
#define KVROWS_ 128          // KVb bf16: 64 KV + 64=ksum_hi + 65=ksum_lo + 0-pad
#define PHK_PAD 136          // fused_kv  Phi LDS [m][136]
#define PHQ_PAD 264          // fused_ctx Phi LDS [n][264]

typedef __bf16 bf16;
typedef __bf16 bf16x4 __attribute__((ext_vector_type(4)));
typedef __bf16 bf16x8 __attribute__((ext_vector_type(8)));
typedef _Float16 f16;
typedef _Float16 f16x4 __attribute__((ext_vector_type(4)));
typedef _Float16 f16x8 __attribute__((ext_vector_type(8)));
typedef float  f32x4  __attribute__((ext_vector_type(4)));

#define GLD(gp, lp) __builtin_amdgcn_global_load_lds( \
    (const __attribute__((address_space(1))) void*)(gp), \
    (__attribute__((address_space(3))) void*)(lp), 16, 0, 0)

// ---------------------------------------------------------------------------
// prep kernels
// ---------------------------------------------------------------------------
__global__ __launch_bounds__(256)
void split_f16v(const float* __restrict__ in, f16* __restrict__ hi,
                f16* __restrict__ lo, int n4)
{
    int i = blockIdx.x * 256 + threadIdx.x;
    if (i < n4) {
        float4 v = ((const float4*)in)[i];
        f16x4 h = { (f16)v.x, (f16)v.y, (f16)v.z, (f16)v.w };
        ((f16x4*)hi)[i] = h;
        if (lo) {
            f16x4 l = { (f16)(v.x - (float)h[0]), (f16)(v.y - (float)h[1]),
                        (f16)(v.z - (float)h[2]), (f16)(v.w - (float)h[3]) };
            ((f16x4*)lo)[i] = l;
        }
    }
}

__global__ __launch_bounds__(256)
void f32_to_bf16v(const float* __restrict__ in, bf16* __restrict__ o, int n4)
{
    int i = blockIdx.x * 256 + threadIdx.x;
    if (i < n4) {
        float4 v = ((const float4*)in)[i];
        bf16x4 h = { (bf16)v.x, (bf16)v.y, (bf16)v.z, (bf16)v.w };
        ((bf16x4*)o)[i] = h;
    }
}

__global__ __launch_bounds__(256)
void zero_f32(float* __restrict__ p, int n)
{
    int i = blockIdx.x * 256 + threadIdx.x;
    if (i < n) p[i] = 0.f;
}

__global__ __launch_bounds__(256)
void init_vt(bf16* __restrict__ VT)
{
    int i = blockIdx.x * 256 + threadIdx.x;          // 64bh x 16rows x 4096
    if (i >= B_*H_*16*N_) return;
    int bh  = i >> 16;
    int rem = i & 65535;
    int row = 64 + (rem >> 12);
    int n   = rem & (N_-1);
    VT[((size_t)bh*VTROWS_ + row)*N_ + n] = (row == 64) ? (bf16)1.0f : (bf16)0.0f;
}

__global__ __launch_bounds__(256)
void pack_kv(const float* __restrict__ KVt32, bf16* __restrict__ KVb)
{
    int i = blockIdx.x * 256 + threadIdx.x;          // 64bh x 128 x 256
    if (i >= B_*H_*KVROWS_*M_) return;
    int bh  = i >> 15;
    int rem = i & 32767;
    int row = rem >> 8;
    int m   = rem & (M_-1);
    bf16 o = (bf16)0.0f;
    if (row < 64) {
        o = (bf16)KVt32[((size_t)bh*VTROWS_ + row)*M_ + m];
    } else if (row == 64) {
        o = (bf16)KVt32[((size_t)bh*VTROWS_ + 64)*M_ + m];
    } else if (row == 65) {
        float v = KVt32[((size_t)bh*VTROWS_ + 64)*M_ + m];
        o = (bf16)(v - (float)(bf16)v);
    }
    KVb[i] = o;
}

// ---------------------------------------------------------------------------
// Unified QKV projection — 256x256 tile, BK=64, 8 waves, 8-phase counted-vmcnt.
// Sync incantation is template-exact (m201): builtin s_barrier + CLOBBER-FREE
// waitcnt asm. (Round-1 regression: "memory" clobbers made the compiler drain
// vmcnt(0) at every barrier — the m97 stall x8.)
// ---------------------------------------------------------------------------

#define STAGE_(dstbuf, srcp, kt, half) do { \
    _Pragma("unroll") \
    for (int q_ = 0; q_ < 2; ++q_) { \
        int idx_ = q_*512 + tid; \
        int row_ = idx_ >> 3; \
        int seg_ = (idx_ & 7) ^ (row_ & 7); \
        GLD((srcp) + (size_t)((half)*128 + row_) * D_ + (kt)*64 + seg_*8, \
            &(dstbuf)[(half)*8192 + idx_*8]); \
    } } while (0)

#define LDA_(buf, i0) do { \
    _Pragma("unroll") \
    for (int i_ = 0; i_ < 4; ++i_) { \
        _Pragma("unroll") \
        for (int k_ = 0; k_ < 2; ++k_) { \
            int row_ = warp_m*128 + ((i0)+i_)*16 + m16; \
            int off_ = (row_*128 + k_*64 + quad*16) ^ ((row_ & 7) << 4); \
            a[i_][k_] = *(const f16x8*)((const char*)(buf) + off_); \
        } } } while (0)

#define LDB_(buf, j0) do { \
    _Pragma("unroll") \
    for (int j_ = 0; j_ < 2; ++j_) { \
        _Pragma("unroll") \
        for (int k_ = 0; k_ < 2; ++k_) { \
            int row_ = warp_n*64 + ((j0)+j_)*16 + m16; \
            int off_ = (row_*128 + k_*64 + quad*16) ^ ((row_ & 7) << 4); \
            b[(j0)+j_][k_] = *(const f16x8*)((const char*)(buf) + off_); \
        } } } while (0)

#define MFMA_Q(I0, J0) do { \
    _Pragma("unroll") \
    for (int i_ = 0; i_ < 4; ++i_) { \
        _Pragma("unroll") \
        for (int j_ = 0; j_ < 2; ++j_) { \
            _Pragma("unroll") \
            for (int k_ = 0; k_ < 2; ++k_) \
                acc[(I0)+i_][(J0)+j_] = __builtin_amdgcn_mfma_f32_16x16x32_f16( \
                    a[i_][k_], b[(J0)+j_][k_], acc[(I0)+i_][(J0)+j_], 0, 0, 0); \
        } } } while (0)

#define BAR_()   __builtin_amdgcn_s_barrier()
#define LGK0_()  do { asm volatile("s_waitcnt lgkmcnt(0)"); \
                      __builtin_amdgcn_sched_barrier(0); } while (0)
#define LGK8_()  asm volatile("s_waitcnt lgkmcnt(8)")
#define VMC4_()  do { asm volatile("s_waitcnt vmcnt(4)"); \
                      __builtin_amdgcn_sched_barrier(0); } while (0)
#define PRIO1_() __builtin_amdgcn_s_setprio(1)
#define PRIO0_() __builtin_amdgcn_s_setprio(0)

__global__ __launch_bounds__(512, 2)
void gemm_qkv(const f16* __restrict__ X, const f16* __restrict__ Wh,
              const float* __restrict__ bqkv,
              f16* __restrict__ Qh, f16* __restrict__ Kh, bf16* __restrict__ VT)
{
    __shared__ __align__(16) f16 sA[2][256*64];   // 64 KB
    __shared__ __align__(16) f16 sB[2][256*64];   // 64 KB
    const int tid = threadIdx.x;

    // T1: bijective XCD swizzle (nwg = 768, 768 % 8 == 0)
    const int nwg  = gridDim.x * gridDim.y;
    int flat = blockIdx.y * gridDim.x + blockIdx.x;
    int wgid = (flat & 7) * (nwg >> 3) + (flat >> 3);
    const int bm = (wgid / 12) * 256;
    const int bn = (wgid % 12) * 256;

    const int lane = tid & 63, wave = tid >> 6;
    const int warp_m = wave >> 2, warp_n = wave & 3;   // 2 x 4 waves
    const int m16 = lane & 15, quad = lane >> 4;

    const f16* gA = X  + (size_t)bm * D_;
    const f16* gB = Wh + (size_t)bn * D_;

    f32x4 acc[8][4];
    #pragma unroll
    for (int i = 0; i < 8; ++i)
        #pragma unroll
        for (int j = 0; j < 4; ++j)
            acc[i][j] = (f32x4){0.f, 0.f, 0.f, 0.f};

    f16x8 a[4][2], b[4][2];

    // prologue: tile0 A+B -> P0, tile1 B -> P1 (12 loads); vmcnt(4) leaves
    // only P1.B possibly outstanding -> P0 fully landed before ph1 reads.
    STAGE_(sA[0], gA, 0, 0);
    STAGE_(sA[0], gA, 0, 1);
    STAGE_(sB[0], gB, 0, 0);
    STAGE_(sB[0], gB, 0, 1);
    STAGE_(sB[1], gB, 1, 0);
    STAGE_(sB[1], gB, 1, 1);
    VMC4_();
    BAR_();

    for (int it = 0; it < 8; ++it) {
        const int t1 = 2*it + 1, t2 = 2*it + 2, t3 = 2*it + 3;
        // ---------- K-tile t0 from P0 ----------
        LDA_(sA[0], 0); LDB_(sB[0], 0);
        STAGE_(sA[1], gA, t1, 0);
        LGK8_();
        BAR_(); LGK0_();
        PRIO1_(); MFMA_Q(0, 0); PRIO0_();
        BAR_();

        LDB_(sB[0], 2);
        STAGE_(sA[1], gA, t1, 1);
        BAR_(); LGK0_();
        PRIO1_(); MFMA_Q(0, 2); PRIO0_();
        BAR_();

        LDA_(sA[0], 4);
        if (t2 < 16) STAGE_(sB[0], gB, t2, 0);
        BAR_(); LGK0_();
        PRIO1_(); MFMA_Q(4, 2); PRIO0_();
        BAR_();

        if (t2 < 16) STAGE_(sB[0], gB, t2, 1);
        VMC4_();
        BAR_();
        PRIO1_(); MFMA_Q(4, 0); PRIO0_();
        BAR_();

        // ---------- K-tile t1 from P1 ----------
        LDA_(sA[1], 0); LDB_(sB[1], 0);
        if (t2 < 16) STAGE_(sA[0], gA, t2, 0);
        LGK8_();
        BAR_(); LGK0_();
        PRIO1_(); MFMA_Q(0, 0); PRIO0_();
        BAR_();

        LDB_(sB[1], 2);
        if (t2 < 16) STAGE_(sA[0], gA, t2, 1);
        BAR_(); LGK0_();
        PRIO1_(); MFMA_Q(0, 2); PRIO0_();
        BAR_();

        LDA_(sA[1], 4);
        if (t3 < 16) STAGE_(sB[1], gB, t3, 0);
        BAR_(); LGK0_();
        PRIO1_(); MFMA_Q(4, 2); PRIO0_();
        BAR_();

        if (t3 < 16) STAGE_(sB[1], gB, t3, 1);
        VMC4_();
        BAR_();
        PRIO1_(); MFMA_Q(4, 0); PRIO0_();
        BAR_();
    }

    // epilogue: scatter Q / K / V (+bias). 256-col tiles never straddle the
    // Q/K/V boundaries (1024 % 256 == 0).
    #pragma unroll
    for (int j = 0; j < 4; ++j) {
        int gcol = bn + warp_n*64 + j*16 + m16;
        float bv = bqkv[gcol];
        #pragma unroll
        for (int i = 0; i < 8; ++i) {
            int row0 = bm + warp_m*128 + i*16 + quad*4;
            if (gcol >= 2*D_) {
                int vcol = gcol - 2*D_;
                int hh = vcol >> 6, dd = vcol & 63;
                int bb = row0 >> 12, nn = row0 & (N_-1);
                bf16x4 pk = { (bf16)(acc[i][j][0]+bv), (bf16)(acc[i][j][1]+bv),
                              (bf16)(acc[i][j][2]+bv), (bf16)(acc[i][j][3]+bv) };
                *(bf16x4*)&VT[(((size_t)bb*H_+hh)*VTROWS_ + dd)*N_ + nn] = pk;
            } else if (gcol >= D_) {
                #pragma unroll
                for (int r = 0; r < 4; ++r)
                    Kh[(size_t)(row0+r) * D_ + gcol - D_] = (f16)(acc[i][j][r] + bv);
            } else {
                #pragma unroll
                for (int r = 0; r < 4; ++r)
                    Qh[(size_t)(row0+r) * D_ + gcol] = (f16)(acc[i][j][r] + bv);
            }
        }
    }
}

// ---------------------------------------------------------------------------
// fused_kv: 512 threads (8 waves), double-buffered sK/sVT, stage for subtile
// t+1 issued mid-compute of subtile t (flight hides under softmax+kv-MFMA).
// vmcnt(0) at loop top only waits loads issued a full compute-phase ago.
// sK/sVT XOR-swizzled (pre-swizzled global source, swizzled ds_read).
// ---------------------------------------------------------------------------
#define STAGEKV_(sub_, bi_) do { \
    const int n0_ = nsp*1024 + (sub_)*128; \
    _Pragma("unroll") \
    for (int it_ = 0; it_ < 2; ++it_) { \
        int idx_ = it_*512 + tid; \
        int row_ = idx_ >> 3, seg_ = (idx_ & 7) ^ (row_ & 7); \
        GLD(Kh + (size_t)(b*N_ + n0_ + row_) * D_ + h*DK_ + seg_*8, \
            &sK[bi_][idx_*8]); \
    } \
    _Pragma("unroll") \
    for (int it_ = 0; it_ < 2; ++it_) { \
        int idx_ = it_*512 + tid; \
        int row_ = idx_ >> 4, seg_ = (idx_ & 15) ^ (row_ & 7); \
        GLD(VT + ((size_t)bh*VTROWS_ + row_)*N_ + n0_ + seg_*8, \
            &sVT[bi_][idx_*8]); \
    } \
    if (tid < 256) { \
        int idx_ = 1024 + tid; \
        int row_ = idx_ >> 4, seg_ = (idx_ & 15) ^ (row_ & 7); \
        GLD(VT + ((size_t)bh*VTROWS_ + row_)*N_ + n0_ + seg_*8, \
            &sVT[bi_][idx_*8]); \
    } } while (0)

__global__ __launch_bounds__(512, 2)
void fused_kv(const f16* __restrict__ Kh, const bf16* __restrict__ VT,
              const f16* __restrict__ omhi, const f16* __restrict__ omlo,
              const int* __restrict__ mask, float* __restrict__ KVt32)
{
    __shared__ __align__(16) f16  sK[2][128*64];      // 32 KB
    __shared__ __align__(16) bf16 sVT[2][VTROWS_*128];// 40 KB
    __shared__ __align__(16) bf16 sPhi[M_*PHK_PAD];   // 68 KB  [m][n] pad 136
    const int nsp = blockIdx.x;          // 0..3
    const int h = blockIdx.y, b = blockIdx.z;
    const int bh = b*H_ + h;
    const int tid = threadIdx.x, lane = tid & 63, wave = tid >> 6;
    const int m16 = lane & 15, quad = lane >> 4;
    const int wm = wave * 32;            // wave's m-range for kv MFMA
    const float inv_sqrt_m = rsqrtf((float)M_ + 1e-6f);
    const f16* omh = omhi + (size_t)h * M_ * DK_;
    const f16* oml = omlo + (size_t)h * M_ * DK_;

    f32x4 kvacc[5][2];
    #pragma unroll
    for (int d = 0; d < 5; ++d)
        #pragma unroll
        for (int j = 0; j < 2; ++j)
            kvacc[d][j] = (f32x4){0.f, 0.f, 0.f, 0.f};

    STAGEKV_(0, 0);

    for (int sub = 0; sub < 8; ++sub) {
        const int cur = sub & 1;
        const int n0 = nsp*1024 + sub*128;

        asm volatile("s_waitcnt vmcnt(0)");     // prev-iter stages (old) landed
        __builtin_amdgcn_sched_barrier(0);
        __builtin_amdgcn_s_barrier();           // (B) all waves' stages landed;
                                                //     prev readers of other buf done
        // ---- feat: proj = K . omega^T (wave owns 16 n-rows) ----
        const char* kb = (const char*)&sK[cur][0];
        const int rowb = wave*16 + m16;
        f16x8 ah0 = *(const f16x8*)(kb + ((rowb*128 +      quad*16) ^ ((rowb & 7) << 4)));
        f16x8 ah1 = *(const f16x8*)(kb + ((rowb*128 + 64 + quad*16) ^ ((rowb & 7) << 4)));

        f32x4 acc[16];
        #pragma unroll
        for (int j = 0; j < 16; ++j) acc[j] = (f32x4){0.f, 0.f, 0.f, 0.f};

        #pragma unroll
        for (int j = 0; j < 16; ++j) {
            size_t ro = (size_t)(j*16 + m16) * DK_ + quad*8;
            f16x8 bh0 = *(const f16x8*)&omh[ro];
            f16x8 bh1 = *(const f16x8*)&omh[ro + 32];
            f16x8 bl0 = *(const f16x8*)&oml[ro];
            f16x8 bl1 = *(const f16x8*)&oml[ro + 32];
            acc[j] = __builtin_amdgcn_mfma_f32_16x16x32_f16(ah0, bh0, acc[j], 0,0,0);
            acc[j] = __builtin_amdgcn_mfma_f32_16x16x32_f16(ah0, bl0, acc[j], 0,0,0);
            acc[j] = __builtin_amdgcn_mfma_f32_16x16x32_f16(ah1, bh1, acc[j], 0,0,0);
            acc[j] = __builtin_amdgcn_mfma_f32_16x16x32_f16(ah1, bl1, acc[j], 0,0,0);
        }

        // issue next subtile's stage AFTER the om loads (so compiler's om
        // waitcnts don't force the fresh stage to land); flight hides under
        // softmax + Phi write + kv MFMA.
        if (sub < 7) STAGEKV_(sub+1, cur^1);

        // rowmax + exp
        #pragma unroll
        for (int r = 0; r < 4; ++r) {
            float mx = acc[0][r];
            #pragma unroll
            for (int j = 1; j < 16; ++j) mx = fmaxf(mx, acc[j][r]);
            mx = fmaxf(mx, __shfl_xor(mx, 1, 64));
            mx = fmaxf(mx, __shfl_xor(mx, 2, 64));
            mx = fmaxf(mx, __shfl_xor(mx, 4, 64));
            mx = fmaxf(mx, __shfl_xor(mx, 8, 64));
            #pragma unroll
            for (int j = 0; j < 16; ++j)
                acc[j][r] = __expf(acc[j][r] - mx) * inv_sqrt_m;
        }

        // Phi -> LDS [m][n] padded, PAD keys zeroed (bf16x4 along n)
        int4 mv4 = *(const int4*)&mask[b*N_ + n0 + wave*16 + quad*4];
        const int* mv = (const int*)&mv4;
        const int nloc = wave*16 + quad*4;
        #pragma unroll
        for (int j = 0; j < 16; ++j) {
            bf16x4 pk;
            #pragma unroll
            for (int r = 0; r < 4; ++r)
                pk[r] = mv[r] ? (bf16)0.0f : (bf16)acc[j][r];
            *(bf16x4*)&sPhi[(j*16 + m16)*PHK_PAD + nloc] = pk;
        }
        asm volatile("s_waitcnt lgkmcnt(0)");   // Phi writes complete
        __builtin_amdgcn_sched_barrier(0);
        __builtin_amdgcn_s_barrier();           // (C) Phi visible

        // ---- kv MFMA: KVt[d][m] += sum_n VT[d][n] * Phi[m][n] ----
        const char* vb = (const char*)&sVT[cur][0];
        #pragma unroll
        for (int kk = 0; kk < 128; kk += 32) {
            bf16x8 av[5], bp[2];
            #pragma unroll
            for (int d = 0; d < 5; ++d) {
                int rowv = d*16 + m16;
                av[d] = *(const bf16x8*)(vb +
                        ((rowv*256 + kk*2 + quad*16) ^ ((rowv & 7) << 4)));
            }
            #pragma unroll
            for (int j = 0; j < 2; ++j)
                bp[j] = *(const bf16x8*)&sPhi[(wm + j*16 + m16)*PHK_PAD + kk + quad*8];
            #pragma unroll
            for (int d = 0; d < 5; ++d)
                #pragma unroll
                for (int j = 0; j < 2; ++j)
                    kvacc[d][j] = __builtin_amdgcn_mfma_f32_16x16x32_bf16(
                        av[d], bp[j], kvacc[d][j], 0, 0, 0);
        }
    }

    #pragma unroll
    for (int d = 0; d < 5; ++d)
        #pragma unroll
        for (int j = 0; j < 2; ++j) {
            int drow = d*16 + quad*4;
            int m = wm + j*16 + m16;
            #pragma unroll
            for (int r = 0; r < 4; ++r)
                atomicAdd(&KVt32[((size_t)bh*VTROWS_ + drow + r)*M_ + m],
                          kvacc[d][j][r]);
        }
}

// ---------------------------------------------------------------------------
// fused_ctx: stage Q + ALL 4 KVb tiles at block start (vmcnt(16) lets feat
// start once Q lands; KVb flight hides under feat); single __syncthreads
// before an uninterrupted ctx GEMM. sQ/sW XOR-swizzled.
// ---------------------------------------------------------------------------
__global__ __launch_bounds__(256)
void fused_ctx(const f16* __restrict__ Qh, const f16* __restrict__ omhi,
               const f16* __restrict__ omlo, const bf16* __restrict__ KVb,
               bf16* __restrict__ ctx)
{
    __shared__ __align__(16) f16  sQ[128*64];          // 16 KB
    __shared__ __align__(16) bf16 sW[4][128*64];       // 64 KB
    __shared__ __align__(16) bf16 sPhi[128*PHQ_PAD];   // 67.6 KB [n][m] pad 264
    __shared__ float sden[2][128];
    const int nblk = blockIdx.x, h = blockIdx.y, b = blockIdx.z;
    const int bh = b*H_ + h;
    const int tid = threadIdx.x, lane = tid & 63, wave = tid >> 6;
    const int m16 = lane & 15, quad = lane >> 4;
    const float inv_sqrt_m = rsqrtf((float)M_ + 1e-6f);
    const f16* omh = omhi + (size_t)h * M_ * DK_;
    const f16* oml = omlo + (size_t)h * M_ * DK_;

    #pragma unroll
    for (int it = 0; it < 4; ++it) {     // Q slab 128x64 f16 (swizzled src)
        int idx = it*256 + tid;
        int row = idx >> 3, seg = (idx & 7) ^ (row & 7);
        GLD(Qh + (size_t)(b*N_ + nblk*128 + row) * D_ + h*DK_ + seg*8, &sQ[idx*8]);
    }
    #pragma unroll
    for (int t = 0; t < 4; ++t)          // all KVb tiles 128x64 bf16
        #pragma unroll
        for (int it = 0; it < 4; ++it) {
            int idx = it*256 + tid;
            int row = idx >> 3, seg = (idx & 7) ^ (row & 7);
            GLD(KVb + ((size_t)bh*KVROWS_ + row)*M_ + t*64 + seg*8, &sW[t][idx*8]);
        }
    asm volatile("s_waitcnt vmcnt(16)"); // Q landed; KVb still in flight
    __builtin_amdgcn_sched_barrier(0);
    __builtin_amdgcn_s_barrier();

    // ---- feat (wave owns 32 n-rows) ----
    {
        f16x8 ah[2][2];
        #pragma unroll
        for (int i = 0; i < 2; ++i)
            #pragma unroll
            for (int k = 0; k < 2; ++k) {
                int row = wave*32 + i*16 + m16;
                ah[i][k] = *(const f16x8*)((const char*)sQ +
                           ((row*128 + k*64 + quad*16) ^ ((row & 7) << 4)));
            }

        f32x4 acc[2][16];
        #pragma unroll
        for (int i = 0; i < 2; ++i)
            #pragma unroll
            for (int j = 0; j < 16; ++j)
                acc[i][j] = (f32x4){0.f, 0.f, 0.f, 0.f};

        #pragma unroll
        for (int j = 0; j < 16; ++j) {
            size_t ro = (size_t)(j*16 + m16) * DK_ + quad*8;
            f16x8 bh0 = *(const f16x8*)&omh[ro];
            f16x8 bh1 = *(const f16x8*)&omh[ro + 32];
            f16x8 bl0 = *(const f16x8*)&oml[ro];
            f16x8 bl1 = *(const f16x8*)&oml[ro + 32];
            #pragma unroll
            for (int i = 0; i < 2; ++i) {
                acc[i][j] = __builtin_amdgcn_mfma_f32_16x16x32_f16(ah[i][0], bh0, acc[i][j], 0,0,0);
                acc[i][j] = __builtin_amdgcn_mfma_f32_16x16x32_f16(ah[i][0], bl0, acc[i][j], 0,0,0);
                acc[i][j] = __builtin_amdgcn_mfma_f32_16x16x32_f16(ah[i][1], bh1, acc[i][j], 0,0,0);
                acc[i][j] = __builtin_amdgcn_mfma_f32_16x16x32_f16(ah[i][1], bl1, acc[i][j], 0,0,0);
            }
        }
        #pragma unroll
        for (int i = 0; i < 2; ++i)
            #pragma unroll
            for (int r = 0; r < 4; ++r) {
                float mx = acc[i][0][r];
                #pragma unroll
                for (int j = 1; j < 16; ++j) mx = fmaxf(mx, acc[i][j][r]);
                mx = fmaxf(mx, __shfl_xor(mx, 1, 64));
                mx = fmaxf(mx, __shfl_xor(mx, 2, 64));
                mx = fmaxf(mx, __shfl_xor(mx, 4, 64));
                mx = fmaxf(mx, __shfl_xor(mx, 8, 64));
                #pragma unroll
                for (int j = 0; j < 16; ++j)
                    acc[i][j][r] = __expf(acc[i][j][r] - mx) * inv_sqrt_m;
            }
        // Phi -> LDS [n][m] padded (scalar b16; pad kills write conflicts)
        #pragma unroll
        for (int i = 0; i < 2; ++i) {
            int nloc0 = wave*32 + i*16 + quad*4;
            #pragma unroll
            for (int j = 0; j < 16; ++j)
                #pragma unroll
                for (int r = 0; r < 4; ++r)
                    sPhi[(nloc0 + r)*PHQ_PAD + j*16 + m16] = (bf16)acc[i][j][r];
        }
    }
    __syncthreads();   // Phi visible; all KVb landed (full drain)

    // ---- ctx GEMM: A = Phi (LDS), W = sW (all resident) — no inner barriers
    const int wm = (wave & 1) * 64, wn = (wave >> 1) * 64;
    f32x4 cacc[4][4];
    #pragma unroll
    for (int i = 0; i < 4; ++i)
        #pragma unroll
        for (int j = 0; j < 4; ++j)
            cacc[i][j] = (f32x4){0.f, 0.f, 0.f, 0.f};

    #pragma unroll
    for (int t = 0; t < 4; ++t) {
        #pragma unroll
        for (int kk = 0; kk < 64; kk += 32) {
            bf16x8 af[4], wf[4];
            #pragma unroll
            for (int i = 0; i < 4; ++i)
                af[i] = *(const bf16x8*)&sPhi[(wm + i*16 + m16)*PHQ_PAD + t*64 + kk + quad*8];
            #pragma unroll
            for (int j = 0; j < 4; ++j) {
                int row = wn + j*16 + m16;
                wf[j] = *(const bf16x8*)((const char*)sW + t*16384 +
                        ((row*128 + kk*2 + quad*16) ^ ((row & 7) << 4)));
            }
            #pragma unroll
            for (int i = 0; i < 4; ++i)
                #pragma unroll
                for (int j = 0; j < 4; ++j)
                    cacc[i][j] = __builtin_amdgcn_mfma_f32_16x16x32_bf16(
                        af[i], wf[j], cacc[i][j], 0, 0, 0);
        }
    }

    if (wn == 64 && m16 < 2) {
        #pragma unroll
        for (int i = 0; i < 4; ++i)
            #pragma unroll
            for (int r = 0; r < 4; ++r)
                sden[m16][wm + i*16 + quad*4 + r] = cacc[i][0][r];
    }
    __syncthreads();
    if (wn == 0) {
        #pragma unroll
        for (int i = 0; i < 4; ++i) {
            int lrow0 = wm + i*16 + quad*4;
            #pragma unroll
            for (int r = 0; r < 4; ++r) {
                int lrow = lrow0 + r;
                int n = nblk*128 + lrow;
                float den = sden[0][lrow] + sden[1][lrow] + EPS_;
                #pragma unroll
                for (int j = 0; j < 4; ++j)
                    ctx[(size_t)(b*N_ + n)*D_ + h*DK_ + j*16 + m16] =
                        (bf16)(cacc[i][j][r] / den);
            }
        }
    }
}

// ---------------------------------------------------------------------------
// Output projection: out = mask ? 0 : ctx @ Wout^T + bout   (bf16 MFMA, fp32 out)
// ---------------------------------------------------------------------------
__global__ __launch_bounds__(256)
void gemm_out(const bf16* __restrict__ A, const bf16* __restrict__ W,
              const float* __restrict__ bias, float* __restrict__ C,
              const int* __restrict__ mask)
{
    __shared__ bf16 sA[128*64];
    __shared__ bf16 sB[128*64];
    const int tid  = threadIdx.x;
    const int bm   = blockIdx.y * 128;
    const int bn   = blockIdx.x * 128;
    const int lane = tid & 63, wave = tid >> 6;
    const int wm   = (wave & 1) * 64, wn = (wave >> 1) * 64;
    const int m16  = lane & 15, quad = lane >> 4;

    f32x4 acc[4][4];
    #pragma unroll
    for (int i = 0; i < 4; ++i)
        #pragma unroll
        for (int j = 0; j < 4; ++j)
            acc[i][j] = (f32x4){0.f, 0.f, 0.f, 0.f};

    for (int k0 = 0; k0 < D_; k0 += 64) {
        __syncthreads();
        #pragma unroll
        for (int it = 0; it < 4; ++it) {
            int idx = it*256 + tid;
            int row = idx >> 3, seg = idx & 7;
            GLD(A + (size_t)(bm + row) * D_ + k0 + seg*8, &sA[idx*8]);
            GLD(W + (size_t)(bn + row) * D_ + k0 + seg*8, &sB[idx*8]);
        }
        __syncthreads();
        #pragma unroll
        for (int kk = 0; kk < 64; kk += 32) {
            bf16x8 af[4], bfr[4];
            #pragma unroll
            for (int i = 0; i < 4; ++i)
                af[i] = *(const bf16x8*)&sA[(wm + i*16 + m16)*64 + kk + quad*8];
            #pragma unroll
            for (int j = 0; j < 4; ++j)
                bfr[j] = *(const bf16x8*)&sB[(wn + j*16 + m16)*64 + kk + quad*8];
            #pragma unroll
            for (int i = 0; i < 4; ++i)
                #pragma unroll
                for (int j = 0; j < 4; ++j)
                    acc[i][j] = __builtin_amdgcn_mfma_f32_16x16x32_bf16(
                        af[i], bfr[j], acc[i][j], 0, 0, 0);
        }
    }

    #pragma unroll
    for (int j = 0; j < 4; ++j) {
        int col = bn + wn + j*16 + m16;
        float bv = bias[col];
        #pragma unroll
        for (int i = 0; i < 4; ++i) {
            int row0 = bm + wm + i*16 + quad*4;
            #pragma unroll
            for (int r = 0; r < 4; ++r) {
                int row = row0 + r;
                float v = acc[i][j][r] + bv;
                if (mask[row] != 0) v = 0.0f;
                C[(size_t)row * D_ + col] = v;
            }
        }
    }
}

// ---------------------------------------------------------------------------
extern "C" void kernel_launch(void* const* d_in, const int* in_sizes, int n_in,
                              void* d_out, int out_size, void* d_ws, size_t ws_size,
                              hipStream_t stream)
{
    const float* x     = (const float*)d_in[0];
    const int*   mask  = (const int*)d_in[1];     // 1 = PAD
    const float* Wqkv  = (const float*)d_in[2];
    const float* bqkv  = (const float*)d_in[3];
    const float* Wout  = (const float*)d_in[4];
    const float* bout  = (const float*)d_in[5];
    const float* omega = (const float*)d_in[6];
    float* out = (float*)d_out;

    char* w = (char*)d_ws;
    f16*   Wh    = (f16*)w;    w += (size_t)3*D_*D_ * 2;              //   6.29 MB
    bf16*  Wob   = (bf16*)w;   w += (size_t)D_*D_ * 2;                //   2.10 MB
    f16*   omhi  = (f16*)w;    w += (size_t)H_*M_*DK_ * 2;            //   0.52 MB
    f16*   omlo  = (f16*)w;    w += (size_t)H_*M_*DK_ * 2;            //   0.52 MB
    f16*   xh    = (f16*)w;    w += (size_t)R_ * D_ * 2;              //  33.55 MB
    f16*   Qh    = (f16*)w;    w += (size_t)R_ * D_ * 2;              //  33.55 MB
    f16*   Kh    = (f16*)w;    w += (size_t)R_ * D_ * 2;              //  33.55 MB (-> ctx)
    bf16*  VT    = (bf16*)w;   w += (size_t)B_*H_*VTROWS_*N_ * 2;     //  41.94 MB
    float* KVt32 = (float*)w;  w += (size_t)B_*H_*VTROWS_*M_ * 4;     //   5.24 MB
    bf16*  KVb   = (bf16*)w;   w += (size_t)B_*H_*KVROWS_*M_ * 2;     //   4.19 MB
    bf16*  VC    = (bf16*)Kh;                                         // alias (Kh dead after fused_kv)

    // 0) prep
    split_f16v<<<(R_*D_/4 + 255)/256, 256, 0, stream>>>(x, xh, nullptr, R_*D_/4);
    split_f16v<<<(3*D_*D_/4 + 255)/256, 256, 0, stream>>>(Wqkv, Wh, nullptr, 3*D_*D_/4);
    split_f16v<<<(H_*M_*DK_/4 + 255)/256, 256, 0, stream>>>(omega, omhi, omlo, H_*M_*DK_/4);
    f32_to_bf16v<<<(D_*D_/4 + 255)/256, 256, 0, stream>>>(Wout, Wob, D_*D_/4);
    zero_f32<<<(B_*H_*VTROWS_*M_ + 255)/256, 256, 0, stream>>>(KVt32, B_*H_*VTROWS_*M_);
    init_vt<<<(B_*H_*16*N_ + 255)/256, 256, 0, stream>>>(VT);

    // 1) unified QKV projection (fp16, 256^2 8-phase): Qh, Kh fp16; V -> VT bf16
    gemm_qkv<<<dim3(3*D_/256, R_/256), 512, 0, stream>>>(xh, Wh, bqkv, Qh, Kh, VT);

    // 2) fused K-features + KV/ksum accumulation (Phi_K in LDS only)
    fused_kv<<<dim3(4, H_, B_), 512, 0, stream>>>(Kh, VT, omhi, omlo, mask, KVt32);

    // 3) pack KVt32 -> KVb bf16 (ksum hi/lo rows 64/65, zero pad to 128)
    pack_kv<<<(B_*H_*KVROWS_*M_ + 255)/256, 256, 0, stream>>>(KVt32, KVb);

    // 4) fused Q-features + ctx (Phi_Q in LDS only) -> VC bf16 (aliases Kh)
    fused_ctx<<<dim3(N_/128, H_, B_), 256, 0, stream>>>(Qh, omhi, omlo, KVb, VC);

    // 5) output projection + bias + PAD-query zeroing -> fp32 out
    gemm_out<<<dim3(8, R_/128), 256, 0, stream>>>(VC, Wob, bout, out, mask);
}

// Round 3
// 647.470 us; speedup vs baseline: 1.0001x; 1.0001x over previous
//
#include <hip/hip_runtime.h>
#include <hip/hip_bf16.h>
#include <math.h>

#define B_  4
#define N_  4096
#define D_  1024
#define H_  16
#define DK_ 64
#define M_  256
#define R_  (B_*N_)          // 16384 rows
#define EPS_ 1e-6f
#define VTROWS_ 80           // 64 V rows + row64=ones(ksum) + 65..79 pad
#define KVROWS_ 128          // KVb bf16: 64 KV + 64=ksum_hi + 65=ksum_lo + 0-pad
#define PHK_PAD 136          // fused_kv  Phi LDS [m][136]
#define PHQ_PAD 264          // fused_ctx Phi LDS [n][264]

typedef __bf16 bf16;
typedef __bf16 bf16x4 __attribute__((ext_vector_type(4)));
typedef __bf16 bf16x8 __attribute__((ext_vector_type(8)));
typedef _Float16 f16;
typedef _Float16 f16x4 __attribute__((ext_vector_type(4)));
typedef _Float16 f16x8 __attribute__((ext_vector_type(8)));
typedef float  f32x4  __attribute__((ext_vector_type(4)));

#define GLD(gp, lp) __builtin_amdgcn_global_load_lds( \
    (const __attribute__((address_space(1))) void*)(gp), \
    (__attribute__((address_space(3))) void*)(lp), 16, 0, 0)

// ---------------------------------------------------------------------------
// prep kernels
// ---------------------------------------------------------------------------
__global__ __launch_bounds__(256)
void split_f16v(const float* __restrict__ in, f16* __restrict__ hi,
                f16* __restrict__ lo, int n4)
{
    int i = blockIdx.x * 256 + threadIdx.x;
    if (i < n4) {
        float4 v = ((const float4*)in)[i];
        f16x4 h = { (f16)v.x, (f16)v.y, (f16)v.z, (f16)v.w };
        ((f16x4*)hi)[i] = h;
        if (lo) {
            f16x4 l = { (f16)(v.x - (float)h[0]), (f16)(v.y - (float)h[1]),
                        (f16)(v.z - (float)h[2]), (f16)(v.w - (float)h[3]) };
            ((f16x4*)lo)[i] = l;
        }
    }
}

__global__ __launch_bounds__(256)
void f32_to_bf16v(const float* __restrict__ in, bf16* __restrict__ o, int n4)
{
    int i = blockIdx.x * 256 + threadIdx.x;
    if (i < n4) {
        float4 v = ((const float4*)in)[i];
        bf16x4 h = { (bf16)v.x, (bf16)v.y, (bf16)v.z, (bf16)v.w };
        ((bf16x4*)o)[i] = h;
    }
}

__global__ __launch_bounds__(256)
void zero_f32(float* __restrict__ p, int n)
{
    int i = blockIdx.x * 256 + threadIdx.x;
    if (i < n) p[i] = 0.f;
}

__global__ __launch_bounds__(256)
void init_vt(bf16* __restrict__ VT)
{
    int i = blockIdx.x * 256 + threadIdx.x;          // 64bh x 16rows x 4096
    if (i >= B_*H_*16*N_) return;
    int bh  = i >> 16;
    int rem = i & 65535;
    int row = 64 + (rem >> 12);
    int n   = rem & (N_-1);
    VT[((size_t)bh*VTROWS_ + row)*N_ + n] = (row == 64) ? (bf16)1.0f : (bf16)0.0f;
}

__global__ __launch_bounds__(256)
void pack_kv(const float* __restrict__ KVt32, bf16* __restrict__ KVb)
{
    int i = blockIdx.x * 256 + threadIdx.x;          // 64bh x 128 x 256
    if (i >= B_*H_*KVROWS_*M_) return;
    int bh  = i >> 15;
    int rem = i & 32767;
    int row = rem >> 8;
    int m   = rem & (M_-1);
    bf16 o = (bf16)0.0f;
    if (row < 64) {
        o = (bf16)KVt32[((size_t)bh*VTROWS_ + row)*M_ + m];
    } else if (row == 64) {
        o = (bf16)KVt32[((size_t)bh*VTROWS_ + 64)*M_ + m];
    } else if (row == 65) {
        float v = KVt32[((size_t)bh*VTROWS_ + 64)*M_ + m];
        o = (bf16)(v - (float)(bf16)v);
    }
    KVb[i] = o;
}

// ---------------------------------------------------------------------------
// Unified QKV projection — 256x256 tile, BK=64, 8 waves, 8-phase counted-vmcnt.
// launch_bounds(512) — NOT (512,2): the ,2 capped VGPR at 128 and spilled the
// 128-VGPR accumulator to scratch (round-1/2 regression root cause).
// ---------------------------------------------------------------------------

#define STAGE_(dstbuf, srcp, kt, half) do { \
    _Pragma("unroll") \
    for (int q_ = 0; q_ < 2; ++q_) { \
        int idx_ = q_*512 + tid; \
        int row_ = idx_ >> 3; \
        int seg_ = (idx_ & 7) ^ (row_ & 7); \
        GLD((srcp) + (size_t)((half)*128 + row_) * D_ + (kt)*64 + seg_*8, \
            &(dstbuf)[(half)*8192 + idx_*8]); \
    } } while (0)

#define LDA_(buf, i0) do { \
    _Pragma("unroll") \
    for (int i_ = 0; i_ < 4; ++i_) { \
        _Pragma("unroll") \
        for (int k_ = 0; k_ < 2; ++k_) { \
            int row_ = warp_m*128 + ((i0)+i_)*16 + m16; \
            int off_ = (row_*128 + k_*64 + quad*16) ^ ((row_ & 7) << 4); \
            a[i_][k_] = *(const f16x8*)((const char*)(buf) + off_); \
        } } } while (0)

#define LDB_(buf, j0) do { \
    _Pragma("unroll") \
    for (int j_ = 0; j_ < 2; ++j_) { \
        _Pragma("unroll") \
        for (int k_ = 0; k_ < 2; ++k_) { \
            int row_ = warp_n*64 + ((j0)+j_)*16 + m16; \
            int off_ = (row_*128 + k_*64 + quad*16) ^ ((row_ & 7) << 4); \
            b[(j0)+j_][k_] = *(const f16x8*)((const char*)(buf) + off_); \
        } } } while (0)

#define MFMA_Q(I0, J0) do { \
    _Pragma("unroll") \
    for (int i_ = 0; i_ < 4; ++i_) { \
        _Pragma("unroll") \
        for (int j_ = 0; j_ < 2; ++j_) { \
            _Pragma("unroll") \
            for (int k_ = 0; k_ < 2; ++k_) \
                acc[(I0)+i_][(J0)+j_] = __builtin_amdgcn_mfma_f32_16x16x32_f16( \
                    a[i_][k_], b[(J0)+j_][k_], acc[(I0)+i_][(J0)+j_], 0, 0, 0); \
        } } } while (0)

#define BAR_()   __builtin_amdgcn_s_barrier()
#define LGK0_()  do { asm volatile("s_waitcnt lgkmcnt(0)"); \
                      __builtin_amdgcn_sched_barrier(0); } while (0)
#define LGK8_()  asm volatile("s_waitcnt lgkmcnt(8)")
#define VMC4_()  do { asm volatile("s_waitcnt vmcnt(4)"); \
                      __builtin_amdgcn_sched_barrier(0); } while (0)
#define PRIO1_() __builtin_amdgcn_s_setprio(1)
#define PRIO0_() __builtin_amdgcn_s_setprio(0)

__global__ __launch_bounds__(512)
void gemm_qkv(const f16* __restrict__ X, const f16* __restrict__ Wh,
              const float* __restrict__ bqkv,
              f16* __restrict__ Qh, f16* __restrict__ Kh, bf16* __restrict__ VT)
{
    __shared__ __align__(16) f16 sA[2][256*64];   // 64 KB
    __shared__ __align__(16) f16 sB[2][256*64];   // 64 KB
    const int tid = threadIdx.x;

    // T1: bijective XCD swizzle (nwg = 768, 768 % 8 == 0)
    const int nwg  = gridDim.x * gridDim.y;
    int flat = blockIdx.y * gridDim.x + blockIdx.x;
    int wgid = (flat & 7) * (nwg >> 3) + (flat >> 3);
    const int bm = (wgid / 12) * 256;
    const int bn = (wgid % 12) * 256;

    const int lane = tid & 63, wave = tid >> 6;
    const int warp_m = wave >> 2, warp_n = wave & 3;   // 2 x 4 waves
    const int m16 = lane & 15, quad = lane >> 4;

    const f16* gA = X  + (size_t)bm * D_;
    const f16* gB = Wh + (size_t)bn * D_;

    f32x4 acc[8][4];
    #pragma unroll
    for (int i = 0; i < 8; ++i)
        #pragma unroll
        for (int j = 0; j < 4; ++j)
            acc[i][j] = (f32x4){0.f, 0.f, 0.f, 0.f};

    f16x8 a[4][2], b[4][2];

    // prologue: tile0 A+B -> P0, tile1 B -> P1 (12 loads); vmcnt(4) leaves
    // only P1.B possibly outstanding -> P0 fully landed before ph1 reads.
    STAGE_(sA[0], gA, 0, 0);
    STAGE_(sA[0], gA, 0, 1);
    STAGE_(sB[0], gB, 0, 0);
    STAGE_(sB[0], gB, 0, 1);
    STAGE_(sB[1], gB, 1, 0);
    STAGE_(sB[1], gB, 1, 1);
    VMC4_();
    BAR_();

    for (int it = 0; it < 8; ++it) {
        const int t1 = 2*it + 1, t2 = 2*it + 2, t3 = 2*it + 3;
        // ---------- K-tile t0 from P0 ----------
        LDA_(sA[0], 0); LDB_(sB[0], 0);
        STAGE_(sA[1], gA, t1, 0);
        LGK8_();
        BAR_(); LGK0_();
        PRIO1_(); MFMA_Q(0, 0); PRIO0_();
        BAR_();

        LDB_(sB[0], 2);
        STAGE_(sA[1], gA, t1, 1);
        BAR_(); LGK0_();
        PRIO1_(); MFMA_Q(0, 2); PRIO0_();
        BAR_();

        LDA_(sA[0], 4);
        if (t2 < 16) STAGE_(sB[0], gB, t2, 0);
        BAR_(); LGK0_();
        PRIO1_(); MFMA_Q(4, 2); PRIO0_();
        BAR_();

        if (t2 < 16) STAGE_(sB[0], gB, t2, 1);
        VMC4_();
        BAR_();
        PRIO1_(); MFMA_Q(4, 0); PRIO0_();
        BAR_();

        // ---------- K-tile t1 from P1 ----------
        LDA_(sA[1], 0); LDB_(sB[1], 0);
        if (t2 < 16) STAGE_(sA[0], gA, t2, 0);
        LGK8_();
        BAR_(); LGK0_();
        PRIO1_(); MFMA_Q(0, 0); PRIO0_();
        BAR_();

        LDB_(sB[1], 2);
        if (t2 < 16) STAGE_(sA[0], gA, t2, 1);
        BAR_(); LGK0_();
        PRIO1_(); MFMA_Q(0, 2); PRIO0_();
        BAR_();

        LDA_(sA[1], 4);
        if (t3 < 16) STAGE_(sB[1], gB, t3, 0);
        BAR_(); LGK0_();
        PRIO1_(); MFMA_Q(4, 2); PRIO0_();
        BAR_();

        if (t3 < 16) STAGE_(sB[1], gB, t3, 1);
        VMC4_();
        BAR_();
        PRIO1_(); MFMA_Q(4, 0); PRIO0_();
        BAR_();
    }

    // epilogue: scatter Q / K / V (+bias). 256-col tiles never straddle the
    // Q/K/V boundaries (1024 % 256 == 0).
    #pragma unroll
    for (int j = 0; j < 4; ++j) {
        int gcol = bn + warp_n*64 + j*16 + m16;
        float bv = bqkv[gcol];
        #pragma unroll
        for (int i = 0; i < 8; ++i) {
            int row0 = bm + warp_m*128 + i*16 + quad*4;
            if (gcol >= 2*D_) {
                int vcol = gcol - 2*D_;
                int hh = vcol >> 6, dd = vcol & 63;
                int bb = row0 >> 12, nn = row0 & (N_-1);
                bf16x4 pk = { (bf16)(acc[i][j][0]+bv), (bf16)(acc[i][j][1]+bv),
                              (bf16)(acc[i][j][2]+bv), (bf16)(acc[i][j][3]+bv) };
                *(bf16x4*)&VT[(((size_t)bb*H_+hh)*VTROWS_ + dd)*N_ + nn] = pk;
            } else if (gcol >= D_) {
                #pragma unroll
                for (int r = 0; r < 4; ++r)
                    Kh[(size_t)(row0+r) * D_ + gcol - D_] = (f16)(acc[i][j][r] + bv);
            } else {
                #pragma unroll
                for (int r = 0; r < 4; ++r)
                    Qh[(size_t)(row0+r) * D_ + gcol] = (f16)(acc[i][j][r] + bv);
            }
        }
    }
}

// ---------------------------------------------------------------------------
// fused_kv: 512 threads (8 waves), double-buffered sK/sVT, stage for subtile
// t+1 issued mid-compute of subtile t. launch_bounds(512) — the ,2 variant
// capped VGPR at 128 and spilled acc+kvacc (round-2 regression).
// ---------------------------------------------------------------------------
#define STAGEKV_(sub_, bi_) do { \
    const int n0_ = nsp*1024 + (sub_)*128; \
    _Pragma("unroll") \
    for (int it_ = 0; it_ < 2; ++it_) { \
        int idx_ = it_*512 + tid; \
        int row_ = idx_ >> 3, seg_ = (idx_ & 7) ^ (row_ & 7); \
        GLD(Kh + (size_t)(b*N_ + n0_ + row_) * D_ + h*DK_ + seg_*8, \
            &sK[bi_][idx_*8]); \
    } \
    _Pragma("unroll") \
    for (int it_ = 0; it_ < 2; ++it_) { \
        int idx_ = it_*512 + tid; \
        int row_ = idx_ >> 4, seg_ = (idx_ & 15) ^ (row_ & 7); \
        GLD(VT + ((size_t)bh*VTROWS_ + row_)*N_ + n0_ + seg_*8, \
            &sVT[bi_][idx_*8]); \
    } \
    if (tid < 256) { \
        int idx_ = 1024 + tid; \
        int row_ = idx_ >> 4, seg_ = (idx_ & 15) ^ (row_ & 7); \
        GLD(VT + ((size_t)bh*VTROWS_ + row_)*N_ + n0_ + seg_*8, \
            &sVT[bi_][idx_*8]); \
    } } while (0)

__global__ __launch_bounds__(512)
void fused_kv(const f16* __restrict__ Kh, const bf16* __restrict__ VT,
              const f16* __restrict__ omhi, const f16* __restrict__ omlo,
              const int* __restrict__ mask, float* __restrict__ KVt32)
{
    __shared__ __align__(16) f16  sK[2][128*64];      // 32 KB
    __shared__ __align__(16) bf16 sVT[2][VTROWS_*128];// 40 KB
    __shared__ __align__(16) bf16 sPhi[M_*PHK_PAD];   // 68 KB  [m][n] pad 136
    const int nsp = blockIdx.x;          // 0..3
    const int h = blockIdx.y, b = blockIdx.z;
    const int bh = b*H_ + h;
    const int tid = threadIdx.x, lane = tid & 63, wave = tid >> 6;
    const int m16 = lane & 15, quad = lane >> 4;
    const int wm = wave * 32;            // wave's m-range for kv MFMA
    const float inv_sqrt_m = rsqrtf((float)M_ + 1e-6f);
    const f16* omh = omhi + (size_t)h * M_ * DK_;
    const f16* oml = omlo + (size_t)h * M_ * DK_;

    f32x4 kvacc[5][2];
    #pragma unroll
    for (int d = 0; d < 5; ++d)
        #pragma unroll
        for (int j = 0; j < 2; ++j)
            kvacc[d][j] = (f32x4){0.f, 0.f, 0.f, 0.f};

    STAGEKV_(0, 0);

    for (int sub = 0; sub < 8; ++sub) {
        const int cur = sub & 1;
        const int n0 = nsp*1024 + sub*128;

        asm volatile("s_waitcnt vmcnt(0)");     // prev-iter stages (old) landed
        __builtin_amdgcn_sched_barrier(0);
        __builtin_amdgcn_s_barrier();           // (B) all waves' stages landed;
                                                //     prev readers of other buf done
        // ---- feat: proj = K . omega^T (wave owns 16 n-rows) ----
        const char* kb = (const char*)&sK[cur][0];
        const int rowb = wave*16 + m16;
        f16x8 ah0 = *(const f16x8*)(kb + ((rowb*128 +      quad*16) ^ ((rowb & 7) << 4)));
        f16x8 ah1 = *(const f16x8*)(kb + ((rowb*128 + 64 + quad*16) ^ ((rowb & 7) << 4)));

        f32x4 acc[16];
        #pragma unroll
        for (int j = 0; j < 16; ++j) acc[j] = (f32x4){0.f, 0.f, 0.f, 0.f};

        #pragma unroll
        for (int j = 0; j < 16; ++j) {
            size_t ro = (size_t)(j*16 + m16) * DK_ + quad*8;
            f16x8 bh0 = *(const f16x8*)&omh[ro];
            f16x8 bh1 = *(const f16x8*)&omh[ro + 32];
            f16x8 bl0 = *(const f16x8*)&oml[ro];
            f16x8 bl1 = *(const f16x8*)&oml[ro + 32];
            acc[j] = __builtin_amdgcn_mfma_f32_16x16x32_f16(ah0, bh0, acc[j], 0,0,0);
            acc[j] = __builtin_amdgcn_mfma_f32_16x16x32_f16(ah0, bl0, acc[j], 0,0,0);
            acc[j] = __builtin_amdgcn_mfma_f32_16x16x32_f16(ah1, bh1, acc[j], 0,0,0);
            acc[j] = __builtin_amdgcn_mfma_f32_16x16x32_f16(ah1, bl1, acc[j], 0,0,0);
        }

        // issue next subtile's stage AFTER the om loads (so compiler's om
        // waitcnts don't force the fresh stage to land); flight hides under
        // softmax + Phi write + kv MFMA.
        if (sub < 7) STAGEKV_(sub+1, cur^1);

        // rowmax + exp
        #pragma unroll
        for (int r = 0; r < 4; ++r) {
            float mx = acc[0][r];
            #pragma unroll
            for (int j = 1; j < 16; ++j) mx = fmaxf(mx, acc[j][r]);
            mx = fmaxf(mx, __shfl_xor(mx, 1, 64));
            mx = fmaxf(mx, __shfl_xor(mx, 2, 64));
            mx = fmaxf(mx, __shfl_xor(mx, 4, 64));
            mx = fmaxf(mx, __shfl_xor(mx, 8, 64));
            #pragma unroll
            for (int j = 0; j < 16; ++j)
                acc[j][r] = __expf(acc[j][r] - mx) * inv_sqrt_m;
        }

        // Phi -> LDS [m][n] padded, PAD keys zeroed (bf16x4 along n)
        int4 mv4 = *(const int4*)&mask[b*N_ + n0 + wave*16 + quad*4];
        const int* mv = (const int*)&mv4;
        const int nloc = wave*16 + quad*4;
        #pragma unroll
        for (int j = 0; j < 16; ++j) {
            bf16x4 pk;
            #pragma unroll
            for (int r = 0; r < 4; ++r)
                pk[r] = mv[r] ? (bf16)0.0f : (bf16)acc[j][r];
            *(bf16x4*)&sPhi[(j*16 + m16)*PHK_PAD + nloc] = pk;
        }
        asm volatile("s_waitcnt lgkmcnt(0)");   // Phi writes complete
        __builtin_amdgcn_sched_barrier(0);
        __builtin_amdgcn_s_barrier();           // (C) Phi visible

        // ---- kv MFMA: KVt[d][m] += sum_n VT[d][n] * Phi[m][n] ----
        const char* vb = (const char*)&sVT[cur][0];
        #pragma unroll
        for (int kk = 0; kk < 128; kk += 32) {
            bf16x8 av[5], bp[2];
            #pragma unroll
            for (int d = 0; d < 5; ++d) {
                int rowv = d*16 + m16;
                av[d] = *(const bf16x8*)(vb +
                        ((rowv*256 + kk*2 + quad*16) ^ ((rowv & 7) << 4)));
            }
            #pragma unroll
            for (int j = 0; j < 2; ++j)
                bp[j] = *(const bf16x8*)&sPhi[(wm + j*16 + m16)*PHK_PAD + kk + quad*8];
            #pragma unroll
            for (int d = 0; d < 5; ++d)
                #pragma unroll
                for (int j = 0; j < 2; ++j)
                    kvacc[d][j] = __builtin_amdgcn_mfma_f32_16x16x32_bf16(
                        av[d], bp[j], kvacc[d][j], 0, 0, 0);
        }
    }

    #pragma unroll
    for (int d = 0; d < 5; ++d)
        #pragma unroll
        for (int j = 0; j < 2; ++j) {
            int drow = d*16 + quad*4;
            int m = wm + j*16 + m16;
            #pragma unroll
            for (int r = 0; r < 4; ++r)
                atomicAdd(&KVt32[((size_t)bh*VTROWS_ + drow + r)*M_ + m],
                          kvacc[d][j][r]);
        }
}

// ---------------------------------------------------------------------------
// fused_ctx: stage Q + ALL 4 KVb tiles at block start (vmcnt(16) lets feat
// start once Q lands; KVb flight hides under feat); single __syncthreads
// before an uninterrupted ctx GEMM. sQ/sW XOR-swizzled.
// ---------------------------------------------------------------------------
__global__ __launch_bounds__(256)
void fused_ctx(const f16* __restrict__ Qh, const f16* __restrict__ omhi,
               const f16* __restrict__ omlo, const bf16* __restrict__ KVb,
               bf16* __restrict__ ctx)
{
    __shared__ __align__(16) f16  sQ[128*64];          // 16 KB
    __shared__ __align__(16) bf16 sW[4][128*64];       // 64 KB
    __shared__ __align__(16) bf16 sPhi[128*PHQ_PAD];   // 67.6 KB [n][m] pad 264
    __shared__ float sden[2][128];
    const int nblk = blockIdx.x, h = blockIdx.y, b = blockIdx.z;
    const int bh = b*H_ + h;
    const int tid = threadIdx.x, lane = tid & 63, wave = tid >> 6;
    const int m16 = lane & 15, quad = lane >> 4;
    const float inv_sqrt_m = rsqrtf((float)M_ + 1e-6f);
    const f16* omh = omhi + (size_t)h * M_ * DK_;
    const f16* oml = omlo + (size_t)h * M_ * DK_;

    #pragma unroll
    for (int it = 0; it < 4; ++it) {     // Q slab 128x64 f16 (swizzled src)
        int idx = it*256 + tid;
        int row = idx >> 3, seg = (idx & 7) ^ (row & 7);
        GLD(Qh + (size_t)(b*N_ + nblk*128 + row) * D_ + h*DK_ + seg*8, &sQ[idx*8]);
    }
    #pragma unroll
    for (int t = 0; t < 4; ++t)          // all KVb tiles 128x64 bf16
        #pragma unroll
        for (int it = 0; it < 4; ++it) {
            int idx = it*256 + tid;
            int row = idx >> 3, seg = (idx & 7) ^ (row & 7);
            GLD(KVb + ((size_t)bh*KVROWS_ + row)*M_ + t*64 + seg*8, &sW[t][idx*8]);
        }
    asm volatile("s_waitcnt vmcnt(16)"); // Q landed; KVb still in flight
    __builtin_amdgcn_sched_barrier(0);
    __builtin_amdgcn_s_barrier();

    // ---- feat (wave owns 32 n-rows) ----
    {
        f16x8 ah[2][2];
        #pragma unroll
        for (int i = 0; i < 2; ++i)
            #pragma unroll
            for (int k = 0; k < 2; ++k) {
                int row = wave*32 + i*16 + m16;
                ah[i][k] = *(const f16x8*)((const char*)sQ +
                           ((row*128 + k*64 + quad*16) ^ ((row & 7) << 4)));
            }

        f32x4 acc[2][16];
        #pragma unroll
        for (int i = 0; i < 2; ++i)
            #pragma unroll
            for (int j = 0; j < 16; ++j)
                acc[i][j] = (f32x4){0.f, 0.f, 0.f, 0.f};

        #pragma unroll
        for (int j = 0; j < 16; ++j) {
            size_t ro = (size_t)(j*16 + m16) * DK_ + quad*8;
            f16x8 bh0 = *(const f16x8*)&omh[ro];
            f16x8 bh1 = *(const f16x8*)&omh[ro + 32];
            f16x8 bl0 = *(const f16x8*)&oml[ro];
            f16x8 bl1 = *(const f16x8*)&oml[ro + 32];
            #pragma unroll
            for (int i = 0; i < 2; ++i) {
                acc[i][j] = __builtin_amdgcn_mfma_f32_16x16x32_f16(ah[i][0], bh0, acc[i][j], 0,0,0);
                acc[i][j] = __builtin_amdgcn_mfma_f32_16x16x32_f16(ah[i][0], bl0, acc[i][j], 0,0,0);
                acc[i][j] = __builtin_amdgcn_mfma_f32_16x16x32_f16(ah[i][1], bh1, acc[i][j], 0,0,0);
                acc[i][j] = __builtin_amdgcn_mfma_f32_16x16x32_f16(ah[i][1], bl1, acc[i][j], 0,0,0);
            }
        }
        #pragma unroll
        for (int i = 0; i < 2; ++i)
            #pragma unroll
            for (int r = 0; r < 4; ++r) {
                float mx = acc[i][0][r];
                #pragma unroll
                for (int j = 1; j < 16; ++j) mx = fmaxf(mx, acc[i][j][r]);
                mx = fmaxf(mx, __shfl_xor(mx, 1, 64));
                mx = fmaxf(mx, __shfl_xor(mx, 2, 64));
                mx = fmaxf(mx, __shfl_xor(mx, 4, 64));
                mx = fmaxf(mx, __shfl_xor(mx, 8, 64));
                #pragma unroll
                for (int j = 0; j < 16; ++j)
                    acc[i][j][r] = __expf(acc[i][j][r] - mx) * inv_sqrt_m;
            }
        // Phi -> LDS [n][m] padded (scalar b16; pad kills write conflicts)
        #pragma unroll
        for (int i = 0; i < 2; ++i) {
            int nloc0 = wave*32 + i*16 + quad*4;
            #pragma unroll
            for (int j = 0; j < 16; ++j)
                #pragma unroll
                for (int r = 0; r < 4; ++r)
                    sPhi[(nloc0 + r)*PHQ_PAD + j*16 + m16] = (bf16)acc[i][j][r];
        }
    }
    __syncthreads();   // Phi visible; all KVb landed (full drain)

    // ---- ctx GEMM: A = Phi (LDS), W = sW (all resident) — no inner barriers
    const int wm = (wave & 1) * 64, wn = (wave >> 1) * 64;
    f32x4 cacc[4][4];
    #pragma unroll
    for (int i = 0; i < 4; ++i)
        #pragma unroll
        for (int j = 0; j < 4; ++j)
            cacc[i][j] = (f32x4){0.f, 0.f, 0.f, 0.f};

    #pragma unroll
    for (int t = 0; t < 4; ++t) {
        #pragma unroll
        for (int kk = 0; kk < 64; kk += 32) {
            bf16x8 af[4], wf[4];
            #pragma unroll
            for (int i = 0; i < 4; ++i)
                af[i] = *(const bf16x8*)&sPhi[(wm + i*16 + m16)*PHQ_PAD + t*64 + kk + quad*8];
            #pragma unroll
            for (int j = 0; j < 4; ++j) {
                int row = wn + j*16 + m16;
                wf[j] = *(const bf16x8*)((const char*)sW + t*16384 +
                        ((row*128 + kk*2 + quad*16) ^ ((row & 7) << 4)));
            }
            #pragma unroll
            for (int i = 0; i < 4; ++i)
                #pragma unroll
                for (int j = 0; j < 4; ++j)
                    cacc[i][j] = __builtin_amdgcn_mfma_f32_16x16x32_bf16(
                        af[i], wf[j], cacc[i][j], 0, 0, 0);
        }
    }

    if (wn == 64 && m16 < 2) {
        #pragma unroll
        for (int i = 0; i < 4; ++i)
            #pragma unroll
            for (int r = 0; r < 4; ++r)
                sden[m16][wm + i*16 + quad*4 + r] = cacc[i][0][r];
    }
    __syncthreads();
    if (wn == 0) {
        #pragma unroll
        for (int i = 0; i < 4; ++i) {
            int lrow0 = wm + i*16 + quad*4;
            #pragma unroll
            for (int r = 0; r < 4; ++r) {
                int lrow = lrow0 + r;
                int n = nblk*128 + lrow;
                float den = sden[0][lrow] + sden[1][lrow] + EPS_;
                #pragma unroll
                for (int j = 0; j < 4; ++j)
                    ctx[(size_t)(b*N_ + n)*D_ + h*DK_ + j*16 + m16] =
                        (bf16)(cacc[i][j][r] / den);
            }
        }
    }
}

// ---------------------------------------------------------------------------
// Output projection: out = mask ? 0 : ctx @ Wout^T + bout   (bf16 MFMA, fp32 out)
// ---------------------------------------------------------------------------
__global__ __launch_bounds__(256)
void gemm_out(const bf16* __restrict__ A, const bf16* __restrict__ W,
              const float* __restrict__ bias, float* __restrict__ C,
              const int* __restrict__ mask)
{
    __shared__ bf16 sA[128*64];
    __shared__ bf16 sB[128*64];
    const int tid  = threadIdx.x;
    const int bm   = blockIdx.y * 128;
    const int bn   = blockIdx.x * 128;
    const int lane = tid & 63, wave = tid >> 6;
    const int wm   = (wave & 1) * 64, wn = (wave >> 1) * 64;
    const int m16  = lane & 15, quad = lane >> 4;

    f32x4 acc[4][4];
    #pragma unroll
    for (int i = 0; i < 4; ++i)
        #pragma unroll
        for (int j = 0; j < 4; ++j)
            acc[i][j] = (f32x4){0.f, 0.f, 0.f, 0.f};

    for (int k0 = 0; k0 < D_; k0 += 64) {
        __syncthreads();
        #pragma unroll
        for (int it = 0; it < 4; ++it) {
            int idx = it*256 + tid;
            int row = idx >> 3, seg = idx & 7;
            GLD(A + (size_t)(bm + row) * D_ + k0 + seg*8, &sA[idx*8]);
            GLD(W + (size_t)(bn + row) * D_ + k0 + seg*8, &sB[idx*8]);
        }
        __syncthreads();
        #pragma unroll
        for (int kk = 0; kk < 64; kk += 32) {
            bf16x8 af[4], bfr[4];
            #pragma unroll
            for (int i = 0; i < 4; ++i)
                af[i] = *(const bf16x8*)&sA[(wm + i*16 + m16)*64 + kk + quad*8];
            #pragma unroll
            for (int j = 0; j < 4; ++j)
                bfr[j] = *(const bf16x8*)&sB[(wn + j*16 + m16)*64 + kk + quad*8];
            #pragma unroll
            for (int i = 0; i < 4; ++i)
                #pragma unroll
                for (int j = 0; j < 4; ++j)
                    acc[i][j] = __builtin_amdgcn_mfma_f32_16x16x32_bf16(
                        af[i], bfr[j], acc[i][j], 0, 0, 0);
        }
    }

    #pragma unroll
    for (int j = 0; j < 4; ++j) {
        int col = bn + wn + j*16 + m16;
        float bv = bias[col];
        #pragma unroll
        for (int i = 0; i < 4; ++i) {
            int row0 = bm + wm + i*16 + quad*4;
            #pragma unroll
            for (int r = 0; r < 4; ++r) {
                int row = row0 + r;
                float v = acc[i][j][r] + bv;
                if (mask[row] != 0) v = 0.0f;
                C[(size_t)row * D_ + col] = v;
            }
        }
    }
}

// ---------------------------------------------------------------------------
extern "C" void kernel_launch(void* const* d_in, const int* in_sizes, int n_in,
                              void* d_out, int out_size, void* d_ws, size_t ws_size,
                              hipStream_t stream)
{
    const float* x     = (const float*)d_in[0];
    const int*   mask  = (const int*)d_in[1];     // 1 = PAD
    const float* Wqkv  = (const float*)d_in[2];
    const float* bqkv  = (const float*)d_in[3];
    const float* Wout  = (const float*)d_in[4];
    const float* bout  = (const float*)d_in[5];
    const float* omega = (const float*)d_in[6];
    float* out = (float*)d_out;

    char* w = (char*)d_ws;
    f16*   Wh    = (f16*)w;    w += (size_t)3*D_*D_ * 2;              //   6.29 MB
    bf16*  Wob   = (bf16*)w;   w += (size_t)D_*D_ * 2;                //   2.10 MB
    f16*   omhi  = (f16*)w;    w += (size_t)H_*M_*DK_ * 2;            //   0.52 MB
    f16*   omlo  = (f16*)w;    w += (size_t)H_*M_*DK_ * 2;            //   0.52 MB
    f16*   xh    = (f16*)w;    w += (size_t)R_ * D_ * 2;              //  33.55 MB
    f16*   Qh    = (f16*)w;    w += (size_t)R_ * D_ * 2;              //  33.55 MB
    f16*   Kh    = (f16*)w;    w += (size_t)R_ * D_ * 2;              //  33.55 MB (-> ctx)
    bf16*  VT    = (bf16*)w;   w += (size_t)B_*H_*VTROWS_*N_ * 2;     //  41.94 MB
    float* KVt32 = (float*)w;  w += (size_t)B_*H_*VTROWS_*M_ * 4;     //   5.24 MB
    bf16*  KVb   = (bf16*)w;   w += (size_t)B_*H_*KVROWS_*M_ * 2;     //   4.19 MB
    bf16*  VC    = (bf16*)Kh;                                         // alias (Kh dead after fused_kv)

    // 0) prep
    split_f16v<<<(R_*D_/4 + 255)/256, 256, 0, stream>>>(x, xh, nullptr, R_*D_/4);
    split_f16v<<<(3*D_*D_/4 + 255)/256, 256, 0, stream>>>(Wqkv, Wh, nullptr, 3*D_*D_/4);
    split_f16v<<<(H_*M_*DK_/4 + 255)/256, 256, 0, stream>>>(omega, omhi, omlo, H_*M_*DK_/4);
    f32_to_bf16v<<<(D_*D_/4 + 255)/256, 256, 0, stream>>>(Wout, Wob, D_*D_/4);
    zero_f32<<<(B_*H_*VTROWS_*M_ + 255)/256, 256, 0, stream>>>(KVt32, B_*H_*VTROWS_*M_);
    init_vt<<<(B_*H_*16*N_ + 255)/256, 256, 0, stream>>>(VT);

    // 1) unified QKV projection (fp16, 256^2 8-phase): Qh, Kh fp16; V -> VT bf16
    gemm_qkv<<<dim3(3*D_/256, R_/256), 512, 0, stream>>>(xh, Wh, bqkv, Qh, Kh, VT);

    // 2) fused K-features + KV/ksum accumulation (Phi_K in LDS only)
    fused_kv<<<dim3(4, H_, B_), 512, 0, stream>>>(Kh, VT, omhi, omlo, mask, KVt32);

    // 3) pack KVt32 -> KVb bf16 (ksum hi/lo rows 64/65, zero pad to 128)
    pack_kv<<<(B_*H_*KVROWS_*M_ + 255)/256, 256, 0, stream>>>(KVt32, KVb);

    // 4) fused Q-features + ctx (Phi_Q in LDS only) -> VC bf16 (aliases Kh)
    fused_ctx<<<dim3(N_/128, H_, B_), 256, 0, stream>>>(Qh, omhi, omlo, KVb, VC);

    // 5) output projection + bias + PAD-query zeroing -> fp32 out
    gemm_out<<<dim3(8, R_/128), 256, 0, stream>>>(VC, Wob, bout, out, mask);
}

// Round 4
// 645.790 us; speedup vs baseline: 1.0027x; 1.0026x over previous
//
#include <hip/hip_runtime.h>
#include <hip/hip_bf16.h>
#include <math.h>

#define B_  4
#define N_  4096
#define D_  1024
#define H_  16
#define DK_ 64
#define M_  256
#define R_  (B_*N_)          // 16384 rows
#define EPS_ 1e-6f
#define VTROWS_ 80           // 64 V rows + row64=ones(ksum) + 65..79 pad
#define KVROWS_ 128          // KVb bf16: 64 KV + 64=ksum_hi + 65=ksum_lo + 0-pad
#define PHK_PAD 136          // fused_kv  Phi LDS [m][136]
#define PHQ_PAD 264          // fused_ctx Phi LDS [n][264]

typedef __bf16 bf16;
typedef __bf16 bf16x4 __attribute__((ext_vector_type(4)));
typedef __bf16 bf16x8 __attribute__((ext_vector_type(8)));
typedef _Float16 f16;
typedef _Float16 f16x4 __attribute__((ext_vector_type(4)));
typedef _Float16 f16x8 __attribute__((ext_vector_type(8)));
typedef float  f32x4  __attribute__((ext_vector_type(4)));

#define GLD(gp, lp) __builtin_amdgcn_global_load_lds( \
    (const __attribute__((address_space(1))) void*)(gp), \
    (__attribute__((address_space(3))) void*)(lp), 16, 0, 0)

// ---------------------------------------------------------------------------
// prep kernels
// ---------------------------------------------------------------------------
__global__ __launch_bounds__(256)
void split_f16v(const float* __restrict__ in, f16* __restrict__ hi,
                f16* __restrict__ lo, int n4)
{
    int i = blockIdx.x * 256 + threadIdx.x;
    if (i < n4) {
        float4 v = ((const float4*)in)[i];
        f16x4 h = { (f16)v.x, (f16)v.y, (f16)v.z, (f16)v.w };
        ((f16x4*)hi)[i] = h;
        if (lo) {
            f16x4 l = { (f16)(v.x - (float)h[0]), (f16)(v.y - (float)h[1]),
                        (f16)(v.z - (float)h[2]), (f16)(v.w - (float)h[3]) };
            ((f16x4*)lo)[i] = l;
        }
    }
}

__global__ __launch_bounds__(256)
void f32_to_bf16v(const float* __restrict__ in, bf16* __restrict__ o, int n4)
{
    int i = blockIdx.x * 256 + threadIdx.x;
    if (i < n4) {
        float4 v = ((const float4*)in)[i];
        bf16x4 h = { (bf16)v.x, (bf16)v.y, (bf16)v.z, (bf16)v.w };
        ((bf16x4*)o)[i] = h;
    }
}

__global__ __launch_bounds__(256)
void zero_f32(float* __restrict__ p, int n)
{
    int i = blockIdx.x * 256 + threadIdx.x;
    if (i < n) p[i] = 0.f;
}

__global__ __launch_bounds__(256)
void init_vt(bf16* __restrict__ VT)
{
    int i = blockIdx.x * 256 + threadIdx.x;          // 64bh x 16rows x 4096
    if (i >= B_*H_*16*N_) return;
    int bh  = i >> 16;
    int rem = i & 65535;
    int row = 64 + (rem >> 12);
    int n   = rem & (N_-1);
    VT[((size_t)bh*VTROWS_ + row)*N_ + n] = (row == 64) ? (bf16)1.0f : (bf16)0.0f;
}

__global__ __launch_bounds__(256)
void pack_kv(const float* __restrict__ KVt32, bf16* __restrict__ KVb)
{
    int i = blockIdx.x * 256 + threadIdx.x;          // 64bh x 128 x 256
    if (i >= B_*H_*KVROWS_*M_) return;
    int bh  = i >> 15;
    int rem = i & 32767;
    int row = rem >> 8;
    int m   = rem & (M_-1);
    bf16 o = (bf16)0.0f;
    if (row < 64) {
        o = (bf16)KVt32[((size_t)bh*VTROWS_ + row)*M_ + m];
    } else if (row == 64) {
        o = (bf16)KVt32[((size_t)bh*VTROWS_ + 64)*M_ + m];
    } else if (row == 65) {
        float v = KVt32[((size_t)bh*VTROWS_ + 64)*M_ + m];
        o = (bf16)(v - (float)(bf16)v);
    }
    KVb[i] = o;
}

// ---------------------------------------------------------------------------
// Unified QKV projection — 256x256 tile, BK=64, 8 waves, 8-phase counted-vmcnt.
// amdgpu_waves_per_eu(2,2): LDS (128KB) already limits to 1 block/CU = 2
// waves/EU, so this is free occupancy-wise but raises the VGPR budget
// 128 -> 256 (acc alone is 128 VGPRs; the default 4/EU target spilled it).
// ---------------------------------------------------------------------------

#define STAGE_(dstbuf, srcp, kt, half) do { \
    _Pragma("unroll") \
    for (int q_ = 0; q_ < 2; ++q_) { \
        int idx_ = q_*512 + tid; \
        int row_ = idx_ >> 3; \
        int seg_ = (idx_ & 7) ^ (row_ & 7); \
        GLD((srcp) + (size_t)((half)*128 + row_) * D_ + (kt)*64 + seg_*8, \
            &(dstbuf)[(half)*8192 + idx_*8]); \
    } } while (0)

#define LDA_(buf, i0) do { \
    _Pragma("unroll") \
    for (int i_ = 0; i_ < 4; ++i_) { \
        _Pragma("unroll") \
        for (int k_ = 0; k_ < 2; ++k_) { \
            int row_ = warp_m*128 + ((i0)+i_)*16 + m16; \
            int off_ = (row_*128 + k_*64 + quad*16) ^ ((row_ & 7) << 4); \
            a[i_][k_] = *(const f16x8*)((const char*)(buf) + off_); \
        } } } while (0)

#define LDB_(buf, j0) do { \
    _Pragma("unroll") \
    for (int j_ = 0; j_ < 2; ++j_) { \
        _Pragma("unroll") \
        for (int k_ = 0; k_ < 2; ++k_) { \
            int row_ = warp_n*64 + ((j0)+j_)*16 + m16; \
            int off_ = (row_*128 + k_*64 + quad*16) ^ ((row_ & 7) << 4); \
            b[(j0)+j_][k_] = *(const f16x8*)((const char*)(buf) + off_); \
        } } } while (0)

#define MFMA_Q(I0, J0) do { \
    _Pragma("unroll") \
    for (int i_ = 0; i_ < 4; ++i_) { \
        _Pragma("unroll") \
        for (int j_ = 0; j_ < 2; ++j_) { \
            _Pragma("unroll") \
            for (int k_ = 0; k_ < 2; ++k_) \
                acc[(I0)+i_][(J0)+j_] = __builtin_amdgcn_mfma_f32_16x16x32_f16( \
                    a[i_][k_], b[(J0)+j_][k_], acc[(I0)+i_][(J0)+j_], 0, 0, 0); \
        } } } while (0)

#define BAR_()   __builtin_amdgcn_s_barrier()
#define LGK0_()  do { asm volatile("s_waitcnt lgkmcnt(0)"); \
                      __builtin_amdgcn_sched_barrier(0); } while (0)
#define LGK8_()  asm volatile("s_waitcnt lgkmcnt(8)")
#define VMC4_()  do { asm volatile("s_waitcnt vmcnt(4)"); \
                      __builtin_amdgcn_sched_barrier(0); } while (0)
#define PRIO1_() __builtin_amdgcn_s_setprio(1)
#define PRIO0_() __builtin_amdgcn_s_setprio(0)

__global__ __launch_bounds__(512)
__attribute__((amdgpu_waves_per_eu(2, 2)))
void gemm_qkv(const f16* __restrict__ X, const f16* __restrict__ Wh,
              const float* __restrict__ bqkv,
              f16* __restrict__ Qh, f16* __restrict__ Kh, bf16* __restrict__ VT)
{
    __shared__ __align__(16) f16 sA[2][256*64];   // 64 KB
    __shared__ __align__(16) f16 sB[2][256*64];   // 64 KB
    const int tid = threadIdx.x;

    // T1: bijective XCD swizzle (nwg = 768, 768 % 8 == 0)
    const int nwg  = gridDim.x * gridDim.y;
    int flat = blockIdx.y * gridDim.x + blockIdx.x;
    int wgid = (flat & 7) * (nwg >> 3) + (flat >> 3);
    const int bm = (wgid / 12) * 256;
    const int bn = (wgid % 12) * 256;

    const int lane = tid & 63, wave = tid >> 6;
    const int warp_m = wave >> 2, warp_n = wave & 3;   // 2 x 4 waves
    const int m16 = lane & 15, quad = lane >> 4;

    const f16* gA = X  + (size_t)bm * D_;
    const f16* gB = Wh + (size_t)bn * D_;

    f32x4 acc[8][4];
    #pragma unroll
    for (int i = 0; i < 8; ++i)
        #pragma unroll
        for (int j = 0; j < 4; ++j)
            acc[i][j] = (f32x4){0.f, 0.f, 0.f, 0.f};

    f16x8 a[4][2], b[4][2];

    // prologue: tile0 A+B -> P0, tile1 B -> P1 (12 loads); vmcnt(4) leaves
    // only P1.B possibly outstanding -> P0 fully landed before ph1 reads.
    STAGE_(sA[0], gA, 0, 0);
    STAGE_(sA[0], gA, 0, 1);
    STAGE_(sB[0], gB, 0, 0);
    STAGE_(sB[0], gB, 0, 1);
    STAGE_(sB[1], gB, 1, 0);
    STAGE_(sB[1], gB, 1, 1);
    VMC4_();
    BAR_();

    for (int it = 0; it < 8; ++it) {
        const int t1 = 2*it + 1, t2 = 2*it + 2, t3 = 2*it + 3;
        // ---------- K-tile t0 from P0 ----------
        LDA_(sA[0], 0); LDB_(sB[0], 0);
        STAGE_(sA[1], gA, t1, 0);
        LGK8_();
        BAR_(); LGK0_();
        PRIO1_(); MFMA_Q(0, 0); PRIO0_();
        BAR_();

        LDB_(sB[0], 2);
        STAGE_(sA[1], gA, t1, 1);
        BAR_(); LGK0_();
        PRIO1_(); MFMA_Q(0, 2); PRIO0_();
        BAR_();

        LDA_(sA[0], 4);
        if (t2 < 16) STAGE_(sB[0], gB, t2, 0);
        BAR_(); LGK0_();
        PRIO1_(); MFMA_Q(4, 2); PRIO0_();
        BAR_();

        if (t2 < 16) STAGE_(sB[0], gB, t2, 1);
        VMC4_();
        BAR_();
        PRIO1_(); MFMA_Q(4, 0); PRIO0_();
        BAR_();

        // ---------- K-tile t1 from P1 ----------
        LDA_(sA[1], 0); LDB_(sB[1], 0);
        if (t2 < 16) STAGE_(sA[0], gA, t2, 0);
        LGK8_();
        BAR_(); LGK0_();
        PRIO1_(); MFMA_Q(0, 0); PRIO0_();
        BAR_();

        LDB_(sB[1], 2);
        if (t2 < 16) STAGE_(sA[0], gA, t2, 1);
        BAR_(); LGK0_();
        PRIO1_(); MFMA_Q(0, 2); PRIO0_();
        BAR_();

        LDA_(sA[1], 4);
        if (t3 < 16) STAGE_(sB[1], gB, t3, 0);
        BAR_(); LGK0_();
        PRIO1_(); MFMA_Q(4, 2); PRIO0_();
        BAR_();

        if (t3 < 16) STAGE_(sB[1], gB, t3, 1);
        VMC4_();
        BAR_();
        PRIO1_(); MFMA_Q(4, 0); PRIO0_();
        BAR_();
    }

    // epilogue: scatter Q / K / V (+bias). 256-col tiles never straddle the
    // Q/K/V boundaries (1024 % 256 == 0).
    #pragma unroll
    for (int j = 0; j < 4; ++j) {
        int gcol = bn + warp_n*64 + j*16 + m16;
        float bv = bqkv[gcol];
        #pragma unroll
        for (int i = 0; i < 8; ++i) {
            int row0 = bm + warp_m*128 + i*16 + quad*4;
            if (gcol >= 2*D_) {
                int vcol = gcol - 2*D_;
                int hh = vcol >> 6, dd = vcol & 63;
                int bb = row0 >> 12, nn = row0 & (N_-1);
                bf16x4 pk = { (bf16)(acc[i][j][0]+bv), (bf16)(acc[i][j][1]+bv),
                              (bf16)(acc[i][j][2]+bv), (bf16)(acc[i][j][3]+bv) };
                *(bf16x4*)&VT[(((size_t)bb*H_+hh)*VTROWS_ + dd)*N_ + nn] = pk;
            } else if (gcol >= D_) {
                #pragma unroll
                for (int r = 0; r < 4; ++r)
                    Kh[(size_t)(row0+r) * D_ + gcol - D_] = (f16)(acc[i][j][r] + bv);
            } else {
                #pragma unroll
                for (int r = 0; r < 4; ++r)
                    Qh[(size_t)(row0+r) * D_ + gcol] = (f16)(acc[i][j][r] + bv);
            }
        }
    }
}

// ---------------------------------------------------------------------------
// fused_kv: 512 threads (8 waves), double-buffered sK/sVT, stage for subtile
// t+1 issued mid-compute of subtile t. amdgpu_waves_per_eu(2,2): LDS (140KB)
// limits to 1 block/CU anyway; lifts VGPR budget 128 -> 256 so the 64 om
// global loads per subtile can pipeline instead of serializing on L2 latency
// (persistent live set is 112 VGPRs; at 128 only ~1 load-group in flight).
// ---------------------------------------------------------------------------
#define STAGEKV_(sub_, bi_) do { \
    const int n0_ = nsp*1024 + (sub_)*128; \
    _Pragma("unroll") \
    for (int it_ = 0; it_ < 2; ++it_) { \
        int idx_ = it_*512 + tid; \
        int row_ = idx_ >> 3, seg_ = (idx_ & 7) ^ (row_ & 7); \
        GLD(Kh + (size_t)(b*N_ + n0_ + row_) * D_ + h*DK_ + seg_*8, \
            &sK[bi_][idx_*8]); \
    } \
    _Pragma("unroll") \
    for (int it_ = 0; it_ < 2; ++it_) { \
        int idx_ = it_*512 + tid; \
        int row_ = idx_ >> 4, seg_ = (idx_ & 15) ^ (row_ & 7); \
        GLD(VT + ((size_t)bh*VTROWS_ + row_)*N_ + n0_ + seg_*8, \
            &sVT[bi_][idx_*8]); \
    } \
    if (tid < 256) { \
        int idx_ = 1024 + tid; \
        int row_ = idx_ >> 4, seg_ = (idx_ & 15) ^ (row_ & 7); \
        GLD(VT + ((size_t)bh*VTROWS_ + row_)*N_ + n0_ + seg_*8, \
            &sVT[bi_][idx_*8]); \
    } } while (0)

__global__ __launch_bounds__(512)
__attribute__((amdgpu_waves_per_eu(2, 2)))
void fused_kv(const f16* __restrict__ Kh, const bf16* __restrict__ VT,
              const f16* __restrict__ omhi, const f16* __restrict__ omlo,
              const int* __restrict__ mask, float* __restrict__ KVt32)
{
    __shared__ __align__(16) f16  sK[2][128*64];      // 32 KB
    __shared__ __align__(16) bf16 sVT[2][VTROWS_*128];// 40 KB
    __shared__ __align__(16) bf16 sPhi[M_*PHK_PAD];   // 68 KB  [m][n] pad 136
    const int nsp = blockIdx.x;          // 0..3
    const int h = blockIdx.y, b = blockIdx.z;
    const int bh = b*H_ + h;
    const int tid = threadIdx.x, lane = tid & 63, wave = tid >> 6;
    const int m16 = lane & 15, quad = lane >> 4;
    const int wm = wave * 32;            // wave's m-range for kv MFMA
    const float inv_sqrt_m = rsqrtf((float)M_ + 1e-6f);
    const f16* omh = omhi + (size_t)h * M_ * DK_;
    const f16* oml = omlo + (size_t)h * M_ * DK_;

    f32x4 kvacc[5][2];
    #pragma unroll
    for (int d = 0; d < 5; ++d)
        #pragma unroll
        for (int j = 0; j < 2; ++j)
            kvacc[d][j] = (f32x4){0.f, 0.f, 0.f, 0.f};

    STAGEKV_(0, 0);

    for (int sub = 0; sub < 8; ++sub) {
        const int cur = sub & 1;
        const int n0 = nsp*1024 + sub*128;

        asm volatile("s_waitcnt vmcnt(0)");     // prev-iter stages (old) landed
        __builtin_amdgcn_sched_barrier(0);
        __builtin_amdgcn_s_barrier();           // (B) all waves' stages landed;
                                                //     prev readers of other buf done
        // ---- feat: proj = K . omega^T (wave owns 16 n-rows) ----
        const char* kb = (const char*)&sK[cur][0];
        const int rowb = wave*16 + m16;
        f16x8 ah0 = *(const f16x8*)(kb + ((rowb*128 +      quad*16) ^ ((rowb & 7) << 4)));
        f16x8 ah1 = *(const f16x8*)(kb + ((rowb*128 + 64 + quad*16) ^ ((rowb & 7) << 4)));

        f32x4 acc[16];
        #pragma unroll
        for (int j = 0; j < 16; ++j) acc[j] = (f32x4){0.f, 0.f, 0.f, 0.f};

        #pragma unroll
        for (int j = 0; j < 16; ++j) {
            size_t ro = (size_t)(j*16 + m16) * DK_ + quad*8;
            f16x8 bh0 = *(const f16x8*)&omh[ro];
            f16x8 bh1 = *(const f16x8*)&omh[ro + 32];
            f16x8 bl0 = *(const f16x8*)&oml[ro];
            f16x8 bl1 = *(const f16x8*)&oml[ro + 32];
            acc[j] = __builtin_amdgcn_mfma_f32_16x16x32_f16(ah0, bh0, acc[j], 0,0,0);
            acc[j] = __builtin_amdgcn_mfma_f32_16x16x32_f16(ah0, bl0, acc[j], 0,0,0);
            acc[j] = __builtin_amdgcn_mfma_f32_16x16x32_f16(ah1, bh1, acc[j], 0,0,0);
            acc[j] = __builtin_amdgcn_mfma_f32_16x16x32_f16(ah1, bl1, acc[j], 0,0,0);
        }

        // issue next subtile's stage AFTER the om loads (so compiler's om
        // waitcnts don't force the fresh stage to land); flight hides under
        // softmax + Phi write + kv MFMA.
        if (sub < 7) STAGEKV_(sub+1, cur^1);

        // rowmax + exp
        #pragma unroll
        for (int r = 0; r < 4; ++r) {
            float mx = acc[0][r];
            #pragma unroll
            for (int j = 1; j < 16; ++j) mx = fmaxf(mx, acc[j][r]);
            mx = fmaxf(mx, __shfl_xor(mx, 1, 64));
            mx = fmaxf(mx, __shfl_xor(mx, 2, 64));
            mx = fmaxf(mx, __shfl_xor(mx, 4, 64));
            mx = fmaxf(mx, __shfl_xor(mx, 8, 64));
            #pragma unroll
            for (int j = 0; j < 16; ++j)
                acc[j][r] = __expf(acc[j][r] - mx) * inv_sqrt_m;
        }

        // Phi -> LDS [m][n] padded, PAD keys zeroed (bf16x4 along n)
        int4 mv4 = *(const int4*)&mask[b*N_ + n0 + wave*16 + quad*4];
        const int* mv = (const int*)&mv4;
        const int nloc = wave*16 + quad*4;
        #pragma unroll
        for (int j = 0; j < 16; ++j) {
            bf16x4 pk;
            #pragma unroll
            for (int r = 0; r < 4; ++r)
                pk[r] = mv[r] ? (bf16)0.0f : (bf16)acc[j][r];
            *(bf16x4*)&sPhi[(j*16 + m16)*PHK_PAD + nloc] = pk;
        }
        asm volatile("s_waitcnt lgkmcnt(0)");   // Phi writes complete
        __builtin_amdgcn_sched_barrier(0);
        __builtin_amdgcn_s_barrier();           // (C) Phi visible

        // ---- kv MFMA: KVt[d][m] += sum_n VT[d][n] * Phi[m][n] ----
        const char* vb = (const char*)&sVT[cur][0];
        #pragma unroll
        for (int kk = 0; kk < 128; kk += 32) {
            bf16x8 av[5], bp[2];
            #pragma unroll
            for (int d = 0; d < 5; ++d) {
                int rowv = d*16 + m16;
                av[d] = *(const bf16x8*)(vb +
                        ((rowv*256 + kk*2 + quad*16) ^ ((rowv & 7) << 4)));
            }
            #pragma unroll
            for (int j = 0; j < 2; ++j)
                bp[j] = *(const bf16x8*)&sPhi[(wm + j*16 + m16)*PHK_PAD + kk + quad*8];
            #pragma unroll
            for (int d = 0; d < 5; ++d)
                #pragma unroll
                for (int j = 0; j < 2; ++j)
                    kvacc[d][j] = __builtin_amdgcn_mfma_f32_16x16x32_bf16(
                        av[d], bp[j], kvacc[d][j], 0, 0, 0);
        }
    }

    #pragma unroll
    for (int d = 0; d < 5; ++d)
        #pragma unroll
        for (int j = 0; j < 2; ++j) {
            int drow = d*16 + quad*4;
            int m = wm + j*16 + m16;
            #pragma unroll
            for (int r = 0; r < 4; ++r)
                atomicAdd(&KVt32[((size_t)bh*VTROWS_ + drow + r)*M_ + m],
                          kvacc[d][j][r]);
        }
}

// ---------------------------------------------------------------------------
// fused_ctx: stage Q + ALL 4 KVb tiles at block start (vmcnt(16) lets feat
// start once Q lands; KVb flight hides under feat); single __syncthreads
// before an uninterrupted ctx GEMM. sQ/sW XOR-swizzled.
// ---------------------------------------------------------------------------
__global__ __launch_bounds__(256)
void fused_ctx(const f16* __restrict__ Qh, const f16* __restrict__ omhi,
               const f16* __restrict__ omlo, const bf16* __restrict__ KVb,
               bf16* __restrict__ ctx)
{
    __shared__ __align__(16) f16  sQ[128*64];          // 16 KB
    __shared__ __align__(16) bf16 sW[4][128*64];       // 64 KB
    __shared__ __align__(16) bf16 sPhi[128*PHQ_PAD];   // 67.6 KB [n][m] pad 264
    __shared__ float sden[2][128];
    const int nblk = blockIdx.x, h = blockIdx.y, b = blockIdx.z;
    const int bh = b*H_ + h;
    const int tid = threadIdx.x, lane = tid & 63, wave = tid >> 6;
    const int m16 = lane & 15, quad = lane >> 4;
    const float inv_sqrt_m = rsqrtf((float)M_ + 1e-6f);
    const f16* omh = omhi + (size_t)h * M_ * DK_;
    const f16* oml = omlo + (size_t)h * M_ * DK_;

    #pragma unroll
    for (int it = 0; it < 4; ++it) {     // Q slab 128x64 f16 (swizzled src)
        int idx = it*256 + tid;
        int row = idx >> 3, seg = (idx & 7) ^ (row & 7);
        GLD(Qh + (size_t)(b*N_ + nblk*128 + row) * D_ + h*DK_ + seg*8, &sQ[idx*8]);
    }
    #pragma unroll
    for (int t = 0; t < 4; ++t)          // all KVb tiles 128x64 bf16
        #pragma unroll
        for (int it = 0; it < 4; ++it) {
            int idx = it*256 + tid;
            int row = idx >> 3, seg = (idx & 7) ^ (row & 7);
            GLD(KVb + ((size_t)bh*KVROWS_ + row)*M_ + t*64 + seg*8, &sW[t][idx*8]);
        }
    asm volatile("s_waitcnt vmcnt(16)"); // Q landed; KVb still in flight
    __builtin_amdgcn_sched_barrier(0);
    __builtin_amdgcn_s_barrier();

    // ---- feat (wave owns 32 n-rows) ----
    {
        f16x8 ah[2][2];
        #pragma unroll
        for (int i = 0; i < 2; ++i)
            #pragma unroll
            for (int k = 0; k < 2; ++k) {
                int row = wave*32 + i*16 + m16;
                ah[i][k] = *(const f16x8*)((const char*)sQ +
                           ((row*128 + k*64 + quad*16) ^ ((row & 7) << 4)));
            }

        f32x4 acc[2][16];
        #pragma unroll
        for (int i = 0; i < 2; ++i)
            #pragma unroll
            for (int j = 0; j < 16; ++j)
                acc[i][j] = (f32x4){0.f, 0.f, 0.f, 0.f};

        #pragma unroll
        for (int j = 0; j < 16; ++j) {
            size_t ro = (size_t)(j*16 + m16) * DK_ + quad*8;
            f16x8 bh0 = *(const f16x8*)&omh[ro];
            f16x8 bh1 = *(const f16x8*)&omh[ro + 32];
            f16x8 bl0 = *(const f16x8*)&oml[ro];
            f16x8 bl1 = *(const f16x8*)&oml[ro + 32];
            #pragma unroll
            for (int i = 0; i < 2; ++i) {
                acc[i][j] = __builtin_amdgcn_mfma_f32_16x16x32_f16(ah[i][0], bh0, acc[i][j], 0,0,0);
                acc[i][j] = __builtin_amdgcn_mfma_f32_16x16x32_f16(ah[i][0], bl0, acc[i][j], 0,0,0);
                acc[i][j] = __builtin_amdgcn_mfma_f32_16x16x32_f16(ah[i][1], bh1, acc[i][j], 0,0,0);
                acc[i][j] = __builtin_amdgcn_mfma_f32_16x16x32_f16(ah[i][1], bl1, acc[i][j], 0,0,0);
            }
        }
        #pragma unroll
        for (int i = 0; i < 2; ++i)
            #pragma unroll
            for (int r = 0; r < 4; ++r) {
                float mx = acc[i][0][r];
                #pragma unroll
                for (int j = 1; j < 16; ++j) mx = fmaxf(mx, acc[i][j][r]);
                mx = fmaxf(mx, __shfl_xor(mx, 1, 64));
                mx = fmaxf(mx, __shfl_xor(mx, 2, 64));
                mx = fmaxf(mx, __shfl_xor(mx, 4, 64));
                mx = fmaxf(mx, __shfl_xor(mx, 8, 64));
                #pragma unroll
                for (int j = 0; j < 16; ++j)
                    acc[i][j][r] = __expf(acc[i][j][r] - mx) * inv_sqrt_m;
            }
        // Phi -> LDS [n][m] padded (scalar b16; pad kills write conflicts)
        #pragma unroll
        for (int i = 0; i < 2; ++i) {
            int nloc0 = wave*32 + i*16 + quad*4;
            #pragma unroll
            for (int j = 0; j < 16; ++j)
                #pragma unroll
                for (int r = 0; r < 4; ++r)
                    sPhi[(nloc0 + r)*PHQ_PAD + j*16 + m16] = (bf16)acc[i][j][r];
        }
    }
    __syncthreads();   // Phi visible; all KVb landed (full drain)

    // ---- ctx GEMM: A = Phi (LDS), W = sW (all resident) — no inner barriers
    const int wm = (wave & 1) * 64, wn = (wave >> 1) * 64;
    f32x4 cacc[4][4];
    #pragma unroll
    for (int i = 0; i < 4; ++i)
        #pragma unroll
        for (int j = 0; j < 4; ++j)
            cacc[i][j] = (f32x4){0.f, 0.f, 0.f, 0.f};

    #pragma unroll
    for (int t = 0; t < 4; ++t) {
        #pragma unroll
        for (int kk = 0; kk < 64; kk += 32) {
            bf16x8 af[4], wf[4];
            #pragma unroll
            for (int i = 0; i < 4; ++i)
                af[i] = *(const bf16x8*)&sPhi[(wm + i*16 + m16)*PHQ_PAD + t*64 + kk + quad*8];
            #pragma unroll
            for (int j = 0; j < 4; ++j) {
                int row = wn + j*16 + m16;
                wf[j] = *(const bf16x8*)((const char*)sW + t*16384 +
                        ((row*128 + kk*2 + quad*16) ^ ((row & 7) << 4)));
            }
            #pragma unroll
            for (int i = 0; i < 4; ++i)
                #pragma unroll
                for (int j = 0; j < 4; ++j)
                    cacc[i][j] = __builtin_amdgcn_mfma_f32_16x16x32_bf16(
                        af[i], wf[j], cacc[i][j], 0, 0, 0);
        }
    }

    if (wn == 64 && m16 < 2) {
        #pragma unroll
        for (int i = 0; i < 4; ++i)
            #pragma unroll
            for (int r = 0; r < 4; ++r)
                sden[m16][wm + i*16 + quad*4 + r] = cacc[i][0][r];
    }
    __syncthreads();
    if (wn == 0) {
        #pragma unroll
        for (int i = 0; i < 4; ++i) {
            int lrow0 = wm + i*16 + quad*4;
            #pragma unroll
            for (int r = 0; r < 4; ++r) {
                int lrow = lrow0 + r;
                int n = nblk*128 + lrow;
                float den = sden[0][lrow] + sden[1][lrow] + EPS_;
                #pragma unroll
                for (int j = 0; j < 4; ++j)
                    ctx[(size_t)(b*N_ + n)*D_ + h*DK_ + j*16 + m16] =
                        (bf16)(cacc[i][j][r] / den);
            }
        }
    }
}

// ---------------------------------------------------------------------------
// Output projection: out = mask ? 0 : ctx @ Wout^T + bout   (bf16 MFMA, fp32 out)
// ---------------------------------------------------------------------------
__global__ __launch_bounds__(256)
void gemm_out(const bf16* __restrict__ A, const bf16* __restrict__ W,
              const float* __restrict__ bias, float* __restrict__ C,
              const int* __restrict__ mask)
{
    __shared__ bf16 sA[128*64];
    __shared__ bf16 sB[128*64];
    const int tid  = threadIdx.x;
    const int bm   = blockIdx.y * 128;
    const int bn   = blockIdx.x * 128;
    const int lane = tid & 63, wave = tid >> 6;
    const int wm   = (wave & 1) * 64, wn = (wave >> 1) * 64;
    const int m16  = lane & 15, quad = lane >> 4;

    f32x4 acc[4][4];
    #pragma unroll
    for (int i = 0; i < 4; ++i)
        #pragma unroll
        for (int j = 0; j < 4; ++j)
            acc[i][j] = (f32x4){0.f, 0.f, 0.f, 0.f};

    for (int k0 = 0; k0 < D_; k0 += 64) {
        __syncthreads();
        #pragma unroll
        for (int it = 0; it < 4; ++it) {
            int idx = it*256 + tid;
            int row = idx >> 3, seg = idx & 7;
            GLD(A + (size_t)(bm + row) * D_ + k0 + seg*8, &sA[idx*8]);
            GLD(W + (size_t)(bn + row) * D_ + k0 + seg*8, &sB[idx*8]);
        }
        __syncthreads();
        #pragma unroll
        for (int kk = 0; kk < 64; kk += 32) {
            bf16x8 af[4], bfr[4];
            #pragma unroll
            for (int i = 0; i < 4; ++i)
                af[i] = *(const bf16x8*)&sA[(wm + i*16 + m16)*64 + kk + quad*8];
            #pragma unroll
            for (int j = 0; j < 4; ++j)
                bfr[j] = *(const bf16x8*)&sB[(wn + j*16 + m16)*64 + kk + quad*8];
            #pragma unroll
            for (int i = 0; i < 4; ++i)
                #pragma unroll
                for (int j = 0; j < 4; ++j)
                    acc[i][j] = __builtin_amdgcn_mfma_f32_16x16x32_bf16(
                        af[i], bfr[j], acc[i][j], 0, 0, 0);
        }
    }

    #pragma unroll
    for (int j = 0; j < 4; ++j) {
        int col = bn + wn + j*16 + m16;
        float bv = bias[col];
        #pragma unroll
        for (int i = 0; i < 4; ++i) {
            int row0 = bm + wm + i*16 + quad*4;
            #pragma unroll
            for (int r = 0; r < 4; ++r) {
                int row = row0 + r;
                float v = acc[i][j][r] + bv;
                if (mask[row] != 0) v = 0.0f;
                C[(size_t)row * D_ + col] = v;
            }
        }
    }
}

// ---------------------------------------------------------------------------
extern "C" void kernel_launch(void* const* d_in, const int* in_sizes, int n_in,
                              void* d_out, int out_size, void* d_ws, size_t ws_size,
                              hipStream_t stream)
{
    const float* x     = (const float*)d_in[0];
    const int*   mask  = (const int*)d_in[1];     // 1 = PAD
    const float* Wqkv  = (const float*)d_in[2];
    const float* bqkv  = (const float*)d_in[3];
    const float* Wout  = (const float*)d_in[4];
    const float* bout  = (const float*)d_in[5];
    const float* omega = (const float*)d_in[6];
    float* out = (float*)d_out;

    char* w = (char*)d_ws;
    f16*   Wh    = (f16*)w;    w += (size_t)3*D_*D_ * 2;              //   6.29 MB
    bf16*  Wob   = (bf16*)w;   w += (size_t)D_*D_ * 2;                //   2.10 MB
    f16*   omhi  = (f16*)w;    w += (size_t)H_*M_*DK_ * 2;            //   0.52 MB
    f16*   omlo  = (f16*)w;    w += (size_t)H_*M_*DK_ * 2;            //   0.52 MB
    f16*   xh    = (f16*)w;    w += (size_t)R_ * D_ * 2;              //  33.55 MB
    f16*   Qh    = (f16*)w;    w += (size_t)R_ * D_ * 2;              //  33.55 MB
    f16*   Kh    = (f16*)w;    w += (size_t)R_ * D_ * 2;              //  33.55 MB (-> ctx)
    bf16*  VT    = (bf16*)w;   w += (size_t)B_*H_*VTROWS_*N_ * 2;     //  41.94 MB
    float* KVt32 = (float*)w;  w += (size_t)B_*H_*VTROWS_*M_ * 4;     //   5.24 MB
    bf16*  KVb   = (bf16*)w;   w += (size_t)B_*H_*KVROWS_*M_ * 2;     //   4.19 MB
    bf16*  VC    = (bf16*)Kh;                                         // alias (Kh dead after fused_kv)

    // 0) prep
    split_f16v<<<(R_*D_/4 + 255)/256, 256, 0, stream>>>(x, xh, nullptr, R_*D_/4);
    split_f16v<<<(3*D_*D_/4 + 255)/256, 256, 0, stream>>>(Wqkv, Wh, nullptr, 3*D_*D_/4);
    split_f16v<<<(H_*M_*DK_/4 + 255)/256, 256, 0, stream>>>(omega, omhi, omlo, H_*M_*DK_/4);
    f32_to_bf16v<<<(D_*D_/4 + 255)/256, 256, 0, stream>>>(Wout, Wob, D_*D_/4);
    zero_f32<<<(B_*H_*VTROWS_*M_ + 255)/256, 256, 0, stream>>>(KVt32, B_*H_*VTROWS_*M_);
    init_vt<<<(B_*H_*16*N_ + 255)/256, 256, 0, stream>>>(VT);

    // 1) unified QKV projection (fp16, 256^2 8-phase): Qh, Kh fp16; V -> VT bf16
    gemm_qkv<<<dim3(3*D_/256, R_/256), 512, 0, stream>>>(xh, Wh, bqkv, Qh, Kh, VT);

    // 2) fused K-features + KV/ksum accumulation (Phi_K in LDS only)
    fused_kv<<<dim3(4, H_, B_), 512, 0, stream>>>(Kh, VT, omhi, omlo, mask, KVt32);

    // 3) pack KVt32 -> KVb bf16 (ksum hi/lo rows 64/65, zero pad to 128)
    pack_kv<<<(B_*H_*KVROWS_*M_ + 255)/256, 256, 0, stream>>>(KVt32, KVb);

    // 4) fused Q-features + ctx (Phi_Q in LDS only) -> VC bf16 (aliases Kh)
    fused_ctx<<<dim3(N_/128, H_, B_), 256, 0, stream>>>(Qh, omhi, omlo, KVb, VC);

    // 5) output projection + bias + PAD-query zeroing -> fp32 out
    gemm_out<<<dim3(8, R_/128), 256, 0, stream>>>(VC, Wob, bout, out, mask);
}

// Round 5
// 457.482 us; speedup vs baseline: 1.4154x; 1.4116x over previous
//
#include <hip/hip_runtime.h>
#include <hip/hip_bf16.h>
#include <math.h>

#define B_  4
#define N_  4096
#define D_  1024
#define H_  16
#define DK_ 64
#define M_  256
#define R_  (B_*N_)          // 16384 rows
#define EPS_ 1e-6f
#define VTROWS_ 80           // 64 V rows + row64=ones(ksum) + 65..79 pad
#define KVROWS_ 128          // KVb bf16: 64 KV + 64=ksum_hi + 65=ksum_lo + 0-pad
#define PHK_PAD 68           // fused_kv  Phi LDS [m][68]  (n-HALF + pad)
#define PHQ_PAD 264          // fused_ctx Phi LDS [n][264]

typedef __bf16 bf16;
typedef __bf16 bf16x4 __attribute__((ext_vector_type(4)));
typedef __bf16 bf16x8 __attribute__((ext_vector_type(8)));
typedef _Float16 f16;
typedef _Float16 f16x4 __attribute__((ext_vector_type(4)));
typedef _Float16 f16x8 __attribute__((ext_vector_type(8)));
typedef float  f32x4  __attribute__((ext_vector_type(4)));

#define GLD(gp, lp) __builtin_amdgcn_global_load_lds( \
    (const __attribute__((address_space(1))) void*)(gp), \
    (__attribute__((address_space(3))) void*)(lp), 16, 0, 0)

#define BAR_()   __builtin_amdgcn_s_barrier()
#define SBAR_()  __builtin_amdgcn_sched_barrier(0)
#define PRIO1_() __builtin_amdgcn_s_setprio(1)
#define PRIO0_() __builtin_amdgcn_s_setprio(0)

// ---------------------------------------------------------------------------
// prep kernels
// ---------------------------------------------------------------------------
__global__ __launch_bounds__(256)
void split_f16v(const float* __restrict__ in, f16* __restrict__ hi,
                f16* __restrict__ lo, int n4)
{
    int i = blockIdx.x * 256 + threadIdx.x;
    if (i < n4) {
        float4 v = ((const float4*)in)[i];
        f16x4 h = { (f16)v.x, (f16)v.y, (f16)v.z, (f16)v.w };
        ((f16x4*)hi)[i] = h;
        if (lo) {
            f16x4 l = { (f16)(v.x - (float)h[0]), (f16)(v.y - (float)h[1]),
                        (f16)(v.z - (float)h[2]), (f16)(v.w - (float)h[3]) };
            ((f16x4*)lo)[i] = l;
        }
    }
}

__global__ __launch_bounds__(256)
void f32_to_bf16v(const float* __restrict__ in, bf16* __restrict__ o, int n4)
{
    int i = blockIdx.x * 256 + threadIdx.x;
    if (i < n4) {
        float4 v = ((const float4*)in)[i];
        bf16x4 h = { (bf16)v.x, (bf16)v.y, (bf16)v.z, (bf16)v.w };
        ((bf16x4*)o)[i] = h;
    }
}

__global__ __launch_bounds__(256)
void zero_f32(float* __restrict__ p, int n)
{
    int i = blockIdx.x * 256 + threadIdx.x;
    if (i < n) p[i] = 0.f;
}

__global__ __launch_bounds__(256)
void init_vt(bf16* __restrict__ VT)
{
    int i = blockIdx.x * 256 + threadIdx.x;          // 64bh x 16rows x 4096
    if (i >= B_*H_*16*N_) return;
    int bh  = i >> 16;
    int rem = i & 65535;
    int row = 64 + (rem >> 12);
    int n   = rem & (N_-1);
    VT[((size_t)bh*VTROWS_ + row)*N_ + n] = (row == 64) ? (bf16)1.0f : (bf16)0.0f;
}

__global__ __launch_bounds__(256)
void pack_kv(const float* __restrict__ KVt32, bf16* __restrict__ KVb)
{
    int i = blockIdx.x * 256 + threadIdx.x;          // 64bh x 128 x 256
    if (i >= B_*H_*KVROWS_*M_) return;
    int bh  = i >> 15;
    int rem = i & 32767;
    int row = rem >> 8;
    int m   = rem & (M_-1);
    bf16 o = (bf16)0.0f;
    if (row < 64) {
        o = (bf16)KVt32[((size_t)bh*VTROWS_ + row)*M_ + m];
    } else if (row == 64) {
        o = (bf16)KVt32[((size_t)bh*VTROWS_ + 64)*M_ + m];
    } else if (row == 65) {
        float v = KVt32[((size_t)bh*VTROWS_ + 64)*M_ + m];
        o = (bf16)(v - (float)(bf16)v);
    }
    KVb[i] = o;
}

// ---------------------------------------------------------------------------
// Unified QKV projection — 256x256 tile, BK=64, 8 waves, 8-phase counted-vmcnt.
// (512, 1): probe — if 2nd arg is min-BLOCKS/CU, budget becomes 256 VGPR.
// ---------------------------------------------------------------------------

#define STAGE_(dstbuf, srcp, kt, half) do { \
    _Pragma("unroll") \
    for (int q_ = 0; q_ < 2; ++q_) { \
        int idx_ = q_*512 + tid; \
        int row_ = idx_ >> 3; \
        int seg_ = (idx_ & 7) ^ (row_ & 7); \
        GLD((srcp) + (size_t)((half)*128 + row_) * D_ + (kt)*64 + seg_*8, \
            &(dstbuf)[(half)*8192 + idx_*8]); \
    } } while (0)

#define LDA_(buf, i0) do { \
    _Pragma("unroll") \
    for (int i_ = 0; i_ < 4; ++i_) { \
        _Pragma("unroll") \
        for (int k_ = 0; k_ < 2; ++k_) { \
            int row_ = warp_m*128 + ((i0)+i_)*16 + m16; \
            int off_ = (row_*128 + k_*64 + quad*16) ^ ((row_ & 7) << 4); \
            a[i_][k_] = *(const f16x8*)((const char*)(buf) + off_); \
        } } } while (0)

#define LDB_(buf, j0) do { \
    _Pragma("unroll") \
    for (int j_ = 0; j_ < 2; ++j_) { \
        _Pragma("unroll") \
        for (int k_ = 0; k_ < 2; ++k_) { \
            int row_ = warp_n*64 + ((j0)+j_)*16 + m16; \
            int off_ = (row_*128 + k_*64 + quad*16) ^ ((row_ & 7) << 4); \
            b[(j0)+j_][k_] = *(const f16x8*)((const char*)(buf) + off_); \
        } } } while (0)

#define MFMA_Q(I0, J0) do { \
    _Pragma("unroll") \
    for (int i_ = 0; i_ < 4; ++i_) { \
        _Pragma("unroll") \
        for (int j_ = 0; j_ < 2; ++j_) { \
            _Pragma("unroll") \
            for (int k_ = 0; k_ < 2; ++k_) \
                acc[(I0)+i_][(J0)+j_] = __builtin_amdgcn_mfma_f32_16x16x32_f16( \
                    a[i_][k_], b[(J0)+j_][k_], acc[(I0)+i_][(J0)+j_], 0, 0, 0); \
        } } } while (0)

#define LGK0_()  do { asm volatile("s_waitcnt lgkmcnt(0)"); SBAR_(); } while (0)
#define LGK8_()  asm volatile("s_waitcnt lgkmcnt(8)")
#define VMC4_()  do { asm volatile("s_waitcnt vmcnt(4)"); SBAR_(); } while (0)

__global__ __launch_bounds__(512, 1)
void gemm_qkv(const f16* __restrict__ X, const f16* __restrict__ Wh,
              const float* __restrict__ bqkv,
              f16* __restrict__ Qh, f16* __restrict__ Kh, bf16* __restrict__ VT)
{
    __shared__ __align__(16) f16 sA[2][256*64];   // 64 KB
    __shared__ __align__(16) f16 sB[2][256*64];   // 64 KB
    const int tid = threadIdx.x;

    // T1: bijective XCD swizzle (nwg = 768, 768 % 8 == 0)
    const int nwg  = gridDim.x * gridDim.y;
    int flat = blockIdx.y * gridDim.x + blockIdx.x;
    int wgid = (flat & 7) * (nwg >> 3) + (flat >> 3);
    const int bm = (wgid / 12) * 256;
    const int bn = (wgid % 12) * 256;

    const int lane = tid & 63, wave = tid >> 6;
    const int warp_m = wave >> 2, warp_n = wave & 3;   // 2 x 4 waves
    const int m16 = lane & 15, quad = lane >> 4;

    const f16* gA = X  + (size_t)bm * D_;
    const f16* gB = Wh + (size_t)bn * D_;

    f32x4 acc[8][4];
    #pragma unroll
    for (int i = 0; i < 8; ++i)
        #pragma unroll
        for (int j = 0; j < 4; ++j)
            acc[i][j] = (f32x4){0.f, 0.f, 0.f, 0.f};

    f16x8 a[4][2], b[4][2];

    STAGE_(sA[0], gA, 0, 0);
    STAGE_(sA[0], gA, 0, 1);
    STAGE_(sB[0], gB, 0, 0);
    STAGE_(sB[0], gB, 0, 1);
    STAGE_(sB[1], gB, 1, 0);
    STAGE_(sB[1], gB, 1, 1);
    VMC4_();
    BAR_();

    for (int it = 0; it < 8; ++it) {
        const int t1 = 2*it + 1, t2 = 2*it + 2, t3 = 2*it + 3;
        LDA_(sA[0], 0); LDB_(sB[0], 0);
        STAGE_(sA[1], gA, t1, 0);
        LGK8_();
        BAR_(); LGK0_();
        PRIO1_(); MFMA_Q(0, 0); PRIO0_();
        BAR_();

        LDB_(sB[0], 2);
        STAGE_(sA[1], gA, t1, 1);
        BAR_(); LGK0_();
        PRIO1_(); MFMA_Q(0, 2); PRIO0_();
        BAR_();

        LDA_(sA[0], 4);
        if (t2 < 16) STAGE_(sB[0], gB, t2, 0);
        BAR_(); LGK0_();
        PRIO1_(); MFMA_Q(4, 2); PRIO0_();
        BAR_();

        if (t2 < 16) STAGE_(sB[0], gB, t2, 1);
        VMC4_();
        BAR_();
        PRIO1_(); MFMA_Q(4, 0); PRIO0_();
        BAR_();

        LDA_(sA[1], 0); LDB_(sB[1], 0);
        if (t2 < 16) STAGE_(sA[0], gA, t2, 0);
        LGK8_();
        BAR_(); LGK0_();
        PRIO1_(); MFMA_Q(0, 0); PRIO0_();
        BAR_();

        LDB_(sB[1], 2);
        if (t2 < 16) STAGE_(sA[0], gA, t2, 1);
        BAR_(); LGK0_();
        PRIO1_(); MFMA_Q(0, 2); PRIO0_();
        BAR_();

        LDA_(sA[1], 4);
        if (t3 < 16) STAGE_(sB[1], gB, t3, 0);
        BAR_(); LGK0_();
        PRIO1_(); MFMA_Q(4, 2); PRIO0_();
        BAR_();

        if (t3 < 16) STAGE_(sB[1], gB, t3, 1);
        VMC4_();
        BAR_();
        PRIO1_(); MFMA_Q(4, 0); PRIO0_();
        BAR_();
    }

    #pragma unroll
    for (int j = 0; j < 4; ++j) {
        int gcol = bn + warp_n*64 + j*16 + m16;
        float bv = bqkv[gcol];
        #pragma unroll
        for (int i = 0; i < 8; ++i) {
            int row0 = bm + warp_m*128 + i*16 + quad*4;
            if (gcol >= 2*D_) {
                int vcol = gcol - 2*D_;
                int hh = vcol >> 6, dd = vcol & 63;
                int bb = row0 >> 12, nn = row0 & (N_-1);
                bf16x4 pk = { (bf16)(acc[i][j][0]+bv), (bf16)(acc[i][j][1]+bv),
                              (bf16)(acc[i][j][2]+bv), (bf16)(acc[i][j][3]+bv) };
                *(bf16x4*)&VT[(((size_t)bb*H_+hh)*VTROWS_ + dd)*N_ + nn] = pk;
            } else if (gcol >= D_) {
                #pragma unroll
                for (int r = 0; r < 4; ++r)
                    Kh[(size_t)(row0+r) * D_ + gcol - D_] = (f16)(acc[i][j][r] + bv);
            } else {
                #pragma unroll
                for (int r = 0; r < 4; ++r)
                    Qh[(size_t)(row0+r) * D_ + gcol] = (f16)(acc[i][j][r] + bv);
            }
        }
    }
}

// ---------------------------------------------------------------------------
// fused_kv v2: om-hi/lo staged into LDS ONCE per block (the round-2..4
// bottleneck was 64 serialized ~L3-latency om reloads per wave per subtile).
// LDS 150KB: sK dbuf 32 + sVT single 20 + sOmH 32 + sOmL 32 + sPhi(half) 34.
// kv MFMA runs in two n-halves through the half-width sPhi.
// ---------------------------------------------------------------------------
#define STAGEK_(sub_, bi_) do { \
    const int n0_ = nsp*1024 + (sub_)*128; \
    _Pragma("unroll") \
    for (int it_ = 0; it_ < 2; ++it_) { \
        int idx_ = it_*512 + tid; \
        int row_ = idx_ >> 3, seg_ = (idx_ & 7) ^ (row_ & 7); \
        GLD(Kh + (size_t)(b*N_ + n0_ + row_) * D_ + h*DK_ + seg_*8, \
            &sK[bi_][idx_*8]); \
    } } while (0)

#define STAGEVT_(sub_) do { \
    const int n0_ = nsp*1024 + (sub_)*128; \
    _Pragma("unroll") \
    for (int it_ = 0; it_ < 2; ++it_) { \
        int idx_ = it_*512 + tid; \
        int row_ = idx_ >> 4, seg_ = (idx_ & 15) ^ (row_ & 7); \
        GLD(VT + ((size_t)bh*VTROWS_ + row_)*N_ + n0_ + seg_*8, \
            &sVT[idx_*8]); \
    } \
    if (tid < 256) { \
        int idx_ = 1024 + tid; \
        int row_ = idx_ >> 4, seg_ = (idx_ & 15) ^ (row_ & 7); \
        GLD(VT + ((size_t)bh*VTROWS_ + row_)*N_ + n0_ + seg_*8, \
            &sVT[idx_*8]); \
    } } while (0)

#define STAGEOM_(arr_, src_) do { \
    _Pragma("unroll") \
    for (int q_ = 0; q_ < 4; ++q_) { \
        int idx_ = q_*512 + tid; \
        int row_ = idx_ >> 3, seg_ = (idx_ & 7) ^ (row_ & 7); \
        GLD((src_) + (size_t)row_*DK_ + seg_*8, &(arr_)[idx_*8]); \
    } } while (0)

__global__ __launch_bounds__(512, 1)
void fused_kv(const f16* __restrict__ Kh, const bf16* __restrict__ VT,
              const f16* __restrict__ omhi, const f16* __restrict__ omlo,
              const int* __restrict__ mask, float* __restrict__ KVt32)
{
    __shared__ __align__(16) f16  sK[2][128*64];      // 32 KB, swizzled
    __shared__ __align__(16) bf16 sVT[VTROWS_*128];   // 20 KB single, swizzled
    __shared__ __align__(16) f16  sOmH[M_*DK_];       // 32 KB, swizzled
    __shared__ __align__(16) f16  sOmL[M_*DK_];       // 32 KB, swizzled
    __shared__ __align__(16) bf16 sPhi[M_*PHK_PAD];   // 34 KB  [m][68] n-half
    const int nsp = blockIdx.x;          // 0..3
    const int h = blockIdx.y, b = blockIdx.z;
    const int bh = b*H_ + h;
    const int tid = threadIdx.x, lane = tid & 63, wave = tid >> 6;
    const int m16 = lane & 15, quad = lane >> 4;
    const int wm = wave * 32;            // wave's m-range for kv MFMA
    const int nloc = wave*16 + quad*4;   // wave's n-rows: wave*16..+15
    const float inv_sqrt_m = rsqrtf((float)M_ + 1e-6f);
    const f16* omh = omhi + (size_t)h * M_ * DK_;
    const f16* oml = omlo + (size_t)h * M_ * DK_;

    f32x4 kvacc[5][2];
    #pragma unroll
    for (int d = 0; d < 5; ++d)
        #pragma unroll
        for (int j = 0; j < 2; ++j)
            kvacc[d][j] = (f32x4){0.f, 0.f, 0.f, 0.f};

    // prologue: om (once) + K0
    STAGEOM_(sOmH, omh);
    STAGEOM_(sOmL, oml);
    STAGEK_(0, 0);

    for (int sub = 0; sub < 8; ++sub) {
        const int cur = sub & 1;
        const int n0 = nsp*1024 + sub*128;

        // (A) everything issued earlier has landed; prev kv readers done
        asm volatile("s_waitcnt vmcnt(0) lgkmcnt(0)");
        SBAR_();
        BAR_();

        // issue this iter's loads: mask (reg), VT(sub), K(sub+1)
        int4 mv4 = *(const int4*)&mask[b*N_ + n0 + nloc];
        const int* mv = (const int*)&mv4;
        STAGEVT_(sub);
        if (sub < 7) STAGEK_(sub+1, cur^1);

        // ---- feat: proj = K . omega^T (wave owns 16 n-rows) ----
        const char* kb = (const char*)&sK[cur][0];
        const int rowb = wave*16 + m16;
        f16x8 ah0 = *(const f16x8*)(kb + ((rowb*128 +      quad*16) ^ ((rowb & 7) << 4)));
        f16x8 ah1 = *(const f16x8*)(kb + ((rowb*128 + 64 + quad*16) ^ ((rowb & 7) << 4)));

        f32x4 acc[16];
        #pragma unroll
        for (int j = 0; j < 16; ++j) acc[j] = (f32x4){0.f, 0.f, 0.f, 0.f};

        PRIO1_();
        #pragma unroll
        for (int j = 0; j < 16; ++j) {
            int rowm = j*16 + m16;
            int bo0 = (rowm*128 +      quad*16) ^ ((rowm & 7) << 4);
            int bo1 = (rowm*128 + 64 + quad*16) ^ ((rowm & 7) << 4);
            f16x8 bh0 = *(const f16x8*)((const char*)sOmH + bo0);
            f16x8 bh1 = *(const f16x8*)((const char*)sOmH + bo1);
            f16x8 bl0 = *(const f16x8*)((const char*)sOmL + bo0);
            f16x8 bl1 = *(const f16x8*)((const char*)sOmL + bo1);
            acc[j] = __builtin_amdgcn_mfma_f32_16x16x32_f16(ah0, bh0, acc[j], 0,0,0);
            acc[j] = __builtin_amdgcn_mfma_f32_16x16x32_f16(ah0, bl0, acc[j], 0,0,0);
            acc[j] = __builtin_amdgcn_mfma_f32_16x16x32_f16(ah1, bh1, acc[j], 0,0,0);
            acc[j] = __builtin_amdgcn_mfma_f32_16x16x32_f16(ah1, bl1, acc[j], 0,0,0);
        }
        PRIO0_();

        // rowmax + exp  (exact per-n max over all 256 m — matches reference)
        #pragma unroll
        for (int r = 0; r < 4; ++r) {
            float mx = acc[0][r];
            #pragma unroll
            for (int j = 1; j < 16; ++j) mx = fmaxf(mx, acc[j][r]);
            mx = fmaxf(mx, __shfl_xor(mx, 1, 64));
            mx = fmaxf(mx, __shfl_xor(mx, 2, 64));
            mx = fmaxf(mx, __shfl_xor(mx, 4, 64));
            mx = fmaxf(mx, __shfl_xor(mx, 8, 64));
            #pragma unroll
            for (int j = 0; j < 16; ++j)
                acc[j][r] = __expf(acc[j][r] - mx) * inv_sqrt_m;
        }

        // ---- Phi half 0: n-cols 0..63 (waves 0..3) ----
        if (wave < 4) {
            #pragma unroll
            for (int j = 0; j < 16; ++j) {
                bf16x4 pk;
                #pragma unroll
                for (int r = 0; r < 4; ++r)
                    pk[r] = mv[r] ? (bf16)0.0f : (bf16)acc[j][r];
                *(bf16x4*)&sPhi[(j*16 + m16)*PHK_PAD + nloc] = pk;
            }
        }
        asm volatile("s_waitcnt lgkmcnt(0)");
        if (sub < 7) { asm volatile("s_waitcnt vmcnt(2)"); }  // VT landed, K in flight
        else         { asm volatile("s_waitcnt vmcnt(0)"); }
        SBAR_();
        BAR_();   // (C1) PhiA + VT visible

        // ---- kv part 1: n-cols 0..63 ----
        PRIO1_();
        #pragma unroll
        for (int ks = 0; ks < 2; ++ks) {
            bf16x8 av[5], bp[2];
            #pragma unroll
            for (int d = 0; d < 5; ++d) {
                int rowv = d*16 + m16;
                av[d] = *(const bf16x8*)((const char*)sVT +
                        ((rowv*256 + ks*64 + quad*16) ^ ((rowv & 7) << 4)));
            }
            #pragma unroll
            for (int j = 0; j < 2; ++j)
                bp[j] = *(const bf16x8*)&sPhi[(wm + j*16 + m16)*PHK_PAD + ks*32 + quad*8];
            #pragma unroll
            for (int d = 0; d < 5; ++d)
                #pragma unroll
                for (int j = 0; j < 2; ++j)
                    kvacc[d][j] = __builtin_amdgcn_mfma_f32_16x16x32_bf16(
                        av[d], bp[j], kvacc[d][j], 0, 0, 0);
        }
        PRIO0_();
        asm volatile("s_waitcnt lgkmcnt(0)");
        SBAR_();
        BAR_();   // (C2) kv1 reads done; sPhi free

        // ---- Phi half 1: n-cols 64..127 (waves 4..7) ----
        if (wave >= 4) {
            #pragma unroll
            for (int j = 0; j < 16; ++j) {
                bf16x4 pk;
                #pragma unroll
                for (int r = 0; r < 4; ++r)
                    pk[r] = mv[r] ? (bf16)0.0f : (bf16)acc[j][r];
                *(bf16x4*)&sPhi[(j*16 + m16)*PHK_PAD + (nloc - 64)] = pk;
            }
        }
        asm volatile("s_waitcnt lgkmcnt(0)");
        SBAR_();
        BAR_();   // (C3) PhiB visible

        // ---- kv part 2: n-cols 64..127 ----
        PRIO1_();
        #pragma unroll
        for (int ks = 0; ks < 2; ++ks) {
            bf16x8 av[5], bp[2];
            #pragma unroll
            for (int d = 0; d < 5; ++d) {
                int rowv = d*16 + m16;
                av[d] = *(const bf16x8*)((const char*)sVT +
                        ((rowv*256 + 128 + ks*64 + quad*16) ^ ((rowv & 7) << 4)));
            }
            #pragma unroll
            for (int j = 0; j < 2; ++j)
                bp[j] = *(const bf16x8*)&sPhi[(wm + j*16 + m16)*PHK_PAD + ks*32 + quad*8];
            #pragma unroll
            for (int d = 0; d < 5; ++d)
                #pragma unroll
                for (int j = 0; j < 2; ++j)
                    kvacc[d][j] = __builtin_amdgcn_mfma_f32_16x16x32_bf16(
                        av[d], bp[j], kvacc[d][j], 0, 0, 0);
        }
        PRIO0_();
    }

    #pragma unroll
    for (int d = 0; d < 5; ++d)
        #pragma unroll
        for (int j = 0; j < 2; ++j) {
            int drow = d*16 + quad*4;
            int m = wm + j*16 + m16;
            #pragma unroll
            for (int r = 0; r < 4; ++r)
                atomicAdd(&KVt32[((size_t)bh*VTROWS_ + drow + r)*M_ + m],
                          kvacc[d][j][r]);
        }
}

// ---------------------------------------------------------------------------
// fused_ctx v2: 512 threads, grid (4,H,B); om staged into LDS ONCE per block
// and reused across 8 q-tiles. Q and KVb read direct to registers (no sQ/sW,
// no mid-GEMM stage drains). Wave owns 16 q-rows in feat; ctx GEMM 2x4 waves.
// ---------------------------------------------------------------------------
__global__ __launch_bounds__(512, 1)
void fused_ctx(const f16* __restrict__ Qh, const f16* __restrict__ omhi,
               const f16* __restrict__ omlo, const bf16* __restrict__ KVb,
               bf16* __restrict__ ctx)
{
    __shared__ __align__(16) f16  sOmH[M_*DK_];        // 32 KB, swizzled
    __shared__ __align__(16) f16  sOmL[M_*DK_];        // 32 KB, swizzled
    __shared__ __align__(16) bf16 sPhi[128*PHQ_PAD];   // 66 KB [n][264]
    __shared__ float sden[2][128];
    const int nsp = blockIdx.x;          // 0..3
    const int h = blockIdx.y, b = blockIdx.z;
    const int bh = b*H_ + h;
    const int tid = threadIdx.x, lane = tid & 63, wave = tid >> 6;
    const int m16 = lane & 15, quad = lane >> 4;
    const float inv_sqrt_m = rsqrtf((float)M_ + 1e-6f);
    const f16* omh = omhi + (size_t)h * M_ * DK_;
    const f16* oml = omlo + (size_t)h * M_ * DK_;

    STAGEOM_(sOmH, omh);
    STAGEOM_(sOmL, oml);
    asm volatile("s_waitcnt vmcnt(0)");
    SBAR_();
    BAR_();

    const int wq = wave >> 2;            // GEMM q-half
    const int wc = wave & 3;             // GEMM col quarter (32 cols)

    for (int nb = 0; nb < 8; ++nb) {
        const int q0 = nsp*1024 + nb*128;

        // ---- feat (wave owns 16 q-rows) ----
        const int rowq = wave*16 + m16;
        f16x8 ah0 = *(const f16x8*)&Qh[(size_t)(b*N_ + q0 + rowq)*D_ + h*DK_ + quad*8];
        f16x8 ah1 = *(const f16x8*)&Qh[(size_t)(b*N_ + q0 + rowq)*D_ + h*DK_ + 32 + quad*8];

        f32x4 acc[16];
        #pragma unroll
        for (int j = 0; j < 16; ++j) acc[j] = (f32x4){0.f, 0.f, 0.f, 0.f};

        PRIO1_();
        #pragma unroll
        for (int j = 0; j < 16; ++j) {
            int rowm = j*16 + m16;
            int bo0 = (rowm*128 +      quad*16) ^ ((rowm & 7) << 4);
            int bo1 = (rowm*128 + 64 + quad*16) ^ ((rowm & 7) << 4);
            f16x8 bh0 = *(const f16x8*)((const char*)sOmH + bo0);
            f16x8 bh1 = *(const f16x8*)((const char*)sOmH + bo1);
            f16x8 bl0 = *(const f16x8*)((const char*)sOmL + bo0);
            f16x8 bl1 = *(const f16x8*)((const char*)sOmL + bo1);
            acc[j] = __builtin_amdgcn_mfma_f32_16x16x32_f16(ah0, bh0, acc[j], 0,0,0);
            acc[j] = __builtin_amdgcn_mfma_f32_16x16x32_f16(ah0, bl0, acc[j], 0,0,0);
            acc[j] = __builtin_amdgcn_mfma_f32_16x16x32_f16(ah1, bh1, acc[j], 0,0,0);
            acc[j] = __builtin_amdgcn_mfma_f32_16x16x32_f16(ah1, bl1, acc[j], 0,0,0);
        }
        PRIO0_();

        // preload KVb fragments for the GEMM (hidden under softmax+Phi write)
        bf16x8 wf[2][8];
        #pragma unroll
        for (int jr = 0; jr < 2; ++jr) {
            int rowk = wc*32 + jr*16 + m16;
            #pragma unroll
            for (int ks = 0; ks < 8; ++ks)
                wf[jr][ks] = *(const bf16x8*)&KVb[((size_t)bh*KVROWS_ + rowk)*M_
                                                  + ks*32 + quad*8];
        }

        // softmax
        #pragma unroll
        for (int r = 0; r < 4; ++r) {
            float mx = acc[0][r];
            #pragma unroll
            for (int j = 1; j < 16; ++j) mx = fmaxf(mx, acc[j][r]);
            mx = fmaxf(mx, __shfl_xor(mx, 1, 64));
            mx = fmaxf(mx, __shfl_xor(mx, 2, 64));
            mx = fmaxf(mx, __shfl_xor(mx, 4, 64));
            mx = fmaxf(mx, __shfl_xor(mx, 8, 64));
            #pragma unroll
            for (int j = 0; j < 16; ++j)
                acc[j][r] = __expf(acc[j][r] - mx) * inv_sqrt_m;
        }

        // Phi -> sPhi [n][m] (scalar writes, pad 264)
        {
            int nloc0 = wave*16 + quad*4;
            #pragma unroll
            for (int j = 0; j < 16; ++j)
                #pragma unroll
                for (int r = 0; r < 4; ++r)
                    sPhi[(nloc0 + r)*PHQ_PAD + j*16 + m16] = (bf16)acc[j][r];
        }
        asm volatile("s_waitcnt lgkmcnt(0)");
        SBAR_();
        BAR_();   // Phi visible

        // ---- ctx GEMM: C[128 q][128 kvrows], waves 2x4 ----
        f32x4 cacc[4][2];
        #pragma unroll
        for (int i = 0; i < 4; ++i)
            #pragma unroll
            for (int j = 0; j < 2; ++j)
                cacc[i][j] = (f32x4){0.f, 0.f, 0.f, 0.f};

        PRIO1_();
        #pragma unroll
        for (int ks = 0; ks < 8; ++ks) {
            bf16x8 af[4];
            #pragma unroll
            for (int i = 0; i < 4; ++i)
                af[i] = *(const bf16x8*)&sPhi[(wq*64 + i*16 + m16)*PHQ_PAD
                                              + ks*32 + quad*8];
            #pragma unroll
            for (int i = 0; i < 4; ++i)
                #pragma unroll
                for (int jr = 0; jr < 2; ++jr)
                    cacc[i][jr] = __builtin_amdgcn_mfma_f32_16x16x32_bf16(
                        af[i], wf[jr][ks], cacc[i][jr], 0, 0, 0);
        }
        PRIO0_();

        // den = cols 64 (ksum_hi) + 65 (ksum_lo): owned by wc==2, jr==0
        if (wc == 2 && m16 < 2) {
            #pragma unroll
            for (int i = 0; i < 4; ++i)
                #pragma unroll
                for (int r = 0; r < 4; ++r)
                    sden[m16][wq*64 + i*16 + quad*4 + r] = cacc[i][0][r];
        }
        asm volatile("s_waitcnt lgkmcnt(0)");
        SBAR_();
        BAR_();   // sden visible

        if (wc < 2) {
            #pragma unroll
            for (int i = 0; i < 4; ++i) {
                #pragma unroll
                for (int r = 0; r < 4; ++r) {
                    int lrow = wq*64 + i*16 + quad*4 + r;
                    float den = sden[0][lrow] + sden[1][lrow] + EPS_;
                    #pragma unroll
                    for (int jr = 0; jr < 2; ++jr)
                        ctx[(size_t)(b*N_ + q0 + lrow)*D_ + h*DK_
                            + wc*32 + jr*16 + m16] = (bf16)(cacc[i][jr][r] / den);
                }
            }
        }
        asm volatile("s_waitcnt lgkmcnt(0)");
        SBAR_();
        BAR_();   // sPhi/sden free for next nb
    }
}

// ---------------------------------------------------------------------------
// Output projection: out = mask ? 0 : ctx @ Wout^T + bout   (bf16 MFMA, fp32 out)
// ---------------------------------------------------------------------------
__global__ __launch_bounds__(256)
void gemm_out(const bf16* __restrict__ A, const bf16* __restrict__ W,
              const float* __restrict__ bias, float* __restrict__ C,
              const int* __restrict__ mask)
{
    __shared__ bf16 sA[128*64];
    __shared__ bf16 sB[128*64];
    const int tid  = threadIdx.x;
    const int bm   = blockIdx.y * 128;
    const int bn   = blockIdx.x * 128;
    const int lane = tid & 63, wave = tid >> 6;
    const int wm   = (wave & 1) * 64, wn = (wave >> 1) * 64;
    const int m16  = lane & 15, quad = lane >> 4;

    f32x4 acc[4][4];
    #pragma unroll
    for (int i = 0; i < 4; ++i)
        #pragma unroll
        for (int j = 0; j < 4; ++j)
            acc[i][j] = (f32x4){0.f, 0.f, 0.f, 0.f};

    for (int k0 = 0; k0 < D_; k0 += 64) {
        __syncthreads();
        #pragma unroll
        for (int it = 0; it < 4; ++it) {
            int idx = it*256 + tid;
            int row = idx >> 3, seg = idx & 7;
            GLD(A + (size_t)(bm + row) * D_ + k0 + seg*8, &sA[idx*8]);
            GLD(W + (size_t)(bn + row) * D_ + k0 + seg*8, &sB[idx*8]);
        }
        __syncthreads();
        #pragma unroll
        for (int kk = 0; kk < 64; kk += 32) {
            bf16x8 af[4], bfr[4];
            #pragma unroll
            for (int i = 0; i < 4; ++i)
                af[i] = *(const bf16x8*)&sA[(wm + i*16 + m16)*64 + kk + quad*8];
            #pragma unroll
            for (int j = 0; j < 4; ++j)
                bfr[j] = *(const bf16x8*)&sB[(wn + j*16 + m16)*64 + kk + quad*8];
            #pragma unroll
            for (int i = 0; i < 4; ++i)
                #pragma unroll
                for (int j = 0; j < 4; ++j)
                    acc[i][j] = __builtin_amdgcn_mfma_f32_16x16x32_bf16(
                        af[i], bfr[j], acc[i][j], 0, 0, 0);
        }
    }

    #pragma unroll
    for (int j = 0; j < 4; ++j) {
        int col = bn + wn + j*16 + m16;
        float bv = bias[col];
        #pragma unroll
        for (int i = 0; i < 4; ++i) {
            int row0 = bm + wm + i*16 + quad*4;
            #pragma unroll
            for (int r = 0; r < 4; ++r) {
                int row = row0 + r;
                float v = acc[i][j][r] + bv;
                if (mask[row] != 0) v = 0.0f;
                C[(size_t)row * D_ + col] = v;
            }
        }
    }
}

// ---------------------------------------------------------------------------
extern "C" void kernel_launch(void* const* d_in, const int* in_sizes, int n_in,
                              void* d_out, int out_size, void* d_ws, size_t ws_size,
                              hipStream_t stream)
{
    const float* x     = (const float*)d_in[0];
    const int*   mask  = (const int*)d_in[1];     // 1 = PAD
    const float* Wqkv  = (const float*)d_in[2];
    const float* bqkv  = (const float*)d_in[3];
    const float* Wout  = (const float*)d_in[4];
    const float* bout  = (const float*)d_in[5];
    const float* omega = (const float*)d_in[6];
    float* out = (float*)d_out;

    char* w = (char*)d_ws;
    f16*   Wh    = (f16*)w;    w += (size_t)3*D_*D_ * 2;              //   6.29 MB
    bf16*  Wob   = (bf16*)w;   w += (size_t)D_*D_ * 2;                //   2.10 MB
    f16*   omhi  = (f16*)w;    w += (size_t)H_*M_*DK_ * 2;            //   0.52 MB
    f16*   omlo  = (f16*)w;    w += (size_t)H_*M_*DK_ * 2;            //   0.52 MB
    f16*   xh    = (f16*)w;    w += (size_t)R_ * D_ * 2;              //  33.55 MB
    f16*   Qh    = (f16*)w;    w += (size_t)R_ * D_ * 2;              //  33.55 MB
    f16*   Kh    = (f16*)w;    w += (size_t)R_ * D_ * 2;              //  33.55 MB (-> ctx)
    bf16*  VT    = (bf16*)w;   w += (size_t)B_*H_*VTROWS_*N_ * 2;     //  41.94 MB
    float* KVt32 = (float*)w;  w += (size_t)B_*H_*VTROWS_*M_ * 4;     //   5.24 MB
    bf16*  KVb   = (bf16*)w;   w += (size_t)B_*H_*KVROWS_*M_ * 2;     //   4.19 MB
    bf16*  VC    = (bf16*)Kh;                                         // alias (Kh dead after fused_kv)

    // 0) prep
    split_f16v<<<(R_*D_/4 + 255)/256, 256, 0, stream>>>(x, xh, nullptr, R_*D_/4);
    split_f16v<<<(3*D_*D_/4 + 255)/256, 256, 0, stream>>>(Wqkv, Wh, nullptr, 3*D_*D_/4);
    split_f16v<<<(H_*M_*DK_/4 + 255)/256, 256, 0, stream>>>(omega, omhi, omlo, H_*M_*DK_/4);
    f32_to_bf16v<<<(D_*D_/4 + 255)/256, 256, 0, stream>>>(Wout, Wob, D_*D_/4);
    zero_f32<<<(B_*H_*VTROWS_*M_ + 255)/256, 256, 0, stream>>>(KVt32, B_*H_*VTROWS_*M_);
    init_vt<<<(B_*H_*16*N_ + 255)/256, 256, 0, stream>>>(VT);

    // 1) unified QKV projection (fp16, 256^2 8-phase): Qh, Kh fp16; V -> VT bf16
    gemm_qkv<<<dim3(3*D_/256, R_/256), 512, 0, stream>>>(xh, Wh, bqkv, Qh, Kh, VT);

    // 2) fused K-features + KV/ksum accumulation (Phi_K in LDS only)
    fused_kv<<<dim3(4, H_, B_), 512, 0, stream>>>(Kh, VT, omhi, omlo, mask, KVt32);

    // 3) pack KVt32 -> KVb bf16 (ksum hi/lo rows 64/65, zero pad to 128)
    pack_kv<<<(B_*H_*KVROWS_*M_ + 255)/256, 256, 0, stream>>>(KVt32, KVb);

    // 4) fused Q-features + ctx (Phi_Q in LDS only) -> VC bf16 (aliases Kh)
    fused_ctx<<<dim3(4, H_, B_), 512, 0, stream>>>(Qh, omhi, omlo, KVb, VC);

    // 5) output projection + bias + PAD-query zeroing -> fp32 out
    gemm_out<<<dim3(8, R_/128), 256, 0, stream>>>(VC, Wob, bout, out, mask);
}

// Round 7
// 438.876 us; speedup vs baseline: 1.4754x; 1.0424x over previous
//
#include <hip/hip_runtime.h>
#include <hip/hip_bf16.h>
#include <math.h>

#define B_  4
#define N_  4096
#define D_  1024
#define H_  16
#define DK_ 64
#define M_  256
#define R_  (B_*N_)          // 16384 rows
#define EPS_ 1e-6f
#define VTROWS_ 80           // 64 V rows + row64=ones(ksum) + 65..79 pad
#define KVROWS_ 128          // KVb bf16: 64 KV + 64=ksum_hi + 65=ksum_lo + 0-pad
#define PHK_PAD 68           // fused_kv  Phi LDS [m][68]  (n-HALF + pad)
#define PHQ_PAD 264          // fused_ctx Phi LDS [n][264]

typedef __bf16 bf16;
typedef __bf16 bf16x4 __attribute__((ext_vector_type(4)));
typedef __bf16 bf16x8 __attribute__((ext_vector_type(8)));
typedef _Float16 f16;
typedef _Float16 f16x4 __attribute__((ext_vector_type(4)));
typedef _Float16 f16x8 __attribute__((ext_vector_type(8)));
typedef float  f32x4  __attribute__((ext_vector_type(4)));

#define GLD(gp, lp) __builtin_amdgcn_global_load_lds( \
    (const __attribute__((address_space(1))) void*)(gp), \
    (__attribute__((address_space(3))) void*)(lp), 16, 0, 0)

#define BAR_()   __builtin_amdgcn_s_barrier()
#define SBAR_()  __builtin_amdgcn_sched_barrier(0)
#define PRIO1_() __builtin_amdgcn_s_setprio(1)
#define PRIO0_() __builtin_amdgcn_s_setprio(0)
#define LGK0_()  do { asm volatile("s_waitcnt lgkmcnt(0)"); SBAR_(); } while (0)
#define LGK8_()  asm volatile("s_waitcnt lgkmcnt(8)")
#define VMC4_()  do { asm volatile("s_waitcnt vmcnt(4)"); SBAR_(); } while (0)

// ---------------------------------------------------------------------------
// prep kernels
// ---------------------------------------------------------------------------
__global__ __launch_bounds__(256)
void split_f16v(const float* __restrict__ in, f16* __restrict__ hi,
                f16* __restrict__ lo, int n4)
{
    int i = blockIdx.x * 256 + threadIdx.x;
    if (i < n4) {
        float4 v = ((const float4*)in)[i];
        f16x4 h = { (f16)v.x, (f16)v.y, (f16)v.z, (f16)v.w };
        ((f16x4*)hi)[i] = h;
        if (lo) {
            f16x4 l = { (f16)(v.x - (float)h[0]), (f16)(v.y - (float)h[1]),
                        (f16)(v.z - (float)h[2]), (f16)(v.w - (float)h[3]) };
            ((f16x4*)lo)[i] = l;
        }
    }
}

__global__ __launch_bounds__(256)
void f32_to_bf16v(const float* __restrict__ in, bf16* __restrict__ o, int n4)
{
    int i = blockIdx.x * 256 + threadIdx.x;
    if (i < n4) {
        float4 v = ((const float4*)in)[i];
        bf16x4 h = { (bf16)v.x, (bf16)v.y, (bf16)v.z, (bf16)v.w };
        ((bf16x4*)o)[i] = h;
    }
}

__global__ __launch_bounds__(256)
void zero_f32(float* __restrict__ p, int n)
{
    int i = blockIdx.x * 256 + threadIdx.x;
    if (i < n) p[i] = 0.f;
}

__global__ __launch_bounds__(256)
void init_vt(bf16* __restrict__ VT)
{
    int i = blockIdx.x * 256 + threadIdx.x;          // 64bh x 16rows x 4096
    if (i >= B_*H_*16*N_) return;
    int bh  = i >> 16;
    int rem = i & 65535;
    int row = 64 + (rem >> 12);
    int n   = rem & (N_-1);
    VT[((size_t)bh*VTROWS_ + row)*N_ + n] = (row == 64) ? (bf16)1.0f : (bf16)0.0f;
}

__global__ __launch_bounds__(256)
void pack_kv(const float* __restrict__ KVt32, bf16* __restrict__ KVb)
{
    int i = blockIdx.x * 256 + threadIdx.x;          // 64bh x 128 x 256
    if (i >= B_*H_*KVROWS_*M_) return;
    int bh  = i >> 15;
    int rem = i & 32767;
    int row = rem >> 8;
    int m   = rem & (M_-1);
    bf16 o = (bf16)0.0f;
    if (row < 64) {
        o = (bf16)KVt32[((size_t)bh*VTROWS_ + row)*M_ + m];
    } else if (row == 64) {
        o = (bf16)KVt32[((size_t)bh*VTROWS_ + 64)*M_ + m];
    } else if (row == 65) {
        float v = KVt32[((size_t)bh*VTROWS_ + 64)*M_ + m];
        o = (bf16)(v - (float)(bf16)v);
    }
    KVb[i] = o;
}

// ---------------------------------------------------------------------------
// 8-phase 256x256 GEMM machinery (shared macros).
// SWAPPED mfma (operands reversed) gives D[bcol][arow]: per lane the 4 regs
// are 4 CONSECUTIVE output columns -> packed 8B/16B epilogue stores.
// ---------------------------------------------------------------------------
#define STAGE_(dstbuf, srcp, kt, half) do { \
    _Pragma("unroll") \
    for (int q_ = 0; q_ < 2; ++q_) { \
        int idx_ = q_*512 + tid; \
        int row_ = idx_ >> 3; \
        int seg_ = (idx_ & 7) ^ (row_ & 7); \
        GLD((srcp) + (size_t)((half)*128 + row_) * D_ + (kt)*64 + seg_*8, \
            &(dstbuf)[(half)*8192 + idx_*8]); \
    } } while (0)

#define LDA_G(T, buf, i0) do { \
    _Pragma("unroll") \
    for (int i_ = 0; i_ < 4; ++i_) { \
        _Pragma("unroll") \
        for (int k_ = 0; k_ < 2; ++k_) { \
            int row_ = warp_m*128 + ((i0)+i_)*16 + m16; \
            int off_ = (row_*128 + k_*64 + quad*16) ^ ((row_ & 7) << 4); \
            a[i_][k_] = *(const T*)((const char*)(buf) + off_); \
        } } } while (0)

#define LDB_G(T, buf, j0) do { \
    _Pragma("unroll") \
    for (int j_ = 0; j_ < 2; ++j_) { \
        _Pragma("unroll") \
        for (int k_ = 0; k_ < 2; ++k_) { \
            int row_ = warp_n*64 + ((j0)+j_)*16 + m16; \
            int off_ = (row_*128 + k_*64 + quad*16) ^ ((row_ & 7) << 4); \
            b[(j0)+j_][k_] = *(const T*)((const char*)(buf) + off_); \
        } } } while (0)

#define MFMA_F16N(I0, J0) do { \
    _Pragma("unroll") \
    for (int i_ = 0; i_ < 4; ++i_) \
        _Pragma("unroll") \
        for (int j_ = 0; j_ < 2; ++j_) \
            _Pragma("unroll") \
            for (int k_ = 0; k_ < 2; ++k_) \
                acc[(I0)+i_][(J0)+j_] = __builtin_amdgcn_mfma_f32_16x16x32_f16( \
                    a[i_][k_], b[(J0)+j_][k_], acc[(I0)+i_][(J0)+j_], 0, 0, 0); \
    } while (0)

#define MFMA_F16S(I0, J0) do { \
    _Pragma("unroll") \
    for (int i_ = 0; i_ < 4; ++i_) \
        _Pragma("unroll") \
        for (int j_ = 0; j_ < 2; ++j_) \
            _Pragma("unroll") \
            for (int k_ = 0; k_ < 2; ++k_) \
                acc[(I0)+i_][(J0)+j_] = __builtin_amdgcn_mfma_f32_16x16x32_f16( \
                    b[(J0)+j_][k_], a[i_][k_], acc[(I0)+i_][(J0)+j_], 0, 0, 0); \
    } while (0)

#define MFMA_BF16S(I0, J0) do { \
    _Pragma("unroll") \
    for (int i_ = 0; i_ < 4; ++i_) \
        _Pragma("unroll") \
        for (int j_ = 0; j_ < 2; ++j_) \
            _Pragma("unroll") \
            for (int k_ = 0; k_ < 2; ++k_) \
                acc[(I0)+i_][(J0)+j_] = __builtin_amdgcn_mfma_f32_16x16x32_bf16( \
                    b[(J0)+j_][k_], a[i_][k_], acc[(I0)+i_][(J0)+j_], 0, 0, 0); \
    } while (0)

// The verified 8-phase K-loop (round-5 gemm_qkv), MFMA op selectable.
#define KLOOP_8PH(MFMA_OP) \
    STAGE_(sA[0], gA, 0, 0); \
    STAGE_(sA[0], gA, 0, 1); \
    STAGE_(sB[0], gB, 0, 0); \
    STAGE_(sB[0], gB, 0, 1); \
    STAGE_(sB[1], gB, 1, 0); \
    STAGE_(sB[1], gB, 1, 1); \
    VMC4_(); \
    BAR_(); \
    for (int it = 0; it < 8; ++it) { \
        const int t1 = 2*it + 1, t2 = 2*it + 2, t3 = 2*it + 3; \
        LDA_G(FRAG_T, sA[0], 0); LDB_G(FRAG_T, sB[0], 0); \
        STAGE_(sA[1], gA, t1, 0); \
        LGK8_(); \
        BAR_(); LGK0_(); \
        PRIO1_(); MFMA_OP(0, 0); PRIO0_(); \
        BAR_(); \
        LDB_G(FRAG_T, sB[0], 2); \
        STAGE_(sA[1], gA, t1, 1); \
        BAR_(); LGK0_(); \
        PRIO1_(); MFMA_OP(0, 2); PRIO0_(); \
        BAR_(); \
        LDA_G(FRAG_T, sA[0], 4); \
        if (t2 < 16) STAGE_(sB[0], gB, t2, 0); \
        BAR_(); LGK0_(); \
        PRIO1_(); MFMA_OP(4, 2); PRIO0_(); \
        BAR_(); \
        if (t2 < 16) STAGE_(sB[0], gB, t2, 1); \
        VMC4_(); \
        BAR_(); \
        PRIO1_(); MFMA_OP(4, 0); PRIO0_(); \
        BAR_(); \
        LDA_G(FRAG_T, sA[1], 0); LDB_G(FRAG_T, sB[1], 0); \
        if (t2 < 16) STAGE_(sA[0], gA, t2, 0); \
        LGK8_(); \
        BAR_(); LGK0_(); \
        PRIO1_(); MFMA_OP(0, 0); PRIO0_(); \
        BAR_(); \
        LDB_G(FRAG_T, sB[1], 2); \
        if (t2 < 16) STAGE_(sA[0], gA, t2, 1); \
        BAR_(); LGK0_(); \
        PRIO1_(); MFMA_OP(0, 2); PRIO0_(); \
        BAR_(); \
        LDA_G(FRAG_T, sA[1], 4); \
        if (t3 < 16) STAGE_(sB[1], gB, t3, 0); \
        BAR_(); LGK0_(); \
        PRIO1_(); MFMA_OP(4, 2); PRIO0_(); \
        BAR_(); \
        if (t3 < 16) STAGE_(sB[1], gB, t3, 1); \
        VMC4_(); \
        BAR_(); \
        PRIO1_(); MFMA_OP(4, 0); PRIO0_(); \
        BAR_(); \
    }

// ---------------------------------------------------------------------------
// QKV projection, Q/K columns (bn 0..7). SWAPPED mfma -> packed f16x4 stores.
// ---------------------------------------------------------------------------
#define FRAG_T f16x8
__global__ __launch_bounds__(512)
void gemm_qkv_qk(const f16* __restrict__ X, const f16* __restrict__ Wh,
                 const float* __restrict__ bqkv,
                 f16* __restrict__ Qh, f16* __restrict__ Kh)
{
    __shared__ __align__(16) f16 sA[2][256*64];   // 64 KB
    __shared__ __align__(16) f16 sB[2][256*64];   // 64 KB
    const int tid = threadIdx.x;

    const int nwg = gridDim.x * gridDim.y;        // 512
    int flat = blockIdx.y * gridDim.x + blockIdx.x;
    int wgid = (flat & 7) * (nwg >> 3) + (flat >> 3);
    const int bm = (wgid >> 3) * 256;
    const int bn = (wgid & 7) * 256;              // 0..1792: Q (<1024) or K

    const int lane = tid & 63, wave = tid >> 6;
    const int warp_m = wave >> 2, warp_n = wave & 3;
    const int m16 = lane & 15, quad = lane >> 4;

    const f16* gA = X  + (size_t)bm * D_;
    const f16* gB = Wh + (size_t)bn * D_;

    f32x4 acc[8][4];
    #pragma unroll
    for (int i = 0; i < 8; ++i)
        #pragma unroll
        for (int j = 0; j < 4; ++j)
            acc[i][j] = (f32x4){0.f, 0.f, 0.f, 0.f};
    f16x8 a[4][2], b[4][2];

    KLOOP_8PH(MFMA_F16S)

    // swapped epilogue: lane(m16,quad), reg r -> C[row=..+m16][col=..+quad*4+r]
    f16* outp = (bn >= D_) ? Kh : Qh;
    const int cofs = (bn >= D_) ? D_ : 0;
    #pragma unroll
    for (int j = 0; j < 4; ++j) {
        int gcol0 = bn + warp_n*64 + j*16 + quad*4;
        float4 bv = *(const float4*)&bqkv[gcol0];
        int col0 = gcol0 - cofs;
        #pragma unroll
        for (int i = 0; i < 8; ++i) {
            int row = bm + warp_m*128 + i*16 + m16;
            f16x4 pk = { (f16)(acc[i][j][0] + bv.x), (f16)(acc[i][j][1] + bv.y),
                         (f16)(acc[i][j][2] + bv.z), (f16)(acc[i][j][3] + bv.w) };
            *(f16x4*)&outp[(size_t)row * D_ + col0] = pk;
        }
    }
}

// ---------------------------------------------------------------------------
// QKV projection, V columns (bn 8..11). Normal mfma; V stores bf16x4 along n
// into transposed VT (already packed 8B — keep round-5 proven path).
// ---------------------------------------------------------------------------
__global__ __launch_bounds__(512)
void gemm_qkv_v(const f16* __restrict__ X, const f16* __restrict__ Wh,
                const float* __restrict__ bqkv, bf16* __restrict__ VT)
{
    __shared__ __align__(16) f16 sA[2][256*64];
    __shared__ __align__(16) f16 sB[2][256*64];
    const int tid = threadIdx.x;

    const int nwg = gridDim.x * gridDim.y;        // 256
    int flat = blockIdx.y * gridDim.x + blockIdx.x;
    int wgid = (flat & 7) * (nwg >> 3) + (flat >> 3);
    const int bm = (wgid >> 2) * 256;
    const int bn = 2*D_ + (wgid & 3) * 256;       // V cols

    const int lane = tid & 63, wave = tid >> 6;
    const int warp_m = wave >> 2, warp_n = wave & 3;
    const int m16 = lane & 15, quad = lane >> 4;

    const f16* gA = X  + (size_t)bm * D_;
    const f16* gB = Wh + (size_t)bn * D_;

    f32x4 acc[8][4];
    #pragma unroll
    for (int i = 0; i < 8; ++i)
        #pragma unroll
        for (int j = 0; j < 4; ++j)
            acc[i][j] = (f32x4){0.f, 0.f, 0.f, 0.f};
    f16x8 a[4][2], b[4][2];

    KLOOP_8PH(MFMA_F16N)

    #pragma unroll
    for (int j = 0; j < 4; ++j) {
        int gcol = bn + warp_n*64 + j*16 + m16;
        float bv = bqkv[gcol];
        int vcol = gcol - 2*D_;
        int hh = vcol >> 6, dd = vcol & 63;
        #pragma unroll
        for (int i = 0; i < 8; ++i) {
            int row0 = bm + warp_m*128 + i*16 + quad*4;
            int bb = row0 >> 12, nn = row0 & (N_-1);
            bf16x4 pk = { (bf16)(acc[i][j][0]+bv), (bf16)(acc[i][j][1]+bv),
                          (bf16)(acc[i][j][2]+bv), (bf16)(acc[i][j][3]+bv) };
            *(bf16x4*)&VT[(((size_t)bb*H_+hh)*VTROWS_ + dd)*N_ + nn] = pk;
        }
    }
}
#undef FRAG_T

// ---------------------------------------------------------------------------
// Output projection, 8-phase 256x256, SWAPPED bf16 mfma -> float4 C stores.
// ---------------------------------------------------------------------------
#define FRAG_T bf16x8
__global__ __launch_bounds__(512)
void gemm_out8(const bf16* __restrict__ A, const bf16* __restrict__ W,
               const float* __restrict__ bias, float* __restrict__ C,
               const int* __restrict__ mask)
{
    __shared__ __align__(16) bf16 sA[2][256*64];
    __shared__ __align__(16) bf16 sB[2][256*64];
    const int tid = threadIdx.x;

    const int nwg = gridDim.x * gridDim.y;        // 256
    int flat = blockIdx.y * gridDim.x + blockIdx.x;
    int wgid = (flat & 7) * (nwg >> 3) + (flat >> 3);
    const int bm = (wgid >> 2) * 256;
    const int bn = (wgid & 3) * 256;

    const int lane = tid & 63, wave = tid >> 6;
    const int warp_m = wave >> 2, warp_n = wave & 3;
    const int m16 = lane & 15, quad = lane >> 4;

    const bf16* gA = A + (size_t)bm * D_;
    const bf16* gB = W + (size_t)bn * D_;

    f32x4 acc[8][4];
    #pragma unroll
    for (int i = 0; i < 8; ++i)
        #pragma unroll
        for (int j = 0; j < 4; ++j)
            acc[i][j] = (f32x4){0.f, 0.f, 0.f, 0.f};
    bf16x8 a[4][2], b[4][2];

    KLOOP_8PH(MFMA_BF16S)

    #pragma unroll
    for (int j = 0; j < 4; ++j) {
        int col0 = bn + warp_n*64 + j*16 + quad*4;
        float4 bv = *(const float4*)&bias[col0];
        #pragma unroll
        for (int i = 0; i < 8; ++i) {
            int row = bm + warp_m*128 + i*16 + m16;
            float4 v;
            if (mask[row] != 0) {
                v = make_float4(0.f, 0.f, 0.f, 0.f);
            } else {
                v = make_float4(acc[i][j][0] + bv.x, acc[i][j][1] + bv.y,
                                acc[i][j][2] + bv.z, acc[i][j][3] + bv.w);
            }
            *(float4*)&C[(size_t)row * D_ + col0] = v;
        }
    }
}
#undef FRAG_T

// ---------------------------------------------------------------------------
// fused_kv (unchanged from round 5)
// ---------------------------------------------------------------------------
#define STAGEK_(sub_, bi_) do { \
    const int n0_ = nsp*1024 + (sub_)*128; \
    _Pragma("unroll") \
    for (int it_ = 0; it_ < 2; ++it_) { \
        int idx_ = it_*512 + tid; \
        int row_ = idx_ >> 3, seg_ = (idx_ & 7) ^ (row_ & 7); \
        GLD(Kh + (size_t)(b*N_ + n0_ + row_) * D_ + h*DK_ + seg_*8, \
            &sK[bi_][idx_*8]); \
    } } while (0)

#define STAGEVT_(sub_) do { \
    const int n0_ = nsp*1024 + (sub_)*128; \
    _Pragma("unroll") \
    for (int it_ = 0; it_ < 2; ++it_) { \
        int idx_ = it_*512 + tid; \
        int row_ = idx_ >> 4, seg_ = (idx_ & 15) ^ (row_ & 7); \
        GLD(VT + ((size_t)bh*VTROWS_ + row_)*N_ + n0_ + seg_*8, \
            &sVT[idx_*8]); \
    } \
    if (tid < 256) { \
        int idx_ = 1024 + tid; \
        int row_ = idx_ >> 4, seg_ = (idx_ & 15) ^ (row_ & 7); \
        GLD(VT + ((size_t)bh*VTROWS_ + row_)*N_ + n0_ + seg_*8, \
            &sVT[idx_*8]); \
    } } while (0)

#define STAGEOM_(arr_, src_) do { \
    _Pragma("unroll") \
    for (int q_ = 0; q_ < 4; ++q_) { \
        int idx_ = q_*512 + tid; \
        int row_ = idx_ >> 3, seg_ = (idx_ & 7) ^ (row_ & 7); \
        GLD((src_) + (size_t)row_*DK_ + seg_*8, &(arr_)[idx_*8]); \
    } } while (0)

__global__ __launch_bounds__(512, 1)
void fused_kv(const f16* __restrict__ Kh, const bf16* __restrict__ VT,
              const f16* __restrict__ omhi, const f16* __restrict__ omlo,
              const int* __restrict__ mask, float* __restrict__ KVt32)
{
    __shared__ __align__(16) f16  sK[2][128*64];      // 32 KB, swizzled
    __shared__ __align__(16) bf16 sVT[VTROWS_*128];   // 20 KB single, swizzled
    __shared__ __align__(16) f16  sOmH[M_*DK_];       // 32 KB, swizzled
    __shared__ __align__(16) f16  sOmL[M_*DK_];       // 32 KB, swizzled
    __shared__ __align__(16) bf16 sPhi[M_*PHK_PAD];   // 34 KB  [m][68] n-half
    const int nsp = blockIdx.x;          // 0..3
    const int h = blockIdx.y, b = blockIdx.z;
    const int bh = b*H_ + h;
    const int tid = threadIdx.x, lane = tid & 63, wave = tid >> 6;
    const int m16 = lane & 15, quad = lane >> 4;
    const int wm = wave * 32;            // wave's m-range for kv MFMA
    const int nloc = wave*16 + quad*4;   // wave's n-rows: wave*16..+15
    const float inv_sqrt_m = rsqrtf((float)M_ + 1e-6f);
    const f16* omh = omhi + (size_t)h * M_ * DK_;
    const f16* oml = omlo + (size_t)h * M_ * DK_;

    f32x4 kvacc[5][2];
    #pragma unroll
    for (int d = 0; d < 5; ++d)
        #pragma unroll
        for (int j = 0; j < 2; ++j)
            kvacc[d][j] = (f32x4){0.f, 0.f, 0.f, 0.f};

    STAGEOM_(sOmH, omh);
    STAGEOM_(sOmL, oml);
    STAGEK_(0, 0);

    for (int sub = 0; sub < 8; ++sub) {
        const int cur = sub & 1;
        const int n0 = nsp*1024 + sub*128;

        asm volatile("s_waitcnt vmcnt(0) lgkmcnt(0)");
        SBAR_();
        BAR_();

        int4 mv4 = *(const int4*)&mask[b*N_ + n0 + nloc];
        const int* mv = (const int*)&mv4;
        STAGEVT_(sub);
        if (sub < 7) STAGEK_(sub+1, cur^1);

        const char* kb = (const char*)&sK[cur][0];
        const int rowb = wave*16 + m16;
        f16x8 ah0 = *(const f16x8*)(kb + ((rowb*128 +      quad*16) ^ ((rowb & 7) << 4)));
        f16x8 ah1 = *(const f16x8*)(kb + ((rowb*128 + 64 + quad*16) ^ ((rowb & 7) << 4)));

        f32x4 acc[16];
        #pragma unroll
        for (int j = 0; j < 16; ++j) acc[j] = (f32x4){0.f, 0.f, 0.f, 0.f};

        PRIO1_();
        #pragma unroll
        for (int j = 0; j < 16; ++j) {
            int rowm = j*16 + m16;
            int bo0 = (rowm*128 +      quad*16) ^ ((rowm & 7) << 4);
            int bo1 = (rowm*128 + 64 + quad*16) ^ ((rowm & 7) << 4);
            f16x8 bh0 = *(const f16x8*)((const char*)sOmH + bo0);
            f16x8 bh1 = *(const f16x8*)((const char*)sOmH + bo1);
            f16x8 bl0 = *(const f16x8*)((const char*)sOmL + bo0);
            f16x8 bl1 = *(const f16x8*)((const char*)sOmL + bo1);
            acc[j] = __builtin_amdgcn_mfma_f32_16x16x32_f16(ah0, bh0, acc[j], 0,0,0);
            acc[j] = __builtin_amdgcn_mfma_f32_16x16x32_f16(ah0, bl0, acc[j], 0,0,0);
            acc[j] = __builtin_amdgcn_mfma_f32_16x16x32_f16(ah1, bh1, acc[j], 0,0,0);
            acc[j] = __builtin_amdgcn_mfma_f32_16x16x32_f16(ah1, bl1, acc[j], 0,0,0);
        }
        PRIO0_();

        #pragma unroll
        for (int r = 0; r < 4; ++r) {
            float mx = acc[0][r];
            #pragma unroll
            for (int j = 1; j < 16; ++j) mx = fmaxf(mx, acc[j][r]);
            mx = fmaxf(mx, __shfl_xor(mx, 1, 64));
            mx = fmaxf(mx, __shfl_xor(mx, 2, 64));
            mx = fmaxf(mx, __shfl_xor(mx, 4, 64));
            mx = fmaxf(mx, __shfl_xor(mx, 8, 64));
            #pragma unroll
            for (int j = 0; j < 16; ++j)
                acc[j][r] = __expf(acc[j][r] - mx) * inv_sqrt_m;
        }

        if (wave < 4) {
            #pragma unroll
            for (int j = 0; j < 16; ++j) {
                bf16x4 pk;
                #pragma unroll
                for (int r = 0; r < 4; ++r)
                    pk[r] = mv[r] ? (bf16)0.0f : (bf16)acc[j][r];
                *(bf16x4*)&sPhi[(j*16 + m16)*PHK_PAD + nloc] = pk;
            }
        }
        asm volatile("s_waitcnt lgkmcnt(0)");
        if (sub < 7) { asm volatile("s_waitcnt vmcnt(2)"); }
        else         { asm volatile("s_waitcnt vmcnt(0)"); }
        SBAR_();
        BAR_();   // (C1) PhiA + VT visible

        PRIO1_();
        #pragma unroll
        for (int ks = 0; ks < 2; ++ks) {
            bf16x8 av[5], bp[2];
            #pragma unroll
            for (int d = 0; d < 5; ++d) {
                int rowv = d*16 + m16;
                av[d] = *(const bf16x8*)((const char*)sVT +
                        ((rowv*256 + ks*64 + quad*16) ^ ((rowv & 7) << 4)));
            }
            #pragma unroll
            for (int j = 0; j < 2; ++j)
                bp[j] = *(const bf16x8*)&sPhi[(wm + j*16 + m16)*PHK_PAD + ks*32 + quad*8];
            #pragma unroll
            for (int d = 0; d < 5; ++d)
                #pragma unroll
                for (int j = 0; j < 2; ++j)
                    kvacc[d][j] = __builtin_amdgcn_mfma_f32_16x16x32_bf16(
                        av[d], bp[j], kvacc[d][j], 0, 0, 0);
        }
        PRIO0_();
        asm volatile("s_waitcnt lgkmcnt(0)");
        SBAR_();
        BAR_();   // (C2)

        if (wave >= 4) {
            #pragma unroll
            for (int j = 0; j < 16; ++j) {
                bf16x4 pk;
                #pragma unroll
                for (int r = 0; r < 4; ++r)
                    pk[r] = mv[r] ? (bf16)0.0f : (bf16)acc[j][r];
                *(bf16x4*)&sPhi[(j*16 + m16)*PHK_PAD + (nloc - 64)] = pk;
            }
        }
        asm volatile("s_waitcnt lgkmcnt(0)");
        SBAR_();
        BAR_();   // (C3)

        PRIO1_();
        #pragma unroll
        for (int ks = 0; ks < 2; ++ks) {
            bf16x8 av[5], bp[2];
            #pragma unroll
            for (int d = 0; d < 5; ++d) {
                int rowv = d*16 + m16;
                av[d] = *(const bf16x8*)((const char*)sVT +
                        ((rowv*256 + 128 + ks*64 + quad*16) ^ ((rowv & 7) << 4)));
            }
            #pragma unroll
            for (int j = 0; j < 2; ++j)
                bp[j] = *(const bf16x8*)&sPhi[(wm + j*16 + m16)*PHK_PAD + ks*32 + quad*8];
            #pragma unroll
            for (int d = 0; d < 5; ++d)
                #pragma unroll
                for (int j = 0; j < 2; ++j)
                    kvacc[d][j] = __builtin_amdgcn_mfma_f32_16x16x32_bf16(
                        av[d], bp[j], kvacc[d][j], 0, 0, 0);
        }
        PRIO0_();
    }

    #pragma unroll
    for (int d = 0; d < 5; ++d)
        #pragma unroll
        for (int j = 0; j < 2; ++j) {
            int drow = d*16 + quad*4;
            int m = wm + j*16 + m16;
            #pragma unroll
            for (int r = 0; r < 4; ++r)
                atomicAdd(&KVt32[((size_t)bh*VTROWS_ + drow + r)*M_ + m],
                          kvacc[d][j][r]);
        }
}

// ---------------------------------------------------------------------------
// fused_ctx (unchanged from round 5)
// ---------------------------------------------------------------------------
__global__ __launch_bounds__(512, 1)
void fused_ctx(const f16* __restrict__ Qh, const f16* __restrict__ omhi,
               const f16* __restrict__ omlo, const bf16* __restrict__ KVb,
               bf16* __restrict__ ctx)
{
    __shared__ __align__(16) f16  sOmH[M_*DK_];        // 32 KB, swizzled
    __shared__ __align__(16) f16  sOmL[M_*DK_];        // 32 KB, swizzled
    __shared__ __align__(16) bf16 sPhi[128*PHQ_PAD];   // 66 KB [n][264]
    __shared__ float sden[2][128];
    const int nsp = blockIdx.x;          // 0..3
    const int h = blockIdx.y, b = blockIdx.z;
    const int bh = b*H_ + h;
    const int tid = threadIdx.x, lane = tid & 63, wave = tid >> 6;
    const int m16 = lane & 15, quad = lane >> 4;
    const float inv_sqrt_m = rsqrtf((float)M_ + 1e-6f);
    const f16* omh = omhi + (size_t)h * M_ * DK_;
    const f16* oml = omlo + (size_t)h * M_ * DK_;

    STAGEOM_(sOmH, omh);
    STAGEOM_(sOmL, oml);
    asm volatile("s_waitcnt vmcnt(0)");
    SBAR_();
    BAR_();

    const int wq = wave >> 2;
    const int wc = wave & 3;

    for (int nb = 0; nb < 8; ++nb) {
        const int q0 = nsp*1024 + nb*128;

        const int rowq = wave*16 + m16;
        f16x8 ah0 = *(const f16x8*)&Qh[(size_t)(b*N_ + q0 + rowq)*D_ + h*DK_ + quad*8];
        f16x8 ah1 = *(const f16x8*)&Qh[(size_t)(b*N_ + q0 + rowq)*D_ + h*DK_ + 32 + quad*8];

        f32x4 acc[16];
        #pragma unroll
        for (int j = 0; j < 16; ++j) acc[j] = (f32x4){0.f, 0.f, 0.f, 0.f};

        PRIO1_();
        #pragma unroll
        for (int j = 0; j < 16; ++j) {
            int rowm = j*16 + m16;
            int bo0 = (rowm*128 +      quad*16) ^ ((rowm & 7) << 4);
            int bo1 = (rowm*128 + 64 + quad*16) ^ ((rowm & 7) << 4);
            f16x8 bh0 = *(const f16x8*)((const char*)sOmH + bo0);
            f16x8 bh1 = *(const f16x8*)((const char*)sOmH + bo1);
            f16x8 bl0 = *(const f16x8*)((const char*)sOmL + bo0);
            f16x8 bl1 = *(const f16x8*)((const char*)sOmL + bo1);
            acc[j] = __builtin_amdgcn_mfma_f32_16x16x32_f16(ah0, bh0, acc[j], 0,0,0);
            acc[j] = __builtin_amdgcn_mfma_f32_16x16x32_f16(ah0, bl0, acc[j], 0,0,0);
            acc[j] = __builtin_amdgcn_mfma_f32_16x16x32_f16(ah1, bh1, acc[j], 0,0,0);
            acc[j] = __builtin_amdgcn_mfma_f32_16x16x32_f16(ah1, bl1, acc[j], 0,0,0);
        }
        PRIO0_();

        bf16x8 wf[2][8];
        #pragma unroll
        for (int jr = 0; jr < 2; ++jr) {
            int rowk = wc*32 + jr*16 + m16;
            #pragma unroll
            for (int ks = 0; ks < 8; ++ks)
                wf[jr][ks] = *(const bf16x8*)&KVb[((size_t)bh*KVROWS_ + rowk)*M_
                                                  + ks*32 + quad*8];
        }

        #pragma unroll
        for (int r = 0; r < 4; ++r) {
            float mx = acc[0][r];
            #pragma unroll
            for (int j = 1; j < 16; ++j) mx = fmaxf(mx, acc[j][r]);
            mx = fmaxf(mx, __shfl_xor(mx, 1, 64));
            mx = fmaxf(mx, __shfl_xor(mx, 2, 64));
            mx = fmaxf(mx, __shfl_xor(mx, 4, 64));
            mx = fmaxf(mx, __shfl_xor(mx, 8, 64));
            #pragma unroll
            for (int j = 0; j < 16; ++j)
                acc[j][r] = __expf(acc[j][r] - mx) * inv_sqrt_m;
        }

        {
            int nloc0 = wave*16 + quad*4;
            #pragma unroll
            for (int j = 0; j < 16; ++j)
                #pragma unroll
                for (int r = 0; r < 4; ++r)
                    sPhi[(nloc0 + r)*PHQ_PAD + j*16 + m16] = (bf16)acc[j][r];
        }
        asm volatile("s_waitcnt lgkmcnt(0)");
        SBAR_();
        BAR_();

        f32x4 cacc[4][2];
        #pragma unroll
        for (int i = 0; i < 4; ++i)
            #pragma unroll
            for (int j = 0; j < 2; ++j)
                cacc[i][j] = (f32x4){0.f, 0.f, 0.f, 0.f};

        PRIO1_();
        #pragma unroll
        for (int ks = 0; ks < 8; ++ks) {
            bf16x8 af[4];
            #pragma unroll
            for (int i = 0; i < 4; ++i)
                af[i] = *(const bf16x8*)&sPhi[(wq*64 + i*16 + m16)*PHQ_PAD
                                              + ks*32 + quad*8];
            #pragma unroll
            for (int i = 0; i < 4; ++i)
                #pragma unroll
                for (int jr = 0; jr < 2; ++jr)
                    cacc[i][jr] = __builtin_amdgcn_mfma_f32_16x16x32_bf16(
                        af[i], wf[jr][ks], cacc[i][jr], 0, 0, 0);
        }
        PRIO0_();

        if (wc == 2 && m16 < 2) {
            #pragma unroll
            for (int i = 0; i < 4; ++i)
                #pragma unroll
                for (int r = 0; r < 4; ++r)
                    sden[m16][wq*64 + i*16 + quad*4 + r] = cacc[i][0][r];
        }
        asm volatile("s_waitcnt lgkmcnt(0)");
        SBAR_();
        BAR_();

        if (wc < 2) {
            #pragma unroll
            for (int i = 0; i < 4; ++i) {
                #pragma unroll
                for (int r = 0; r < 4; ++r) {
                    int lrow = wq*64 + i*16 + quad*4 + r;
                    float den = sden[0][lrow] + sden[1][lrow] + EPS_;
                    #pragma unroll
                    for (int jr = 0; jr < 2; ++jr)
                        ctx[(size_t)(b*N_ + q0 + lrow)*D_ + h*DK_
                            + wc*32 + jr*16 + m16] = (bf16)(cacc[i][jr][r] / den);
                }
            }
        }
        asm volatile("s_waitcnt lgkmcnt(0)");
        SBAR_();
        BAR_();
    }
}

// ---------------------------------------------------------------------------
extern "C" void kernel_launch(void* const* d_in, const int* in_sizes, int n_in,
                              void* d_out, int out_size, void* d_ws, size_t ws_size,
                              hipStream_t stream)
{
    const float* x     = (const float*)d_in[0];
    const int*   mask  = (const int*)d_in[1];     // 1 = PAD
    const float* Wqkv  = (const float*)d_in[2];
    const float* bqkv  = (const float*)d_in[3];
    const float* Wout  = (const float*)d_in[4];
    const float* bout  = (const float*)d_in[5];
    const float* omega = (const float*)d_in[6];
    float* out = (float*)d_out;

    char* w = (char*)d_ws;
    f16*   Wh    = (f16*)w;    w += (size_t)3*D_*D_ * 2;              //   6.29 MB
    bf16*  Wob   = (bf16*)w;   w += (size_t)D_*D_ * 2;                //   2.10 MB
    f16*   omhi  = (f16*)w;    w += (size_t)H_*M_*DK_ * 2;            //   0.52 MB
    f16*   omlo  = (f16*)w;    w += (size_t)H_*M_*DK_ * 2;            //   0.52 MB
    f16*   xh    = (f16*)w;    w += (size_t)R_ * D_ * 2;              //  33.55 MB
    f16*   Qh    = (f16*)w;    w += (size_t)R_ * D_ * 2;              //  33.55 MB
    f16*   Kh    = (f16*)w;    w += (size_t)R_ * D_ * 2;              //  33.55 MB (-> ctx)
    bf16*  VT    = (bf16*)w;   w += (size_t)B_*H_*VTROWS_*N_ * 2;     //  41.94 MB
    float* KVt32 = (float*)w;  w += (size_t)B_*H_*VTROWS_*M_ * 4;     //   5.24 MB
    bf16*  KVb   = (bf16*)w;   w += (size_t)B_*H_*KVROWS_*M_ * 2;     //   4.19 MB
    bf16*  VC    = (bf16*)Kh;                                         // alias (Kh dead after fused_kv)

    // 0) prep
    split_f16v<<<(R_*D_/4 + 255)/256, 256, 0, stream>>>(x, xh, nullptr, R_*D_/4);
    split_f16v<<<(3*D_*D_/4 + 255)/256, 256, 0, stream>>>(Wqkv, Wh, nullptr, 3*D_*D_/4);
    split_f16v<<<(H_*M_*DK_/4 + 255)/256, 256, 0, stream>>>(omega, omhi, omlo, H_*M_*DK_/4);
    f32_to_bf16v<<<(D_*D_/4 + 255)/256, 256, 0, stream>>>(Wout, Wob, D_*D_/4);
    zero_f32<<<(B_*H_*VTROWS_*M_ + 255)/256, 256, 0, stream>>>(KVt32, B_*H_*VTROWS_*M_);
    init_vt<<<(B_*H_*16*N_ + 255)/256, 256, 0, stream>>>(VT);

    // 1) QKV projection: Q/K (swapped-epilogue) + V (transposed VT)
    gemm_qkv_qk<<<dim3(8, R_/256), 512, 0, stream>>>(xh, Wh, bqkv, Qh, Kh);
    gemm_qkv_v <<<dim3(4, R_/256), 512, 0, stream>>>(xh, Wh, bqkv, VT);

    // 2) fused K-features + KV/ksum accumulation (Phi_K in LDS only)
    fused_kv<<<dim3(4, H_, B_), 512, 0, stream>>>(Kh, VT, omhi, omlo, mask, KVt32);

    // 3) pack KVt32 -> KVb bf16 (ksum hi/lo rows 64/65, zero pad to 128)
    pack_kv<<<(B_*H_*KVROWS_*M_ + 255)/256, 256, 0, stream>>>(KVt32, KVb);

    // 4) fused Q-features + ctx (Phi_Q in LDS only) -> VC bf16 (aliases Kh)
    fused_ctx<<<dim3(4, H_, B_), 512, 0, stream>>>(Qh, omhi, omlo, KVb, VC);

    // 5) output projection + bias + PAD-query zeroing -> fp32 out (8-phase)
    gemm_out8<<<dim3(4, R_/256), 512, 0, stream>>>(VC, Wob, bout, out, mask);
}

// Round 8
// 423.241 us; speedup vs baseline: 1.5299x; 1.0369x over previous
//
#include <hip/hip_runtime.h>
#include <hip/hip_bf16.h>
#include <math.h>

#define B_  4
#define N_  4096
#define D_  1024
#define H_  16
#define DK_ 64
#define M_  256
#define R_  (B_*N_)          // 16384 rows
#define EPS_ 1e-6f
#define VTROWS_ 80           // 64 V rows + row64=ones(ksum) + 65..79 pad
#define KVROWS_ 128          // KVb bf16: 64 KV + 64=ksum_hi + 65=ksum_lo + 0-pad
#define PHK_PAD 68           // fused_kv  Phi LDS [m][68]  (n-HALF + pad)
#define PHQ_PAD 264          // fused_ctx Phi LDS [n][264]

typedef __bf16 bf16;
typedef __bf16 bf16x4 __attribute__((ext_vector_type(4)));
typedef __bf16 bf16x8 __attribute__((ext_vector_type(8)));
typedef _Float16 f16;
typedef _Float16 f16x4 __attribute__((ext_vector_type(4)));
typedef _Float16 f16x8 __attribute__((ext_vector_type(8)));
typedef float  f32x4  __attribute__((ext_vector_type(4)));

#define GLD(gp, lp) __builtin_amdgcn_global_load_lds( \
    (const __attribute__((address_space(1))) void*)(gp), \
    (__attribute__((address_space(3))) void*)(lp), 16, 0, 0)

#define BAR_()   __builtin_amdgcn_s_barrier()
#define SBAR_()  __builtin_amdgcn_sched_barrier(0)
#define PRIO1_() __builtin_amdgcn_s_setprio(1)
#define PRIO0_() __builtin_amdgcn_s_setprio(0)
#define LGK0_()  do { asm volatile("s_waitcnt lgkmcnt(0)"); SBAR_(); } while (0)
#define LGK8_()  asm volatile("s_waitcnt lgkmcnt(8)")
#define VMC4_()  do { asm volatile("s_waitcnt vmcnt(4)"); SBAR_(); } while (0)

// ---------------------------------------------------------------------------
// prep_all: all 6 elementwise prep ops in ONE launch (range-branched).
// blocks: [0,16384) x->xh | [16384,19456) Wqkv->Wh | [19456,19712) omega
//         [19712,20736) Wout->Wob | [20736,22016) zero KVt32
//         [22016,24064) init VT rows 64..79
// ---------------------------------------------------------------------------
__global__ __launch_bounds__(256)
void prep_all(const float* __restrict__ x, f16* __restrict__ xh,
              const float* __restrict__ Wqkv, f16* __restrict__ Wh,
              const float* __restrict__ omega, f16* __restrict__ omhi,
              f16* __restrict__ omlo,
              const float* __restrict__ Wout, bf16* __restrict__ Wob,
              float* __restrict__ KVt32, bf16* __restrict__ VT)
{
    const int bid = blockIdx.x, tid = threadIdx.x;
    if (bid < 16384) {                       // x -> xh  (f16x4)
        int i = bid*256 + tid;
        float4 v = ((const float4*)x)[i];
        f16x4 h = { (f16)v.x, (f16)v.y, (f16)v.z, (f16)v.w };
        ((f16x4*)xh)[i] = h;
    } else if (bid < 19456) {                // Wqkv -> Wh
        int i = (bid - 16384)*256 + tid;
        float4 v = ((const float4*)Wqkv)[i];
        f16x4 h = { (f16)v.x, (f16)v.y, (f16)v.z, (f16)v.w };
        ((f16x4*)Wh)[i] = h;
    } else if (bid < 19712) {                // omega -> omhi + omlo (residual)
        int i = (bid - 19456)*256 + tid;
        float4 v = ((const float4*)omega)[i];
        f16x4 h = { (f16)v.x, (f16)v.y, (f16)v.z, (f16)v.w };
        ((f16x4*)omhi)[i] = h;
        f16x4 l = { (f16)(v.x - (float)h[0]), (f16)(v.y - (float)h[1]),
                    (f16)(v.z - (float)h[2]), (f16)(v.w - (float)h[3]) };
        ((f16x4*)omlo)[i] = l;
    } else if (bid < 20736) {                // Wout -> Wob (bf16x4)
        int i = (bid - 19712)*256 + tid;
        float4 v = ((const float4*)Wout)[i];
        bf16x4 h = { (bf16)v.x, (bf16)v.y, (bf16)v.z, (bf16)v.w };
        ((bf16x4*)Wob)[i] = h;
    } else if (bid < 22016) {                // zero KVt32 (float4)
        int i = (bid - 20736)*256 + tid;
        ((float4*)KVt32)[i] = make_float4(0.f, 0.f, 0.f, 0.f);
    } else {                                 // VT rows 64..79 (bf16x8)
        int i = (bid - 22016)*256 + tid;     // < 524288
        int bh  = i >> 13;                   // / (16*512)
        int rem = i & 8191;
        int row = 64 + (rem >> 9);
        int n8  = rem & 511;
        bf16 val = (row == 64) ? (bf16)1.0f : (bf16)0.0f;
        bf16x8 pk = { val, val, val, val, val, val, val, val };
        *(bf16x8*)&VT[((size_t)bh*VTROWS_ + row)*N_ + n8*8] = pk;
    }
}

__global__ __launch_bounds__(256)
void pack_kv(const float* __restrict__ KVt32, bf16* __restrict__ KVb)
{
    int i = blockIdx.x * 256 + threadIdx.x;          // 64bh x 128 x 256
    if (i >= B_*H_*KVROWS_*M_) return;
    int bh  = i >> 15;
    int rem = i & 32767;
    int row = rem >> 8;
    int m   = rem & (M_-1);
    bf16 o = (bf16)0.0f;
    if (row < 64) {
        o = (bf16)KVt32[((size_t)bh*VTROWS_ + row)*M_ + m];
    } else if (row == 64) {
        o = (bf16)KVt32[((size_t)bh*VTROWS_ + 64)*M_ + m];
    } else if (row == 65) {
        float v = KVt32[((size_t)bh*VTROWS_ + 64)*M_ + m];
        o = (bf16)(v - (float)(bf16)v);
    }
    KVb[i] = o;
}

// ---------------------------------------------------------------------------
// 8-phase 256x256 GEMM machinery (shared macros).
// SWAPPED mfma (operands reversed) gives D[bcol][arow]: per lane the 4 regs
// are 4 CONSECUTIVE output columns -> packed 8B/16B epilogue stores.
// ---------------------------------------------------------------------------
#define STAGE_(dstbuf, srcp, kt, half) do { \
    _Pragma("unroll") \
    for (int q_ = 0; q_ < 2; ++q_) { \
        int idx_ = q_*512 + tid; \
        int row_ = idx_ >> 3; \
        int seg_ = (idx_ & 7) ^ (row_ & 7); \
        GLD((srcp) + (size_t)((half)*128 + row_) * D_ + (kt)*64 + seg_*8, \
            &(dstbuf)[(half)*8192 + idx_*8]); \
    } } while (0)

#define LDA_G(T, buf, i0) do { \
    _Pragma("unroll") \
    for (int i_ = 0; i_ < 4; ++i_) { \
        _Pragma("unroll") \
        for (int k_ = 0; k_ < 2; ++k_) { \
            int row_ = warp_m*128 + ((i0)+i_)*16 + m16; \
            int off_ = (row_*128 + k_*64 + quad*16) ^ ((row_ & 7) << 4); \
            a[i_][k_] = *(const T*)((const char*)(buf) + off_); \
        } } } while (0)

#define LDB_G(T, buf, j0) do { \
    _Pragma("unroll") \
    for (int j_ = 0; j_ < 2; ++j_) { \
        _Pragma("unroll") \
        for (int k_ = 0; k_ < 2; ++k_) { \
            int row_ = warp_n*64 + ((j0)+j_)*16 + m16; \
            int off_ = (row_*128 + k_*64 + quad*16) ^ ((row_ & 7) << 4); \
            b[(j0)+j_][k_] = *(const T*)((const char*)(buf) + off_); \
        } } } while (0)

#define MFMA_F16N(I0, J0) do { \
    _Pragma("unroll") \
    for (int i_ = 0; i_ < 4; ++i_) \
        _Pragma("unroll") \
        for (int j_ = 0; j_ < 2; ++j_) \
            _Pragma("unroll") \
            for (int k_ = 0; k_ < 2; ++k_) \
                acc[(I0)+i_][(J0)+j_] = __builtin_amdgcn_mfma_f32_16x16x32_f16( \
                    a[i_][k_], b[(J0)+j_][k_], acc[(I0)+i_][(J0)+j_], 0, 0, 0); \
    } while (0)

#define MFMA_F16S(I0, J0) do { \
    _Pragma("unroll") \
    for (int i_ = 0; i_ < 4; ++i_) \
        _Pragma("unroll") \
        for (int j_ = 0; j_ < 2; ++j_) \
            _Pragma("unroll") \
            for (int k_ = 0; k_ < 2; ++k_) \
                acc[(I0)+i_][(J0)+j_] = __builtin_amdgcn_mfma_f32_16x16x32_f16( \
                    b[(J0)+j_][k_], a[i_][k_], acc[(I0)+i_][(J0)+j_], 0, 0, 0); \
    } while (0)

#define MFMA_BF16S(I0, J0) do { \
    _Pragma("unroll") \
    for (int i_ = 0; i_ < 4; ++i_) \
        _Pragma("unroll") \
        for (int j_ = 0; j_ < 2; ++j_) \
            _Pragma("unroll") \
            for (int k_ = 0; k_ < 2; ++k_) \
                acc[(I0)+i_][(J0)+j_] = __builtin_amdgcn_mfma_f32_16x16x32_bf16( \
                    b[(J0)+j_][k_], a[i_][k_], acc[(I0)+i_][(J0)+j_], 0, 0, 0); \
    } while (0)

// The verified 8-phase K-loop (round-5/7), MFMA op selectable.
#define KLOOP_8PH(MFMA_OP) \
    STAGE_(sA[0], gA, 0, 0); \
    STAGE_(sA[0], gA, 0, 1); \
    STAGE_(sB[0], gB, 0, 0); \
    STAGE_(sB[0], gB, 0, 1); \
    STAGE_(sB[1], gB, 1, 0); \
    STAGE_(sB[1], gB, 1, 1); \
    VMC4_(); \
    BAR_(); \
    for (int it = 0; it < 8; ++it) { \
        const int t1 = 2*it + 1, t2 = 2*it + 2, t3 = 2*it + 3; \
        LDA_G(FRAG_T, sA[0], 0); LDB_G(FRAG_T, sB[0], 0); \
        STAGE_(sA[1], gA, t1, 0); \
        LGK8_(); \
        BAR_(); LGK0_(); \
        PRIO1_(); MFMA_OP(0, 0); PRIO0_(); \
        BAR_(); \
        LDB_G(FRAG_T, sB[0], 2); \
        STAGE_(sA[1], gA, t1, 1); \
        BAR_(); LGK0_(); \
        PRIO1_(); MFMA_OP(0, 2); PRIO0_(); \
        BAR_(); \
        LDA_G(FRAG_T, sA[0], 4); \
        if (t2 < 16) STAGE_(sB[0], gB, t2, 0); \
        BAR_(); LGK0_(); \
        PRIO1_(); MFMA_OP(4, 2); PRIO0_(); \
        BAR_(); \
        if (t2 < 16) STAGE_(sB[0], gB, t2, 1); \
        VMC4_(); \
        BAR_(); \
        PRIO1_(); MFMA_OP(4, 0); PRIO0_(); \
        BAR_(); \
        LDA_G(FRAG_T, sA[1], 0); LDB_G(FRAG_T, sB[1], 0); \
        if (t2 < 16) STAGE_(sA[0], gA, t2, 0); \
        LGK8_(); \
        BAR_(); LGK0_(); \
        PRIO1_(); MFMA_OP(0, 0); PRIO0_(); \
        BAR_(); \
        LDB_G(FRAG_T, sB[1], 2); \
        if (t2 < 16) STAGE_(sA[0], gA, t2, 1); \
        BAR_(); LGK0_(); \
        PRIO1_(); MFMA_OP(0, 2); PRIO0_(); \
        BAR_(); \
        LDA_G(FRAG_T, sA[1], 4); \
        if (t3 < 16) STAGE_(sB[1], gB, t3, 0); \
        BAR_(); LGK0_(); \
        PRIO1_(); MFMA_OP(4, 2); PRIO0_(); \
        BAR_(); \
        if (t3 < 16) STAGE_(sB[1], gB, t3, 1); \
        VMC4_(); \
        BAR_(); \
        PRIO1_(); MFMA_OP(4, 0); PRIO0_(); \
        BAR_(); \
    }

// ---------------------------------------------------------------------------
// Unified QKV projection in ONE launch (768 blocks): bnx<8 -> Q/K columns
// (SWAPPED mfma, packed f16x4 stores); bnx>=8 -> V columns (normal mfma,
// transposed bf16x4 VT stores). Branch is block-uniform.
// ---------------------------------------------------------------------------
#define FRAG_T f16x8
__global__ __launch_bounds__(512)
void gemm_qkv_all(const f16* __restrict__ X, const f16* __restrict__ Wh,
                  const float* __restrict__ bqkv,
                  f16* __restrict__ Qh, f16* __restrict__ Kh,
                  bf16* __restrict__ VT)
{
    __shared__ __align__(16) f16 sA[2][256*64];   // 64 KB
    __shared__ __align__(16) f16 sB[2][256*64];   // 64 KB
    const int tid = threadIdx.x;

    const int nwg = gridDim.x * gridDim.y;        // 768 (% 8 == 0)
    int flat = blockIdx.y * gridDim.x + blockIdx.x;
    int wgid = (flat & 7) * (nwg >> 3) + (flat >> 3);
    const int bm  = (wgid / 12) * 256;
    const int bnx = wgid % 12;

    const int lane = tid & 63, wave = tid >> 6;
    const int warp_m = wave >> 2, warp_n = wave & 3;
    const int m16 = lane & 15, quad = lane >> 4;

    f32x4 acc[8][4];
    #pragma unroll
    for (int i = 0; i < 8; ++i)
        #pragma unroll
        for (int j = 0; j < 4; ++j)
            acc[i][j] = (f32x4){0.f, 0.f, 0.f, 0.f};
    f16x8 a[4][2], b[4][2];

    if (bnx < 8) {
        const int bn = bnx * 256;                 // Q (<1024) or K
        const f16* gA = X  + (size_t)bm * D_;
        const f16* gB = Wh + (size_t)bn * D_;

        KLOOP_8PH(MFMA_F16S)

        // swapped epilogue: reg r -> C[row=..+m16][col=..+quad*4+r]
        f16* outp = (bn >= D_) ? Kh : Qh;
        const int cofs = (bn >= D_) ? D_ : 0;
        #pragma unroll
        for (int j = 0; j < 4; ++j) {
            int gcol0 = bn + warp_n*64 + j*16 + quad*4;
            float4 bv = *(const float4*)&bqkv[gcol0];
            int col0 = gcol0 - cofs;
            #pragma unroll
            for (int i = 0; i < 8; ++i) {
                int row = bm + warp_m*128 + i*16 + m16;
                f16x4 pk = { (f16)(acc[i][j][0] + bv.x), (f16)(acc[i][j][1] + bv.y),
                             (f16)(acc[i][j][2] + bv.z), (f16)(acc[i][j][3] + bv.w) };
                *(f16x4*)&outp[(size_t)row * D_ + col0] = pk;
            }
        }
    } else {
        const int bn = 2*D_ + (bnx - 8) * 256;    // V cols
        const f16* gA = X  + (size_t)bm * D_;
        const f16* gB = Wh + (size_t)bn * D_;

        KLOOP_8PH(MFMA_F16N)

        #pragma unroll
        for (int j = 0; j < 4; ++j) {
            int gcol = bn + warp_n*64 + j*16 + m16;
            float bv = bqkv[gcol];
            int vcol = gcol - 2*D_;
            int hh = vcol >> 6, dd = vcol & 63;
            #pragma unroll
            for (int i = 0; i < 8; ++i) {
                int row0 = bm + warp_m*128 + i*16 + quad*4;
                int bb = row0 >> 12, nn = row0 & (N_-1);
                bf16x4 pk = { (bf16)(acc[i][j][0]+bv), (bf16)(acc[i][j][1]+bv),
                              (bf16)(acc[i][j][2]+bv), (bf16)(acc[i][j][3]+bv) };
                *(bf16x4*)&VT[(((size_t)bb*H_+hh)*VTROWS_ + dd)*N_ + nn] = pk;
            }
        }
    }
}
#undef FRAG_T

// ---------------------------------------------------------------------------
// Output projection, 8-phase 256x256, SWAPPED bf16 mfma -> float4 C stores.
// ---------------------------------------------------------------------------
#define FRAG_T bf16x8
__global__ __launch_bounds__(512)
void gemm_out8(const bf16* __restrict__ A, const bf16* __restrict__ W,
               const float* __restrict__ bias, float* __restrict__ C,
               const int* __restrict__ mask)
{
    __shared__ __align__(16) bf16 sA[2][256*64];
    __shared__ __align__(16) bf16 sB[2][256*64];
    const int tid = threadIdx.x;

    const int nwg = gridDim.x * gridDim.y;        // 256
    int flat = blockIdx.y * gridDim.x + blockIdx.x;
    int wgid = (flat & 7) * (nwg >> 3) + (flat >> 3);
    const int bm = (wgid >> 2) * 256;
    const int bn = (wgid & 3) * 256;

    const int lane = tid & 63, wave = tid >> 6;
    const int warp_m = wave >> 2, warp_n = wave & 3;
    const int m16 = lane & 15, quad = lane >> 4;

    const bf16* gA = A + (size_t)bm * D_;
    const bf16* gB = W + (size_t)bn * D_;

    f32x4 acc[8][4];
    #pragma unroll
    for (int i = 0; i < 8; ++i)
        #pragma unroll
        for (int j = 0; j < 4; ++j)
            acc[i][j] = (f32x4){0.f, 0.f, 0.f, 0.f};
    bf16x8 a[4][2], b[4][2];

    KLOOP_8PH(MFMA_BF16S)

    #pragma unroll
    for (int j = 0; j < 4; ++j) {
        int col0 = bn + warp_n*64 + j*16 + quad*4;
        float4 bv = *(const float4*)&bias[col0];
        #pragma unroll
        for (int i = 0; i < 8; ++i) {
            int row = bm + warp_m*128 + i*16 + m16;
            float4 v;
            if (mask[row] != 0) {
                v = make_float4(0.f, 0.f, 0.f, 0.f);
            } else {
                v = make_float4(acc[i][j][0] + bv.x, acc[i][j][1] + bv.y,
                                acc[i][j][2] + bv.z, acc[i][j][3] + bv.w);
            }
            *(float4*)&C[(size_t)row * D_ + col0] = v;
        }
    }
}
#undef FRAG_T

// ---------------------------------------------------------------------------
// fused_kv (unchanged)
// ---------------------------------------------------------------------------
#define STAGEK_(sub_, bi_) do { \
    const int n0_ = nsp*1024 + (sub_)*128; \
    _Pragma("unroll") \
    for (int it_ = 0; it_ < 2; ++it_) { \
        int idx_ = it_*512 + tid; \
        int row_ = idx_ >> 3, seg_ = (idx_ & 7) ^ (row_ & 7); \
        GLD(Kh + (size_t)(b*N_ + n0_ + row_) * D_ + h*DK_ + seg_*8, \
            &sK[bi_][idx_*8]); \
    } } while (0)

#define STAGEVT_(sub_) do { \
    const int n0_ = nsp*1024 + (sub_)*128; \
    _Pragma("unroll") \
    for (int it_ = 0; it_ < 2; ++it_) { \
        int idx_ = it_*512 + tid; \
        int row_ = idx_ >> 4, seg_ = (idx_ & 15) ^ (row_ & 7); \
        GLD(VT + ((size_t)bh*VTROWS_ + row_)*N_ + n0_ + seg_*8, \
            &sVT[idx_*8]); \
    } \
    if (tid < 256) { \
        int idx_ = 1024 + tid; \
        int row_ = idx_ >> 4, seg_ = (idx_ & 15) ^ (row_ & 7); \
        GLD(VT + ((size_t)bh*VTROWS_ + row_)*N_ + n0_ + seg_*8, \
            &sVT[idx_*8]); \
    } } while (0)

#define STAGEOM_(arr_, src_) do { \
    _Pragma("unroll") \
    for (int q_ = 0; q_ < 4; ++q_) { \
        int idx_ = q_*512 + tid; \
        int row_ = idx_ >> 3, seg_ = (idx_ & 7) ^ (row_ & 7); \
        GLD((src_) + (size_t)row_*DK_ + seg_*8, &(arr_)[idx_*8]); \
    } } while (0)

__global__ __launch_bounds__(512, 1)
void fused_kv(const f16* __restrict__ Kh, const bf16* __restrict__ VT,
              const f16* __restrict__ omhi, const f16* __restrict__ omlo,
              const int* __restrict__ mask, float* __restrict__ KVt32)
{
    __shared__ __align__(16) f16  sK[2][128*64];      // 32 KB, swizzled
    __shared__ __align__(16) bf16 sVT[VTROWS_*128];   // 20 KB single, swizzled
    __shared__ __align__(16) f16  sOmH[M_*DK_];       // 32 KB, swizzled
    __shared__ __align__(16) f16  sOmL[M_*DK_];       // 32 KB, swizzled
    __shared__ __align__(16) bf16 sPhi[M_*PHK_PAD];   // 34 KB  [m][68] n-half
    const int nsp = blockIdx.x;          // 0..3
    const int h = blockIdx.y, b = blockIdx.z;
    const int bh = b*H_ + h;
    const int tid = threadIdx.x, lane = tid & 63, wave = tid >> 6;
    const int m16 = lane & 15, quad = lane >> 4;
    const int wm = wave * 32;            // wave's m-range for kv MFMA
    const int nloc = wave*16 + quad*4;   // wave's n-rows: wave*16..+15
    const float inv_sqrt_m = rsqrtf((float)M_ + 1e-6f);
    const f16* omh = omhi + (size_t)h * M_ * DK_;
    const f16* oml = omlo + (size_t)h * M_ * DK_;

    f32x4 kvacc[5][2];
    #pragma unroll
    for (int d = 0; d < 5; ++d)
        #pragma unroll
        for (int j = 0; j < 2; ++j)
            kvacc[d][j] = (f32x4){0.f, 0.f, 0.f, 0.f};

    STAGEOM_(sOmH, omh);
    STAGEOM_(sOmL, oml);
    STAGEK_(0, 0);

    for (int sub = 0; sub < 8; ++sub) {
        const int cur = sub & 1;
        const int n0 = nsp*1024 + sub*128;

        asm volatile("s_waitcnt vmcnt(0) lgkmcnt(0)");
        SBAR_();
        BAR_();

        int4 mv4 = *(const int4*)&mask[b*N_ + n0 + nloc];
        const int* mv = (const int*)&mv4;
        STAGEVT_(sub);
        if (sub < 7) STAGEK_(sub+1, cur^1);

        const char* kb = (const char*)&sK[cur][0];
        const int rowb = wave*16 + m16;
        f16x8 ah0 = *(const f16x8*)(kb + ((rowb*128 +      quad*16) ^ ((rowb & 7) << 4)));
        f16x8 ah1 = *(const f16x8*)(kb + ((rowb*128 + 64 + quad*16) ^ ((rowb & 7) << 4)));

        f32x4 acc[16];
        #pragma unroll
        for (int j = 0; j < 16; ++j) acc[j] = (f32x4){0.f, 0.f, 0.f, 0.f};

        PRIO1_();
        #pragma unroll
        for (int j = 0; j < 16; ++j) {
            int rowm = j*16 + m16;
            int bo0 = (rowm*128 +      quad*16) ^ ((rowm & 7) << 4);
            int bo1 = (rowm*128 + 64 + quad*16) ^ ((rowm & 7) << 4);
            f16x8 bh0 = *(const f16x8*)((const char*)sOmH + bo0);
            f16x8 bh1 = *(const f16x8*)((const char*)sOmH + bo1);
            f16x8 bl0 = *(const f16x8*)((const char*)sOmL + bo0);
            f16x8 bl1 = *(const f16x8*)((const char*)sOmL + bo1);
            acc[j] = __builtin_amdgcn_mfma_f32_16x16x32_f16(ah0, bh0, acc[j], 0,0,0);
            acc[j] = __builtin_amdgcn_mfma_f32_16x16x32_f16(ah0, bl0, acc[j], 0,0,0);
            acc[j] = __builtin_amdgcn_mfma_f32_16x16x32_f16(ah1, bh1, acc[j], 0,0,0);
            acc[j] = __builtin_amdgcn_mfma_f32_16x16x32_f16(ah1, bl1, acc[j], 0,0,0);
        }
        PRIO0_();

        #pragma unroll
        for (int r = 0; r < 4; ++r) {
            float mx = acc[0][r];
            #pragma unroll
            for (int j = 1; j < 16; ++j) mx = fmaxf(mx, acc[j][r]);
            mx = fmaxf(mx, __shfl_xor(mx, 1, 64));
            mx = fmaxf(mx, __shfl_xor(mx, 2, 64));
            mx = fmaxf(mx, __shfl_xor(mx, 4, 64));
            mx = fmaxf(mx, __shfl_xor(mx, 8, 64));
            #pragma unroll
            for (int j = 0; j < 16; ++j)
                acc[j][r] = __expf(acc[j][r] - mx) * inv_sqrt_m;
        }

        if (wave < 4) {
            #pragma unroll
            for (int j = 0; j < 16; ++j) {
                bf16x4 pk;
                #pragma unroll
                for (int r = 0; r < 4; ++r)
                    pk[r] = mv[r] ? (bf16)0.0f : (bf16)acc[j][r];
                *(bf16x4*)&sPhi[(j*16 + m16)*PHK_PAD + nloc] = pk;
            }
        }
        asm volatile("s_waitcnt lgkmcnt(0)");
        if (sub < 7) { asm volatile("s_waitcnt vmcnt(2)"); }
        else         { asm volatile("s_waitcnt vmcnt(0)"); }
        SBAR_();
        BAR_();   // (C1) PhiA + VT visible

        PRIO1_();
        #pragma unroll
        for (int ks = 0; ks < 2; ++ks) {
            bf16x8 av[5], bp[2];
            #pragma unroll
            for (int d = 0; d < 5; ++d) {
                int rowv = d*16 + m16;
                av[d] = *(const bf16x8*)((const char*)sVT +
                        ((rowv*256 + ks*64 + quad*16) ^ ((rowv & 7) << 4)));
            }
            #pragma unroll
            for (int j = 0; j < 2; ++j)
                bp[j] = *(const bf16x8*)&sPhi[(wm + j*16 + m16)*PHK_PAD + ks*32 + quad*8];
            #pragma unroll
            for (int d = 0; d < 5; ++d)
                #pragma unroll
                for (int j = 0; j < 2; ++j)
                    kvacc[d][j] = __builtin_amdgcn_mfma_f32_16x16x32_bf16(
                        av[d], bp[j], kvacc[d][j], 0, 0, 0);
        }
        PRIO0_();
        asm volatile("s_waitcnt lgkmcnt(0)");
        SBAR_();
        BAR_();   // (C2)

        if (wave >= 4) {
            #pragma unroll
            for (int j = 0; j < 16; ++j) {
                bf16x4 pk;
                #pragma unroll
                for (int r = 0; r < 4; ++r)
                    pk[r] = mv[r] ? (bf16)0.0f : (bf16)acc[j][r];
                *(bf16x4*)&sPhi[(j*16 + m16)*PHK_PAD + (nloc - 64)] = pk;
            }
        }
        asm volatile("s_waitcnt lgkmcnt(0)");
        SBAR_();
        BAR_();   // (C3)

        PRIO1_();
        #pragma unroll
        for (int ks = 0; ks < 2; ++ks) {
            bf16x8 av[5], bp[2];
            #pragma unroll
            for (int d = 0; d < 5; ++d) {
                int rowv = d*16 + m16;
                av[d] = *(const bf16x8*)((const char*)sVT +
                        ((rowv*256 + 128 + ks*64 + quad*16) ^ ((rowv & 7) << 4)));
            }
            #pragma unroll
            for (int j = 0; j < 2; ++j)
                bp[j] = *(const bf16x8*)&sPhi[(wm + j*16 + m16)*PHK_PAD + ks*32 + quad*8];
            #pragma unroll
            for (int d = 0; d < 5; ++d)
                #pragma unroll
                for (int j = 0; j < 2; ++j)
                    kvacc[d][j] = __builtin_amdgcn_mfma_f32_16x16x32_bf16(
                        av[d], bp[j], kvacc[d][j], 0, 0, 0);
        }
        PRIO0_();
    }

    #pragma unroll
    for (int d = 0; d < 5; ++d)
        #pragma unroll
        for (int j = 0; j < 2; ++j) {
            int drow = d*16 + quad*4;
            int m = wm + j*16 + m16;
            #pragma unroll
            for (int r = 0; r < 4; ++r)
                atomicAdd(&KVt32[((size_t)bh*VTROWS_ + drow + r)*M_ + m],
                          kvacc[d][j][r]);
        }
}

// ---------------------------------------------------------------------------
// fused_ctx (unchanged)
// ---------------------------------------------------------------------------
__global__ __launch_bounds__(512, 1)
void fused_ctx(const f16* __restrict__ Qh, const f16* __restrict__ omhi,
               const f16* __restrict__ omlo, const bf16* __restrict__ KVb,
               bf16* __restrict__ ctx)
{
    __shared__ __align__(16) f16  sOmH[M_*DK_];        // 32 KB, swizzled
    __shared__ __align__(16) f16  sOmL[M_*DK_];        // 32 KB, swizzled
    __shared__ __align__(16) bf16 sPhi[128*PHQ_PAD];   // 66 KB [n][264]
    __shared__ float sden[2][128];
    const int nsp = blockIdx.x;          // 0..3
    const int h = blockIdx.y, b = blockIdx.z;
    const int bh = b*H_ + h;
    const int tid = threadIdx.x, lane = tid & 63, wave = tid >> 6;
    const int m16 = lane & 15, quad = lane >> 4;
    const float inv_sqrt_m = rsqrtf((float)M_ + 1e-6f);
    const f16* omh = omhi + (size_t)h * M_ * DK_;
    const f16* oml = omlo + (size_t)h * M_ * DK_;

    STAGEOM_(sOmH, omh);
    STAGEOM_(sOmL, oml);
    asm volatile("s_waitcnt vmcnt(0)");
    SBAR_();
    BAR_();

    const int wq = wave >> 2;
    const int wc = wave & 3;

    for (int nb = 0; nb < 8; ++nb) {
        const int q0 = nsp*1024 + nb*128;

        const int rowq = wave*16 + m16;
        f16x8 ah0 = *(const f16x8*)&Qh[(size_t)(b*N_ + q0 + rowq)*D_ + h*DK_ + quad*8];
        f16x8 ah1 = *(const f16x8*)&Qh[(size_t)(b*N_ + q0 + rowq)*D_ + h*DK_ + 32 + quad*8];

        f32x4 acc[16];
        #pragma unroll
        for (int j = 0; j < 16; ++j) acc[j] = (f32x4){0.f, 0.f, 0.f, 0.f};

        PRIO1_();
        #pragma unroll
        for (int j = 0; j < 16; ++j) {
            int rowm = j*16 + m16;
            int bo0 = (rowm*128 +      quad*16) ^ ((rowm & 7) << 4);
            int bo1 = (rowm*128 + 64 + quad*16) ^ ((rowm & 7) << 4);
            f16x8 bh0 = *(const f16x8*)((const char*)sOmH + bo0);
            f16x8 bh1 = *(const f16x8*)((const char*)sOmH + bo1);
            f16x8 bl0 = *(const f16x8*)((const char*)sOmL + bo0);
            f16x8 bl1 = *(const f16x8*)((const char*)sOmL + bo1);
            acc[j] = __builtin_amdgcn_mfma_f32_16x16x32_f16(ah0, bh0, acc[j], 0,0,0);
            acc[j] = __builtin_amdgcn_mfma_f32_16x16x32_f16(ah0, bl0, acc[j], 0,0,0);
            acc[j] = __builtin_amdgcn_mfma_f32_16x16x32_f16(ah1, bh1, acc[j], 0,0,0);
            acc[j] = __builtin_amdgcn_mfma_f32_16x16x32_f16(ah1, bl1, acc[j], 0,0,0);
        }
        PRIO0_();

        bf16x8 wf[2][8];
        #pragma unroll
        for (int jr = 0; jr < 2; ++jr) {
            int rowk = wc*32 + jr*16 + m16;
            #pragma unroll
            for (int ks = 0; ks < 8; ++ks)
                wf[jr][ks] = *(const bf16x8*)&KVb[((size_t)bh*KVROWS_ + rowk)*M_
                                                  + ks*32 + quad*8];
        }

        #pragma unroll
        for (int r = 0; r < 4; ++r) {
            float mx = acc[0][r];
            #pragma unroll
            for (int j = 1; j < 16; ++j) mx = fmaxf(mx, acc[j][r]);
            mx = fmaxf(mx, __shfl_xor(mx, 1, 64));
            mx = fmaxf(mx, __shfl_xor(mx, 2, 64));
            mx = fmaxf(mx, __shfl_xor(mx, 4, 64));
            mx = fmaxf(mx, __shfl_xor(mx, 8, 64));
            #pragma unroll
            for (int j = 0; j < 16; ++j)
                acc[j][r] = __expf(acc[j][r] - mx) * inv_sqrt_m;
        }

        {
            int nloc0 = wave*16 + quad*4;
            #pragma unroll
            for (int j = 0; j < 16; ++j)
                #pragma unroll
                for (int r = 0; r < 4; ++r)
                    sPhi[(nloc0 + r)*PHQ_PAD + j*16 + m16] = (bf16)acc[j][r];
        }
        asm volatile("s_waitcnt lgkmcnt(0)");
        SBAR_();
        BAR_();

        f32x4 cacc[4][2];
        #pragma unroll
        for (int i = 0; i < 4; ++i)
            #pragma unroll
            for (int j = 0; j < 2; ++j)
                cacc[i][j] = (f32x4){0.f, 0.f, 0.f, 0.f};

        PRIO1_();
        #pragma unroll
        for (int ks = 0; ks < 8; ++ks) {
            bf16x8 af[4];
            #pragma unroll
            for (int i = 0; i < 4; ++i)
                af[i] = *(const bf16x8*)&sPhi[(wq*64 + i*16 + m16)*PHQ_PAD
                                              + ks*32 + quad*8];
            #pragma unroll
            for (int i = 0; i < 4; ++i)
                #pragma unroll
                for (int jr = 0; jr < 2; ++jr)
                    cacc[i][jr] = __builtin_amdgcn_mfma_f32_16x16x32_bf16(
                        af[i], wf[jr][ks], cacc[i][jr], 0, 0, 0);
        }
        PRIO0_();

        if (wc == 2 && m16 < 2) {
            #pragma unroll
            for (int i = 0; i < 4; ++i)
                #pragma unroll
                for (int r = 0; r < 4; ++r)
                    sden[m16][wq*64 + i*16 + quad*4 + r] = cacc[i][0][r];
        }
        asm volatile("s_waitcnt lgkmcnt(0)");
        SBAR_();
        BAR_();

        if (wc < 2) {
            #pragma unroll
            for (int i = 0; i < 4; ++i) {
                #pragma unroll
                for (int r = 0; r < 4; ++r) {
                    int lrow = wq*64 + i*16 + quad*4 + r;
                    float den = sden[0][lrow] + sden[1][lrow] + EPS_;
                    #pragma unroll
                    for (int jr = 0; jr < 2; ++jr)
                        ctx[(size_t)(b*N_ + q0 + lrow)*D_ + h*DK_
                            + wc*32 + jr*16 + m16] = (bf16)(cacc[i][jr][r] / den);
                }
            }
        }
        asm volatile("s_waitcnt lgkmcnt(0)");
        SBAR_();
        BAR_();
    }
}

// ---------------------------------------------------------------------------
extern "C" void kernel_launch(void* const* d_in, const int* in_sizes, int n_in,
                              void* d_out, int out_size, void* d_ws, size_t ws_size,
                              hipStream_t stream)
{
    const float* x     = (const float*)d_in[0];
    const int*   mask  = (const int*)d_in[1];     // 1 = PAD
    const float* Wqkv  = (const float*)d_in[2];
    const float* bqkv  = (const float*)d_in[3];
    const float* Wout  = (const float*)d_in[4];
    const float* bout  = (const float*)d_in[5];
    const float* omega = (const float*)d_in[6];
    float* out = (float*)d_out;

    char* w = (char*)d_ws;
    f16*   Wh    = (f16*)w;    w += (size_t)3*D_*D_ * 2;              //   6.29 MB
    bf16*  Wob   = (bf16*)w;   w += (size_t)D_*D_ * 2;                //   2.10 MB
    f16*   omhi  = (f16*)w;    w += (size_t)H_*M_*DK_ * 2;            //   0.52 MB
    f16*   omlo  = (f16*)w;    w += (size_t)H_*M_*DK_ * 2;            //   0.52 MB
    f16*   xh    = (f16*)w;    w += (size_t)R_ * D_ * 2;              //  33.55 MB
    f16*   Qh    = (f16*)w;    w += (size_t)R_ * D_ * 2;              //  33.55 MB
    f16*   Kh    = (f16*)w;    w += (size_t)R_ * D_ * 2;              //  33.55 MB (-> ctx)
    bf16*  VT    = (bf16*)w;   w += (size_t)B_*H_*VTROWS_*N_ * 2;     //  41.94 MB
    float* KVt32 = (float*)w;  w += (size_t)B_*H_*VTROWS_*M_ * 4;     //   5.24 MB
    bf16*  KVb   = (bf16*)w;   w += (size_t)B_*H_*KVROWS_*M_ * 2;     //   4.19 MB
    bf16*  VC    = (bf16*)Kh;                                         // alias (Kh dead after fused_kv)

    // 0) all prep in one launch
    prep_all<<<24064, 256, 0, stream>>>(x, xh, Wqkv, Wh, omega, omhi, omlo,
                                        Wout, Wob, KVt32, VT);

    // 1) unified QKV projection, one launch: Q/K swapped-epilogue + V -> VT
    gemm_qkv_all<<<dim3(12, R_/256), 512, 0, stream>>>(xh, Wh, bqkv, Qh, Kh, VT);

    // 2) fused K-features + KV/ksum accumulation (Phi_K in LDS only)
    fused_kv<<<dim3(4, H_, B_), 512, 0, stream>>>(Kh, VT, omhi, omlo, mask, KVt32);

    // 3) pack KVt32 -> KVb bf16 (ksum hi/lo rows 64/65, zero pad to 128)
    pack_kv<<<(B_*H_*KVROWS_*M_ + 255)/256, 256, 0, stream>>>(KVt32, KVb);

    // 4) fused Q-features + ctx (Phi_Q in LDS only) -> VC bf16 (aliases Kh)
    fused_ctx<<<dim3(4, H_, B_), 512, 0, stream>>>(Qh, omhi, omlo, KVb, VC);

    // 5) output projection + bias + PAD-query zeroing -> fp32 out (8-phase)
    gemm_out8<<<dim3(4, R_/256), 512, 0, stream>>>(VC, Wob, bout, out, mask);
}